// Round 9
// baseline (21592.274 us; speedup 1.0000x reference)
//
#include <hip/hip_runtime.h>
#include <math.h>

#define NB 64
#define ND 2048
#define NE 512
#define NM 25
#define NOUT 4096
#define NHEADS 8
#define NDH 64
#define NS 64
#define NITER 50
#define NKSYN 2560
#define NWG 256
#define NTHR 512
#define PRED_TOTAL (NB * NOUT * NITER)   /* 13107200 */

typedef unsigned short bf16_t;

__device__ __forceinline__ float sigm(float x) { return 1.f / (1.f + expf(-x)); }

__device__ __forceinline__ bf16_t f2bf(float f) {
    unsigned u = __float_as_uint(f);
    unsigned r = (u + 0x7FFFu + ((u >> 16) & 1u)) >> 16;
    return (bf16_t)r;
}
__device__ __forceinline__ float bf2f(bf16_t h) {
    return __uint_as_float(((unsigned)h) << 16);
}

__device__ __forceinline__ float wredsum(float v) {
#pragma unroll
    for (int o = 32; o; o >>= 1) v += __shfl_xor(v, o);
    return v;
}
__device__ __forceinline__ float wredmax(float v) {
#pragma unroll
    for (int o = 32; o; o >>= 1) v = fmaxf(v, __shfl_xor(v, o));
    return v;
}

template <int OP>
__device__ __forceinline__ float blockReduce(float v, float* red) {
    const int tid = threadIdx.x, lane = tid & 63, wid = tid >> 6;
    v = (OP == 0) ? wredsum(v) : wredmax(v);
    __syncthreads();
    if (lane == 0) red[wid] = v;
    __syncthreads();
    if (tid == 0) {
        const int nw = blockDim.x >> 6;
        float r = red[0];
        for (int w = 1; w < nw; ++w) r = (OP == 0) ? r + red[w] : fmaxf(r, red[w]);
        red[0] = r;
    }
    __syncthreads();
    return red[0];
}

// Software grid barrier, round-4 post-mortem fix: RELEASE add on arrival
// (publishes this block's stores via L2 writeback), RELAXED polls (agent-
// visible, NO per-poll cache invalidate -- the round-4 bug), then exactly one
// ACQUIRE fence after the spin. barCnt zeroed by k_init_state every call.
__device__ __forceinline__ void gsync(unsigned* cnt, unsigned* nbar) {
    __syncthreads();
    if (threadIdx.x == 0) {
        __hip_atomic_fetch_add(cnt, 1u, __ATOMIC_RELEASE, __HIP_MEMORY_SCOPE_AGENT);
        const unsigned tgt = ++(*nbar) * NWG;
        while (__hip_atomic_load(cnt, __ATOMIC_RELAXED, __HIP_MEMORY_SCOPE_AGENT) < tgt)
            __builtin_amdgcn_s_sleep(1);
        __builtin_amdgcn_fence(__ATOMIC_ACQUIRE, "agent");
    }
    __syncthreads();
}

struct CtmP {
    const float *W_qq, *b_qq, *r_a, *r_o;
    const bf16_t *kp_t, *vp_t;
    const float *woSyn, *syn_w, *sbe, *ln_g, *ln_b;
    const float *w1t, *b1, *w2t, *b2;
    const float *out_w, *out_b;
    const int *ial, *iar, *iol, *ior;
    float *actT, *oT, *aA, *bA, *aO, *bO;
    float *trace2, *part, *predTemp, *out;
    unsigned *barCnt;
    int tmode;
};

// final: reduce 8 out-partials + log-softmax entropy -> predictions+certainty.
// Runs on blocks 0..63 (b = bid), 512 threads.
__device__ __forceinline__ void finalPhase(const CtmP& P, int b, int tt, float* red) {
    const int t = threadIdx.x;
    float pr[8];
    float lmax = -1e30f;
#pragma unroll
    for (int c = 0; c < 8; ++c) {
        const int j = t + c * 512;
        float v = P.out_b[j];
#pragma unroll
        for (int kp = 0; kp < 8; ++kp) v += P.part[((size_t)(kp * NB + b)) * NOUT + j];
        pr[c] = v;
        lmax = fmaxf(lmax, v);
    }
    const float mx = blockReduce<1>(lmax, red);
    float ls = 0.f;
#pragma unroll
    for (int c = 0; c < 8; ++c) ls += expf(pr[c] - mx);
    const float se = blockReduce<0>(ls, red);
    const float logZ = mx + logf(se);
    float le = 0.f;
#pragma unroll
    for (int c = 0; c < 8; ++c) { const float lp = pr[c] - logZ; le += expf(lp) * lp; }
    const float ent = blockReduce<0>(le, red);
    const float ne = -ent * 0.12022458674074694f;  // 1/ln(4096)
    if (P.tmode) {
#pragma unroll
        for (int c = 0; c < 8; ++c)
            P.predTemp[((size_t)b * NITER + tt) * NOUT + t + c * 512] = pr[c];
    } else {
#pragma unroll
        for (int c = 0; c < 8; ++c) {
            const int j = t + c * 512;
            P.out[((size_t)b * NOUT + j) * NITER + tt] = pr[c];
        }
    }
    if (t == 0) {
        P.out[PRED_TOTAL + b * 100 + tt] = ne;
        P.out[PRED_TOTAL + b * 100 + 50 + tt] = 1.f - ne;
    }
}

// Persistent kernel: 256 blocks x 512 threads, 5 software barriers/step.
// Phase bodies are verbatim ports of the round-8 multi-kernel versions.
__global__ __launch_bounds__(NTHR) void ctm_loop(CtmP P) {
    __shared__ float syncS[512];
    __shared__ float partK[512];
    __shared__ float qhS[128];
    __shared__ float attnS[128];
    __shared__ float red[8];
    __shared__ float syncL[2][4096];
    const int bid = blockIdx.x;
    const int jt = bid >> 6, b = bid & 63;
    const int t = threadIdx.x;
    const int lane = t & 63, wv = t >> 6;
    unsigned nbar = 0;

    for (int it = 0; it < NITER; ++it) {
        const int src = it & 1, dst = src ^ 1;
        // ---- Phase A: final(it-1) on jt==0, then front(it) on all ----
        if (it > 0 && jt == 0) finalPhase(P, b, it - 1, red);
        {
            // phase 1: action sync (all blocks compute; jt0 persists dbuf)
            {
                const int i = t;
                const float pl = P.actT[P.ial[i] * NB + b];
                const float prr = P.actT[P.iar[i] * NB + b];
                const float r = P.r_a[i];
                const float aN = r * P.aA[src * 32768 + b * NE + i] + pl * prr;
                const float bN = r * P.bA[src * 32768 + b * NE + i] + 1.f;
                if (jt == 0) {
                    P.aA[dst * 32768 + b * NE + i] = aN;
                    P.bA[dst * 32768 + b * NE + i] = bN;
                }
                syncS[i] = aN * rsqrtf(bN);
            }
            __syncthreads();
            // phase 2: qh j-slice [jt*128, +128), k-split 4
            {
                const int g = t >> 7, l = t & 127;
                const int j = jt * 128 + l;
                float acc = 0.f;
                const int kk0 = g * 128;
#pragma unroll 4
                for (int k = kk0; k < kk0 + 128; ++k)
                    acc = fmaf(syncS[k], P.W_qq[k * NE + j], acc);
                partK[g * 128 + l] = acc;
            }
            __syncthreads();
            if (t < 128)
                qhS[t] = P.b_qq[jt * 128 + t] + partK[t] + partK[128 + t] + partK[256 + t] + partK[384 + t];
            __syncthreads();
            // phase 3: scores + softmax for heads 2jt, 2jt+1
            if (wv < 2) {
                const int h = jt * 2 + wv, s = lane;
                const bf16_t* kpp = P.kp_t + ((size_t)(b * NHEADS + h) * NDH) * NS + s;
                float sc = 0.f;
#pragma unroll 8
                for (int d = 0; d < NDH; ++d) sc = fmaf(qhS[wv * 64 + d], bf2f(kpp[d * NS]), sc);
                sc *= 0.125f;
                const float mxv = wredmax(sc);
                const float ev = expf(sc - mxv);
                const float sm = wredsum(ev);
                attnS[wv * 64 + s] = ev / sm;
            }
            __syncthreads();
            // phase 4: o = attn @ V -> oT[e][b]
            if (wv < 2) {
                const int h = jt * 2 + wv, d = lane;
                const bf16_t* vpp = P.vp_t + ((size_t)(b * NHEADS + h) * NS) * NDH + d;
                float o = 0.f;
#pragma unroll 8
                for (int s2 = 0; s2 < NS; ++s2) o = fmaf(attnS[wv * 64 + s2], bf2f(vpp[s2 * NDH]), o);
                P.oT[(size_t)(h * NDH + d) * NB + b] = o;
            }
        }
        gsync(P.barCnt, &nbar);

        // ---- Phase B: syn GEMM, 1024 units over 256 blocks (2 par x 2 seq) ----
        {
            const int half = t >> 8;
            const int t2 = t & 255;
            const int jl = t2 & 63;
            const int b0 = __builtin_amdgcn_readfirstlane((t2 >> 6) & 3) * 16;
#pragma unroll 1
            for (int u = 0; u < 2; ++u) {
                const int unit = bid * 4 + half * 2 + u;
                const int kp = unit >> 6, jt2 = unit & 63;
                const int j = jt2 * 64 + jl;
                float acc[16];
#pragma unroll
                for (int q = 0; q < 16; ++q) acc[q] = 0.f;
                const int k0 = kp * 160;
#pragma unroll 4
                for (int k = k0; k < k0 + 160; ++k) {
                    const float w = (k < NE) ? P.woSyn[(size_t)k * NOUT + j]
                                             : P.syn_w[(size_t)k * NOUT + j];
                    const float* pk = (k < NE) ? (P.oT + k * NB + b0)
                                               : (P.actT + (k - NE) * NB + b0);
#pragma unroll
                    for (int q = 0; q < 16; ++q) acc[q] = fmaf(pk[q], w, acc[q]);
                }
#pragma unroll
                for (int q = 0; q < 16; ++q)
                    P.part[((size_t)(kp * NB + b0 + q)) * NOUT + j] = acc[q];
            }
        }
        gsync(P.barCnt, &nbar);

        // ---- Phase C: reduce 16 partials + GLU + LN -> trace2[pos] (jt==0) ----
        if (jt == 0) {
            const int pos = it % NM;
            float g[4];
            float ssum = 0.f;
#pragma unroll
            for (int c = 0; c < 4; ++c) {
                const int n = t + c * 512;
                float ya = P.sbe[n], yb = P.sbe[n + ND];
#pragma unroll
                for (int kp = 0; kp < 16; ++kp) {
                    ya += P.part[((size_t)(kp * NB + b)) * NOUT + n];
                    yb += P.part[((size_t)(kp * NB + b)) * NOUT + n + ND];
                }
                g[c] = ya * sigm(yb);
                ssum += g[c];
            }
            const float mean = blockReduce<0>(ssum, red) * (1.f / ND);
            float vsum = 0.f;
#pragma unroll
            for (int c = 0; c < 4; ++c) { const float d = g[c] - mean; vsum += d * d; }
            const float var = blockReduce<0>(vsum, red) * (1.f / ND);
            const float rs = rsqrtf(var + 1e-5f);
#pragma unroll
            for (int c = 0; c < 4; ++c) {
                const int n = t + c * 512;
                const float st = (g[c] - mean) * rs * P.ln_g[n] + P.ln_b[n];
                P.trace2[((size_t)pos * ND + n) * NB + b] = st;
            }
        }
        gsync(P.barCnt, &nbar);

        // ---- Phase D: per-neuron NLMs -> actT (1 neuron per wave) ----
        {
            const int pos = it % NM;
            const int bb = lane;
            const int n = bid * 8 + __builtin_amdgcn_readfirstlane(wv);
            const float* brow = P.b1 + n * 64;
            float acc[64];
#pragma unroll
            for (int q = 0; q < 64; ++q) acc[q] = brow[q];
            int phys = (pos + 1 < NM) ? pos + 1 : 0;
            float tr = P.trace2[((size_t)phys * ND + n) * NB + bb];
#pragma unroll 1
            for (int m = 0; m < NM; ++m) {
                const int physN = (phys + 1 < NM) ? phys + 1 : 0;
                float trn = 0.f;
                if (m + 1 < NM) trn = P.trace2[((size_t)physN * ND + n) * NB + bb];
                const float* wrow = P.w1t + ((size_t)n * NM + m) * 64;
#pragma unroll
                for (int q = 0; q < 64; ++q) acc[q] = fmaf(tr, wrow[q], acc[q]);
                tr = trn; phys = physN;
            }
            const float* w2r = P.w2t + n * 64;
            float z0 = P.b2[n * 2 + 0], z1 = P.b2[n * 2 + 1];
#pragma unroll
            for (int i = 0; i < 32; ++i) {
                const float hv = acc[i] * sigm(acc[32 + i]);
                z0 = fmaf(hv, w2r[i], z0);
                z1 = fmaf(hv, w2r[32 + i], z1);
            }
            P.actT[n * NB + bb] = z0 * sigm(z1);
        }
        gsync(P.barCnt, &nbar);

        // ---- Phase E: output sync + out GEMM, 512 units over 256 blocks ----
        {
            const int half = t >> 8;
            const int t2 = t & 255;
            const int unit = bid * 2 + half;
            const int kp = unit >> 6, jt2 = unit & 63;
            float* sL = syncL[half];
#pragma unroll
            for (int c = 0; c < 16; ++c) {
                const int idx = t2 + c * 256;
                const int il = idx >> 6, bb = idx & 63;
                const int i = kp * 64 + il;
                const float pl = P.actT[P.iol[i] * NB + bb];
                const float prr = P.actT[P.ior[i] * NB + bb];
                const float r = P.r_o[i];
                const float aN = r * P.aO[src * 32768 + i * NB + bb] + pl * prr;
                const float bN = r * P.bO[src * 32768 + i * NB + bb] + 1.f;
                if (jt2 == 0) {
                    P.aO[dst * 32768 + i * NB + bb] = aN;
                    P.bO[dst * 32768 + i * NB + bb] = bN;
                }
                sL[il * 64 + bb] = aN * rsqrtf(bN);
            }
            __syncthreads();
            const int bb = t2 & 63;
            const int j0 = jt2 * 64 + __builtin_amdgcn_readfirstlane((t2 >> 6) & 3) * 16;
            float acc[16];
#pragma unroll
            for (int q = 0; q < 16; ++q) acc[q] = 0.f;
#pragma unroll 4
            for (int k = 0; k < 64; ++k) {
                const float sv = sL[k * 64 + bb];
                const float* wrow = P.out_w + (size_t)(kp * 64 + k) * NOUT + j0;
#pragma unroll
                for (int q = 0; q < 16; ++q) acc[q] = fmaf(sv, wrow[q], acc[q]);
            }
            float* dstp = P.part + ((size_t)(kp * NB + bb)) * NOUT + j0;
#pragma unroll
            for (int q = 0; q < 16; ++q) dstp[q] = acc[q];
        }
        gsync(P.barCnt, &nbar);
    }
    // final for t = 49
    if (jt == 0) finalPhase(P, b, NITER - 1, red);
}

// ---------------- one-time precompute kernels ----------------

__global__ __launch_bounds__(512) void k_p0(const float* __restrict__ dec_a,
                                            const float* __restrict__ dec_o,
                                            const float* __restrict__ q_b,
                                            const float* __restrict__ wq,
                                            const float* __restrict__ bq,
                                            float* __restrict__ r_a, float* __restrict__ r_o,
                                            float* __restrict__ b_qq) {
    const int t = threadIdx.x;
    r_a[t] = expf(-fminf(fmaxf(dec_a[t], 0.f), 15.f));
    r_o[t] = expf(-fminf(fmaxf(dec_o[t], 0.f), 15.f));
    float acc = bq[t];
#pragma unroll 4
    for (int k = 0; k < NE; ++k) acc = fmaf(q_b[k], wq[k * NE + t], acc);
    b_qq[t] = acc;
}

__global__ __launch_bounds__(256) void k_wqq(const float* __restrict__ q_w,
                                             const float* __restrict__ wq,
                                             float* __restrict__ W_qq) {
    const int r = blockIdx.x >> 1;
    const int c = ((blockIdx.x & 1) << 8) + threadIdx.x;
    float acc = 0.f;
#pragma unroll 4
    for (int k = 0; k < NE; ++k) acc = fmaf(q_w[r * NE + k], wq[k * NE + c], acc);
    W_qq[r * NE + c] = acc;
}

__global__ __launch_bounds__(256) void k_woT(const float* __restrict__ wo,
                                             float* __restrict__ woT) {
    __shared__ float tile[64][65];
    const int te = blockIdx.x >> 3, tj = blockIdx.x & 7;
    for (int i = threadIdx.x; i < 4096; i += 256) {
        const int r = i >> 6, c = i & 63;
        tile[r][c] = wo[(size_t)(te * 64 + r) * NE + tj * 64 + c];
    }
    __syncthreads();
    for (int i = threadIdx.x; i < 4096; i += 256) {
        const int r = i >> 6, c = i & 63;
        woT[(size_t)(tj * 64 + r) * NE + te * 64 + c] = tile[c][r];
    }
}

__global__ __launch_bounds__(256) void k_woSyn(const float* __restrict__ woT,
                                               const float* __restrict__ syn_w,
                                               float* __restrict__ woSyn) {
    const int eg = blockIdx.x >> 6, ct = blockIdx.x & 63;
    const int c = ct * 64 + (threadIdx.x & 63);
    const int e0 = eg * 64 + __builtin_amdgcn_readfirstlane(threadIdx.x >> 6) * 16;
    float acc[16];
#pragma unroll
    for (int q = 0; q < 16; ++q) acc[q] = 0.f;
#pragma unroll 4
    for (int jp = 0; jp < NE; ++jp) {
        const float wv = syn_w[(size_t)jp * NOUT + c];
        const float* er = woT + (size_t)jp * NE + e0;
#pragma unroll
        for (int q = 0; q < 16; ++q) acc[q] = fmaf(er[q], wv, acc[q]);
    }
#pragma unroll
    for (int q = 0; q < 16; ++q)
        woSyn[(size_t)(e0 + q) * NOUT + c] = acc[q];
}

__global__ __launch_bounds__(256) void k_sbe(const float* __restrict__ syn_b,
                                             const float* __restrict__ bo,
                                             const float* __restrict__ syn_w,
                                             float* __restrict__ sbe) {
    const int c = blockIdx.x * 256 + threadIdx.x;
    float acc = syn_b[c];
#pragma unroll 4
    for (int jp = 0; jp < NE; ++jp)
        acc = fmaf(bo[jp], syn_w[(size_t)jp * NOUT + c], acc);
    sbe[c] = acc;
}

__global__ __launch_bounds__(256) void k_init_trace2(const float* __restrict__ st,
                                                     float* __restrict__ trace2) {
    const int idx = blockIdx.x * 256 + threadIdx.x;
    const int n = (idx >> 6) & (ND - 1);
    const int m = idx >> 17;
    trace2[idx] = st[n * NM + m];
}

// actT init + zero aA(2),bA(2),aO(2),bO(2),barCnt contiguous span.
// Ceil-div grid + guard (round-3 lesson: barCnt MUST be zeroed).
#define INIT_TOTAL (NB * ND + 8 * NB * NE + 64)
__global__ __launch_bounds__(256) void k_init_state(const float* __restrict__ sa,
                                                    float* __restrict__ actT,
                                                    float* __restrict__ zeroBase) {
    const int idx = blockIdx.x * 256 + threadIdx.x;
    if (idx >= INIT_TOTAL) return;
    if (idx < NB * ND) {
        const int b = idx & 63, n = idx >> 6;
        actT[n * NB + b] = sa[n];
    } else {
        zeroBase[idx - NB * ND] = 0.f;
    }
}

__global__ __launch_bounds__(512) void k_p1(const float* __restrict__ x,
                                            const float* __restrict__ kv_w,
                                            const float* __restrict__ kv_b,
                                            const float* __restrict__ ln_g,
                                            const float* __restrict__ ln_b,
                                            const float* __restrict__ wk,
                                            const float* __restrict__ bk,
                                            const float* __restrict__ wv,
                                            const float* __restrict__ bv,
                                            bf16_t* __restrict__ kp_t,
                                            bf16_t* __restrict__ vp_t) {
    __shared__ float kvS[NE];
    __shared__ float red[8];
    const int b = blockIdx.x >> 6, s = blockIdx.x & 63;
    const int e = threadIdx.x;
    float acc = kv_b[e];
#pragma unroll
    for (int c = 0; c < 12; ++c) acc = fmaf(x[b * 768 + c * 64 + s], kv_w[c * NE + e], acc);
    const float m = blockReduce<0>(acc, red) * (1.f / NE);
    const float d = acc - m;
    const float v = blockReduce<0>(d * d, red) * (1.f / NE);
    kvS[e] = d * rsqrtf(v + 1e-5f) * ln_g[e] + ln_b[e];
    __syncthreads();
    const int j = e;
    float kpv = bk[j], vpv = bv[j];
#pragma unroll 2
    for (int k = 0; k < NE; k += 4) {
        const float4 kv4 = *(const float4*)(kvS + k);
        kpv = fmaf(kv4.x, wk[(k + 0) * NE + j], kpv);
        kpv = fmaf(kv4.y, wk[(k + 1) * NE + j], kpv);
        kpv = fmaf(kv4.z, wk[(k + 2) * NE + j], kpv);
        kpv = fmaf(kv4.w, wk[(k + 3) * NE + j], kpv);
        vpv = fmaf(kv4.x, wv[(k + 0) * NE + j], vpv);
        vpv = fmaf(kv4.y, wv[(k + 1) * NE + j], vpv);
        vpv = fmaf(kv4.z, wv[(k + 2) * NE + j], vpv);
        vpv = fmaf(kv4.w, wv[(k + 3) * NE + j], vpv);
    }
    const int h = j >> 6, dd = j & 63;
    kp_t[((size_t)(b * NHEADS + h) * NDH + dd) * NS + s] = f2bf(kpv);
    vp_t[((size_t)(b * NHEADS + h) * NS + s) * NDH + dd] = f2bf(vpv);
}

__global__ __launch_bounds__(256) void k_w1t(const float* __restrict__ w1,
                                             float* __restrict__ w1t) {
    __shared__ float tile[64][65];
    const int m = blockIdx.x >> 5, n0 = (blockIdx.x & 31) << 6;
    for (int i = threadIdx.x; i < 4096; i += 256) {
        const int hh = i >> 6, nn = i & 63;
        tile[hh][nn] = w1[(size_t)(m * 64 + hh) * ND + n0 + nn];
    }
    __syncthreads();
    for (int i = threadIdx.x; i < 4096; i += 256) {
        const int nn = i >> 6, hh = i & 63;
        w1t[((size_t)(n0 + nn) * NM + m) * 64 + hh] = tile[hh][nn];
    }
}

__global__ __launch_bounds__(256) void k_w2t(const float* __restrict__ w2,
                                             float* __restrict__ w2t) {
    const int idx = blockIdx.x * 256 + threadIdx.x;
    const int i = idx & 31;
    const int c = (idx >> 5) & 1;
    const int n = idx >> 6;
    w2t[idx] = w2[(size_t)(i * 2 + c) * ND + n];
}

__global__ __launch_bounds__(256) void k_transpose(const float* __restrict__ predTemp,
                                                   float* __restrict__ out) {
    __shared__ float tile[NS * NITER];
    const int b = blockIdx.x >> 6;
    const int j0 = (blockIdx.x & 63) * 64;
    for (int i = threadIdx.x; i < 3200; i += 256) {
        const int tt = i >> 6, jj = i & 63;
        tile[jj * NITER + tt] = predTemp[((size_t)b * NITER + tt) * NOUT + j0 + jj];
    }
    __syncthreads();
    float* dst = out + ((size_t)b * NOUT + j0) * NITER;
    for (int i = threadIdx.x; i < 3200; i += 256) dst[i] = tile[i];
}

extern "C" void kernel_launch(void* const* d_in, const int* in_sizes, int n_in,
                              void* d_out, int out_size, void* d_ws, size_t ws_size,
                              hipStream_t stream) {
    const float* x        = (const float*)d_in[0];
    const float* kv_w     = (const float*)d_in[1];
    const float* kv_b     = (const float*)d_in[2];
    const float* kv_ln_g  = (const float*)d_in[3];
    const float* kv_ln_b  = (const float*)d_in[4];
    const float* q_w      = (const float*)d_in[5];
    const float* q_b      = (const float*)d_in[6];
    const float* wq       = (const float*)d_in[7];
    const float* wk       = (const float*)d_in[8];
    const float* wv       = (const float*)d_in[9];
    const float* wo       = (const float*)d_in[10];
    const float* bq       = (const float*)d_in[11];
    const float* bk       = (const float*)d_in[12];
    const float* bv       = (const float*)d_in[13];
    const float* bo       = (const float*)d_in[14];
    const float* syn_w    = (const float*)d_in[15];
    const float* syn_b    = (const float*)d_in[16];
    const float* syn_ln_g = (const float*)d_in[17];
    const float* syn_ln_b = (const float*)d_in[18];
    const float* nlm1_w   = (const float*)d_in[19];
    const float* nlm1_b   = (const float*)d_in[20];
    const float* nlm2_w   = (const float*)d_in[21];
    const float* nlm2_b   = (const float*)d_in[22];
    const float* start_a  = (const float*)d_in[23];
    const float* start_tr = (const float*)d_in[24];
    const float* dec_a    = (const float*)d_in[25];
    const float* dec_o    = (const float*)d_in[26];
    const float* out_w    = (const float*)d_in[27];
    const float* out_b    = (const float*)d_in[28];
    const int* ial        = (const int*)d_in[29];
    const int* iar        = (const int*)d_in[30];
    const int* iol        = (const int*)d_in[31];
    const int* ior        = (const int*)d_in[32];
    float* out = (float*)d_out;

    float* ws = (float*)d_ws;
    size_t off = 0;
    auto alloc = [&](size_t n) { float* p = ws + off; off += n; return p; };
    float* actT   = alloc((size_t)ND * NB);
    float* oT     = alloc((size_t)NE * NB);
    bf16_t* kp_t  = (bf16_t*)alloc((size_t)NB * NE * NS / 2);
    bf16_t* vp_t  = (bf16_t*)alloc((size_t)NB * NE * NS / 2);
    float* W_qq   = alloc((size_t)NE * NE);
    float* woT    = alloc((size_t)NE * NE);
    float* woSyn  = alloc((size_t)NE * NOUT);
    float* sbe    = alloc(NOUT);
    float* b_qq   = alloc(NE);
    float* r_a    = alloc(NE);
    float* r_o    = alloc(NE);
    float* aA     = alloc((size_t)2 * NB * NE);         // zero span start
    float* bA     = alloc((size_t)2 * NB * NE);
    float* aO     = alloc((size_t)2 * NB * NE);
    float* bO     = alloc((size_t)2 * NB * NE);
    float* barMem = alloc(64);                          // barrier counter
    float* trace2 = alloc((size_t)NM * ND * NB);
    float* part   = alloc((size_t)16 * NB * NOUT);
    float* w1t    = alloc((size_t)ND * NM * 64);
    float* w2t    = alloc((size_t)ND * 64);
    int tmode = 0;
    float* predTemp = nullptr;
    if ((off + (size_t)PRED_TOTAL) * sizeof(float) <= ws_size) {
        predTemp = alloc((size_t)PRED_TOTAL);
        tmode = 1;
    }

    k_p0<<<1, 512, 0, stream>>>(dec_a, dec_o, q_b, wq, bq, r_a, r_o, b_qq);
    k_wqq<<<1024, 256, 0, stream>>>(q_w, wq, W_qq);
    k_woT<<<64, 256, 0, stream>>>(wo, woT);
    k_woSyn<<<512, 256, 0, stream>>>(woT, syn_w, woSyn);
    k_sbe<<<16, 256, 0, stream>>>(syn_b, bo, syn_w, sbe);
    k_init_trace2<<<(NM * ND * NB) / 256, 256, 0, stream>>>(start_tr, trace2);
    k_init_state<<<(INIT_TOTAL + 255) / 256, 256, 0, stream>>>(start_a, actT, aA);
    k_p1<<<NB * NS, 512, 0, stream>>>(x, kv_w, kv_b, kv_ln_g, kv_ln_b, wk, bk, wv, bv, kp_t, vp_t);
    k_w1t<<<800, 256, 0, stream>>>(nlm1_w, w1t);
    k_w2t<<<(ND * 64) / 256, 256, 0, stream>>>(nlm2_w, w2t);

    CtmP cp;
    cp.W_qq = W_qq; cp.b_qq = b_qq; cp.r_a = r_a; cp.r_o = r_o;
    cp.kp_t = kp_t; cp.vp_t = vp_t;
    cp.woSyn = woSyn; cp.syn_w = syn_w; cp.sbe = sbe;
    cp.ln_g = syn_ln_g; cp.ln_b = syn_ln_b;
    cp.w1t = w1t; cp.b1 = nlm1_b; cp.w2t = w2t; cp.b2 = nlm2_b;
    cp.out_w = out_w; cp.out_b = out_b;
    cp.ial = ial; cp.iar = iar; cp.iol = iol; cp.ior = ior;
    cp.actT = actT; cp.oT = oT; cp.aA = aA; cp.bA = bA; cp.aO = aO; cp.bO = bO;
    cp.trace2 = trace2; cp.part = part; cp.predTemp = predTemp; cp.out = out;
    cp.barCnt = (unsigned*)barMem;
    cp.tmode = tmode;
    ctm_loop<<<NWG, NTHR, 0, stream>>>(cp);

    if (tmode) k_transpose<<<NB * 64, 256, 0, stream>>>(predTemp, out);
}

// Round 10
// 6739.808 us; speedup vs baseline: 3.2037x; 3.2037x over previous
//
#include <hip/hip_runtime.h>
#include <math.h>

#define NB 64
#define ND 2048
#define NE 512
#define NM 25
#define NOUT 4096
#define NHEADS 8
#define NDH 64
#define NS 64
#define NITER 50
#define NKSYN 2560
#define PRED_TOTAL (NB * NOUT * NITER)   /* 13107200 */

typedef unsigned short bf16_t;

__device__ __forceinline__ float sigm(float x) { return 1.f / (1.f + expf(-x)); }

__device__ __forceinline__ bf16_t f2bf(float f) {
    unsigned u = __float_as_uint(f);
    unsigned r = (u + 0x7FFFu + ((u >> 16) & 1u)) >> 16;
    return (bf16_t)r;
}
__device__ __forceinline__ float bf2f(bf16_t h) {
    return __uint_as_float(((unsigned)h) << 16);
}

__device__ __forceinline__ float wredsum(float v) {
#pragma unroll
    for (int o = 32; o; o >>= 1) v += __shfl_xor(v, o);
    return v;
}
__device__ __forceinline__ float wredmax(float v) {
#pragma unroll
    for (int o = 32; o; o >>= 1) v = fmaxf(v, __shfl_xor(v, o));
    return v;
}

template <int OP>
__device__ __forceinline__ float blockReduce(float v, float* red) {
    const int tid = threadIdx.x, lane = tid & 63, wid = tid >> 6;
    v = (OP == 0) ? wredsum(v) : wredmax(v);
    __syncthreads();
    if (lane == 0) red[wid] = v;
    __syncthreads();
    if (tid == 0) {
        const int nw = blockDim.x >> 6;
        float r = red[0];
        for (int w = 1; w < nw; ++w) r = (OP == 0) ? r + red[w] : fmaxf(r, red[w]);
        red[0] = r;
    }
    __syncthreads();
    return red[0];
}

// ---------------- per-step kernels ----------------

// KA: grid 256 (jt 4 x b 64) x 512. final(tt) on jt==0, then front(it).
__global__ __launch_bounds__(512) void k_front_final(
        const float* __restrict__ actT, float* __restrict__ oT,
        float* __restrict__ aA, float* __restrict__ bA,
        const float* __restrict__ r_a,
        const int* __restrict__ ial, const int* __restrict__ iar,
        const float* __restrict__ W_qq, const float* __restrict__ b_qq,
        const bf16_t* __restrict__ kp_t, const bf16_t* __restrict__ vp_t,
        const float* __restrict__ part, const float* __restrict__ out_b,
        float* __restrict__ out, float* __restrict__ predTemp,
        int doFront, int doFinal, int tt, int tmode, int it) {
    __shared__ float syncS[512];
    __shared__ float partK[512];
    __shared__ float qhS[128];
    __shared__ float attnS[128];
    __shared__ float red[8];
    const int bid = blockIdx.x;
    const int jt = bid >> 6, b = bid & 63;
    const int t = threadIdx.x;
    const int lane = t & 63, wv = t >> 6;

    if (doFinal && jt == 0) {
        float pr[8];
        float lmax = -1e30f;
#pragma unroll
        for (int c = 0; c < 8; ++c) {
            const int j = t + c * 512;
            float v = out_b[j];
#pragma unroll
            for (int kp = 0; kp < 8; ++kp) v += part[((size_t)(kp * NB + b)) * NOUT + j];
            pr[c] = v;
            lmax = fmaxf(lmax, v);
        }
        const float mx = blockReduce<1>(lmax, red);
        float ls = 0.f;
#pragma unroll
        for (int c = 0; c < 8; ++c) ls += expf(pr[c] - mx);
        const float se = blockReduce<0>(ls, red);
        const float logZ = mx + logf(se);
        float le = 0.f;
#pragma unroll
        for (int c = 0; c < 8; ++c) { const float lp = pr[c] - logZ; le += expf(lp) * lp; }
        const float ent = blockReduce<0>(le, red);
        const float ne = -ent * 0.12022458674074694f;  // 1/ln(4096)
        if (tmode) {
#pragma unroll
            for (int c = 0; c < 8; ++c)
                predTemp[((size_t)b * NITER + tt) * NOUT + t + c * 512] = pr[c];
        } else {
#pragma unroll
            for (int c = 0; c < 8; ++c) {
                const int j = t + c * 512;
                out[((size_t)b * NOUT + j) * NITER + tt] = pr[c];
            }
        }
        if (t == 0) {
            out[PRED_TOTAL + b * 100 + tt] = ne;
            out[PRED_TOTAL + b * 100 + 50 + tt] = 1.f - ne;
        }
    }
    if (!doFront) return;

    const int src = it & 1, dst = src ^ 1;
    // phase 1: action sync (all blocks compute; jt0 persists dbuf)
    {
        const int i = t;
        const float pl = actT[ial[i] * NB + b];
        const float prr = actT[iar[i] * NB + b];
        const float r = r_a[i];
        const float aN = r * aA[src * 32768 + b * NE + i] + pl * prr;
        const float bN = r * bA[src * 32768 + b * NE + i] + 1.f;
        if (jt == 0) {
            aA[dst * 32768 + b * NE + i] = aN;
            bA[dst * 32768 + b * NE + i] = bN;
        }
        syncS[i] = aN * rsqrtf(bN);
    }
    __syncthreads();
    // phase 2: qh j-slice [jt*128, +128), k split 4-way
    {
        const int g = t >> 7, l = t & 127;
        const int j = jt * 128 + l;
        float acc = 0.f;
        const int kk0 = g * 128;
#pragma unroll 4
        for (int k = kk0; k < kk0 + 128; ++k)
            acc = fmaf(syncS[k], W_qq[k * NE + j], acc);
        partK[g * 128 + l] = acc;
    }
    __syncthreads();
    if (t < 128) {
        qhS[t] = b_qq[jt * 128 + t] + partK[t] + partK[128 + t] + partK[256 + t] + partK[384 + t];
    }
    __syncthreads();
    // phase 3: scores + softmax for heads 2jt, 2jt+1 (waves 0-1)
    if (wv < 2) {
        const int h = jt * 2 + wv, s = lane;
        const bf16_t* kpp = kp_t + ((size_t)(b * NHEADS + h) * NDH) * NS + s;
        float sc = 0.f;
#pragma unroll 8
        for (int d = 0; d < NDH; ++d) sc = fmaf(qhS[wv * 64 + d], bf2f(kpp[d * NS]), sc);
        sc *= 0.125f;
        const float mxv = wredmax(sc);
        const float ev = expf(sc - mxv);
        const float sm = wredsum(ev);
        attnS[wv * 64 + s] = ev / sm;
    }
    __syncthreads();
    // phase 4: o = attn @ V -> oT[e][b]
    if (wv < 2) {
        const int h = jt * 2 + wv, d = lane;
        const bf16_t* vpp = vp_t + ((size_t)(b * NHEADS + h) * NS) * NDH + d;
        float o = 0.f;
#pragma unroll 8
        for (int s2 = 0; s2 < NS; ++s2) o = fmaf(attnS[wv * 64 + s2], bf2f(vpp[s2 * NDH]), o);
        oT[(size_t)(h * NDH + d) * NB + b] = o;
    }
}

// KB: syn GEMM partials, bf16 weights. grid 512 (kp 8 x jt 64) x 256.
// k<512: oT rows x bwoSyn (wo folded); else actT rows x bsynw.
__global__ __launch_bounds__(256, 4) void k_gemm_syn(const float* __restrict__ oT,
                                                     const float* __restrict__ actT,
                                                     const bf16_t* __restrict__ bwoSyn,
                                                     const bf16_t* __restrict__ bsynw,
                                                     float* __restrict__ part) {
    const int kp = blockIdx.x >> 6, jt = blockIdx.x & 63;
    const int j = jt * 64 + (threadIdx.x & 63);
    const int b0 = __builtin_amdgcn_readfirstlane(threadIdx.x >> 6) * 16;
    float acc[16];
#pragma unroll
    for (int q = 0; q < 16; ++q) acc[q] = 0.f;
    const int k0 = kp * 320;
#pragma unroll 4
    for (int k = k0; k < k0 + 320; ++k) {
        const bf16_t wraw = (k < NE) ? bwoSyn[(size_t)k * NOUT + j]
                                     : bsynw[(size_t)(k - NE) * NOUT + j];
        const float w = bf2f(wraw);
        const float* pk = (k < NE) ? (oT + k * NB + b0)
                                   : (actT + (k - NE) * NB + b0);   // uniform -> s_load
#pragma unroll
        for (int q = 0; q < 16; ++q) acc[q] = fmaf(pk[q], w, acc[q]);
    }
#pragma unroll
    for (int q = 0; q < 16; ++q)
        part[((size_t)(kp * NB + b0 + q)) * NOUT + j] = acc[q];
}

// KC: reduce 8 partials + bias_eff + GLU + LN -> trace2[pos]. grid 64 x 256.
__global__ __launch_bounds__(256) void k_glu_ln(const float* __restrict__ part,
                                                const float* __restrict__ sbe,
                                                const float* __restrict__ ln_g,
                                                const float* __restrict__ ln_b,
                                                float* __restrict__ trace2, int pos) {
    __shared__ float red[8];
    const int b = blockIdx.x;
    const int t = threadIdx.x;
    float g[8];
    float ssum = 0.f;
#pragma unroll
    for (int c = 0; c < 8; ++c) {
        const int n = t + c * 256;
        float ya = sbe[n], yb = sbe[n + ND];
#pragma unroll
        for (int kp = 0; kp < 8; ++kp) {
            ya += part[((size_t)(kp * NB + b)) * NOUT + n];
            yb += part[((size_t)(kp * NB + b)) * NOUT + n + ND];
        }
        g[c] = ya * sigm(yb);
        ssum += g[c];
    }
    const float mean = blockReduce<0>(ssum, red) * (1.f / ND);
    float vsum = 0.f;
#pragma unroll
    for (int c = 0; c < 8; ++c) { const float d = g[c] - mean; vsum += d * d; }
    const float var = blockReduce<0>(vsum, red) * (1.f / ND);
    const float rs = rsqrtf(var + 1e-5f);
#pragma unroll
    for (int c = 0; c < 8; ++c) {
        const int n = t + c * 256;
        const float st = (g[c] - mean) * rs * ln_g[n] + ln_b[n];
        trace2[((size_t)pos * ND + n) * NB + b] = st;
    }
}

// KD: per-neuron NLMs -> actT, bf16 w1. grid 512 x 256 (1 neuron/wave). lane=b.
// w1 dwords are wave-uniform -> s_load; unpack via scalar-friendly shifts.
__global__ __launch_bounds__(256, 2) void k_nlm(const float* __restrict__ trace2,
                                                const bf16_t* __restrict__ bw1t,
                                                const float* __restrict__ b1,
                                                const float* __restrict__ w2t,
                                                const float* __restrict__ b2,
                                                float* __restrict__ actT, int pos) {
    const int b = threadIdx.x & 63;
    const int wvu = __builtin_amdgcn_readfirstlane(threadIdx.x >> 6);
    const int n = blockIdx.x * 4 + wvu;                    // uniform per wave
    const float* brow = b1 + n * 64;
    float acc[64];
#pragma unroll
    for (int q = 0; q < 64; ++q) acc[q] = brow[q];
    int phys = (pos + 1 < NM) ? pos + 1 : 0;
    float tr = trace2[((size_t)phys * ND + n) * NB + b];
#pragma unroll 1
    for (int m = 0; m < NM; ++m) {
        const int physN = (phys + 1 < NM) ? phys + 1 : 0;
        float trn = 0.f;
        if (m + 1 < NM) trn = trace2[((size_t)physN * ND + n) * NB + b];
        const unsigned* wrow = (const unsigned*)(bw1t + ((size_t)n * NM + m) * 64);
#pragma unroll
        for (int q = 0; q < 32; ++q) {
            const unsigned u = wrow[q];                    // uniform -> s_load
            const float w0 = __uint_as_float(u << 16);
            const float w1 = __uint_as_float(u & 0xffff0000u);
            acc[2 * q + 0] = fmaf(tr, w0, acc[2 * q + 0]);
            acc[2 * q + 1] = fmaf(tr, w1, acc[2 * q + 1]);
        }
        tr = trn; phys = physN;
    }
    const float* w2r = w2t + n * 64;                        // uniform
    float z0 = b2[n * 2 + 0], z1 = b2[n * 2 + 1];
#pragma unroll
    for (int i = 0; i < 32; ++i) {
        const float hv = acc[i] * sigm(acc[32 + i]);
        z0 = fmaf(hv, w2r[i], z0);
        z1 = fmaf(hv, w2r[32 + i], z1);
    }
    actT[n * NB + b] = z0 * sigm(z1);
}

// KE: output sync + out GEMM partials, bf16 out_w. grid 512 (kp 8 x jt 64) x 256.
__global__ __launch_bounds__(256) void k_out(const float* __restrict__ actT,
                                             float* __restrict__ aO, float* __restrict__ bO,
                                             const float* __restrict__ r_o,
                                             const int* __restrict__ iol,
                                             const int* __restrict__ ior,
                                             const bf16_t* __restrict__ boutw,
                                             float* __restrict__ part, int it) {
    __shared__ float syncL[4096];  // [64 k][64 b]
    const int kp = blockIdx.x >> 6, jt = blockIdx.x & 63;
    const int t = threadIdx.x;
    const int src = it & 1, dst = src ^ 1;
#pragma unroll
    for (int c = 0; c < 16; ++c) {
        const int idx = t + c * 256;
        const int il = idx >> 6, b = idx & 63;
        const int i = kp * 64 + il;
        const float pl = actT[iol[i] * NB + b];
        const float prr = actT[ior[i] * NB + b];
        const float r = r_o[i];
        const float aN = r * aO[src * 32768 + i * NB + b] + pl * prr;
        const float bN = r * bO[src * 32768 + i * NB + b] + 1.f;
        if (jt == 0) {
            aO[dst * 32768 + i * NB + b] = aN;
            bO[dst * 32768 + i * NB + b] = bN;
        }
        syncL[il * 64 + b] = aN * rsqrtf(bN);
    }
    __syncthreads();
    const int b = t & 63;
    const int j0 = jt * 64 + __builtin_amdgcn_readfirstlane(t >> 6) * 16;
    float acc[16];
#pragma unroll
    for (int q = 0; q < 16; ++q) acc[q] = 0.f;
#pragma unroll 4
    for (int k = 0; k < 64; ++k) {
        const float sv = syncL[k * 64 + b];
        const unsigned* wrow = (const unsigned*)(boutw + (size_t)(kp * 64 + k) * NOUT + j0);
#pragma unroll
        for (int q = 0; q < 8; ++q) {
            const unsigned u = wrow[q];                    // uniform -> s_load
            const float w0 = __uint_as_float(u << 16);
            const float w1 = __uint_as_float(u & 0xffff0000u);
            acc[2 * q + 0] = fmaf(sv, w0, acc[2 * q + 0]);
            acc[2 * q + 1] = fmaf(sv, w1, acc[2 * q + 1]);
        }
    }
    float* dstp = part + ((size_t)(kp * NB + b)) * NOUT + j0;
#pragma unroll
    for (int q = 0; q < 16; ++q) dstp[q] = acc[q];
}

// ---------------- one-time precompute kernels ----------------

__global__ __launch_bounds__(512) void k_p0(const float* __restrict__ dec_a,
                                            const float* __restrict__ dec_o,
                                            const float* __restrict__ q_b,
                                            const float* __restrict__ wq,
                                            const float* __restrict__ bq,
                                            float* __restrict__ r_a, float* __restrict__ r_o,
                                            float* __restrict__ b_qq) {
    const int t = threadIdx.x;
    r_a[t] = expf(-fminf(fmaxf(dec_a[t], 0.f), 15.f));
    r_o[t] = expf(-fminf(fmaxf(dec_o[t], 0.f), 15.f));
    float acc = bq[t];
#pragma unroll 4
    for (int k = 0; k < NE; ++k) acc = fmaf(q_b[k], wq[k * NE + t], acc);
    b_qq[t] = acc;
}

__global__ __launch_bounds__(256) void k_wqq(const float* __restrict__ q_w,
                                             const float* __restrict__ wq,
                                             float* __restrict__ W_qq) {
    const int r = blockIdx.x >> 1;
    const int c = ((blockIdx.x & 1) << 8) + threadIdx.x;
    float acc = 0.f;
#pragma unroll 4
    for (int k = 0; k < NE; ++k) acc = fmaf(q_w[r * NE + k], wq[k * NE + c], acc);
    W_qq[r * NE + c] = acc;
}

__global__ __launch_bounds__(256) void k_woT(const float* __restrict__ wo,
                                             float* __restrict__ woT) {
    __shared__ float tile[64][65];
    const int te = blockIdx.x >> 3, tj = blockIdx.x & 7;
    for (int i = threadIdx.x; i < 4096; i += 256) {
        const int r = i >> 6, c = i & 63;
        tile[r][c] = wo[(size_t)(te * 64 + r) * NE + tj * 64 + c];
    }
    __syncthreads();
    for (int i = threadIdx.x; i < 4096; i += 256) {
        const int r = i >> 6, c = i & 63;
        woT[(size_t)(tj * 64 + r) * NE + te * 64 + c] = tile[c][r];
    }
}

// woSyn (bf16 out): woSyn[e][c] = sum_jp wo[e][jp]*syn_w[jp][c]
__global__ __launch_bounds__(256) void k_woSyn(const float* __restrict__ woT,
                                               const float* __restrict__ syn_w,
                                               bf16_t* __restrict__ bwoSyn) {
    const int eg = blockIdx.x >> 6, ct = blockIdx.x & 63;
    const int c = ct * 64 + (threadIdx.x & 63);
    const int e0 = eg * 64 + __builtin_amdgcn_readfirstlane(threadIdx.x >> 6) * 16;
    float acc[16];
#pragma unroll
    for (int q = 0; q < 16; ++q) acc[q] = 0.f;
#pragma unroll 4
    for (int jp = 0; jp < NE; ++jp) {
        const float wv = syn_w[(size_t)jp * NOUT + c];
        const float* er = woT + (size_t)jp * NE + e0;
#pragma unroll
        for (int q = 0; q < 16; ++q) acc[q] = fmaf(er[q], wv, acc[q]);
    }
#pragma unroll
    for (int q = 0; q < 16; ++q)
        bwoSyn[(size_t)(e0 + q) * NOUT + c] = f2bf(acc[q]);
}

__global__ __launch_bounds__(256) void k_sbe(const float* __restrict__ syn_b,
                                             const float* __restrict__ bo,
                                             const float* __restrict__ syn_w,
                                             float* __restrict__ sbe) {
    const int c = blockIdx.x * 256 + threadIdx.x;
    float acc = syn_b[c];
#pragma unroll 4
    for (int jp = 0; jp < NE; ++jp)
        acc = fmaf(bo[jp], syn_w[(size_t)jp * NOUT + c], acc);
    sbe[c] = acc;
}

// syn_w rows [512,2560) -> bf16
__global__ __launch_bounds__(256) void k_cvt_synw(const float* __restrict__ syn_w,
                                                  bf16_t* __restrict__ bsynw) {
    const size_t idx = (size_t)blockIdx.x * 256 + threadIdx.x;   // < 2048*4096
    bsynw[idx] = f2bf(syn_w[(size_t)NE * NOUT + idx]);
}

// out_w -> bf16
__global__ __launch_bounds__(256) void k_cvt_outw(const float* __restrict__ out_w,
                                                  bf16_t* __restrict__ boutw) {
    const size_t idx = (size_t)blockIdx.x * 256 + threadIdx.x;   // < 512*4096
    boutw[idx] = f2bf(out_w[idx]);
}

__global__ __launch_bounds__(256) void k_init_trace2(const float* __restrict__ st,
                                                     float* __restrict__ trace2) {
    const int idx = blockIdx.x * 256 + threadIdx.x;
    const int n = (idx >> 6) & (ND - 1);
    const int m = idx >> 17;
    trace2[idx] = st[n * NM + m];
}

#define INIT_TOTAL (NB * ND + 8 * NB * NE)
__global__ __launch_bounds__(256) void k_init_state(const float* __restrict__ sa,
                                                    float* __restrict__ actT,
                                                    float* __restrict__ zeroBase) {
    const int idx = blockIdx.x * 256 + threadIdx.x;
    if (idx >= INIT_TOTAL) return;
    if (idx < NB * ND) {
        const int b = idx & 63, n = idx >> 6;
        actT[n * NB + b] = sa[n];
    } else {
        zeroBase[idx - NB * ND] = 0.f;
    }
}

__global__ __launch_bounds__(512) void k_p1(const float* __restrict__ x,
                                            const float* __restrict__ kv_w,
                                            const float* __restrict__ kv_b,
                                            const float* __restrict__ ln_g,
                                            const float* __restrict__ ln_b,
                                            const float* __restrict__ wk,
                                            const float* __restrict__ bk,
                                            const float* __restrict__ wv,
                                            const float* __restrict__ bv,
                                            bf16_t* __restrict__ kp_t,
                                            bf16_t* __restrict__ vp_t) {
    __shared__ float kvS[NE];
    __shared__ float red[8];
    const int b = blockIdx.x >> 6, s = blockIdx.x & 63;
    const int e = threadIdx.x;
    float acc = kv_b[e];
#pragma unroll
    for (int c = 0; c < 12; ++c) acc = fmaf(x[b * 768 + c * 64 + s], kv_w[c * NE + e], acc);
    const float m = blockReduce<0>(acc, red) * (1.f / NE);
    const float d = acc - m;
    const float v = blockReduce<0>(d * d, red) * (1.f / NE);
    kvS[e] = d * rsqrtf(v + 1e-5f) * ln_g[e] + ln_b[e];
    __syncthreads();
    const int j = e;
    float kpv = bk[j], vpv = bv[j];
#pragma unroll 2
    for (int k = 0; k < NE; k += 4) {
        const float4 kv4 = *(const float4*)(kvS + k);
        kpv = fmaf(kv4.x, wk[(k + 0) * NE + j], kpv);
        kpv = fmaf(kv4.y, wk[(k + 1) * NE + j], kpv);
        kpv = fmaf(kv4.z, wk[(k + 2) * NE + j], kpv);
        kpv = fmaf(kv4.w, wk[(k + 3) * NE + j], kpv);
        vpv = fmaf(kv4.x, wv[(k + 0) * NE + j], vpv);
        vpv = fmaf(kv4.y, wv[(k + 1) * NE + j], vpv);
        vpv = fmaf(kv4.z, wv[(k + 2) * NE + j], vpv);
        vpv = fmaf(kv4.w, wv[(k + 3) * NE + j], vpv);
    }
    const int h = j >> 6, dd = j & 63;
    kp_t[((size_t)(b * NHEADS + h) * NDH + dd) * NS + s] = f2bf(kpv);
    vp_t[((size_t)(b * NHEADS + h) * NS + s) * NDH + dd] = f2bf(vpv);
}

// w1 (25,64,2048) -> bw1t[n][m][hh] (bf16), coalesced via LDS tile.
__global__ __launch_bounds__(256) void k_w1t(const float* __restrict__ w1,
                                             bf16_t* __restrict__ bw1t) {
    __shared__ float tile[64][65];
    const int m = blockIdx.x >> 5, n0 = (blockIdx.x & 31) << 6;
    for (int i = threadIdx.x; i < 4096; i += 256) {
        const int hh = i >> 6, nn = i & 63;
        tile[hh][nn] = w1[(size_t)(m * 64 + hh) * ND + n0 + nn];
    }
    __syncthreads();
    for (int i = threadIdx.x; i < 4096; i += 256) {
        const int nn = i >> 6, hh = i & 63;
        bw1t[((size_t)(n0 + nn) * NM + m) * 64 + hh] = f2bf(tile[hh][nn]);
    }
}

__global__ __launch_bounds__(256) void k_w2t(const float* __restrict__ w2,
                                             float* __restrict__ w2t) {
    const int idx = blockIdx.x * 256 + threadIdx.x;
    const int i = idx & 31;
    const int c = (idx >> 5) & 1;
    const int n = idx >> 6;
    w2t[idx] = w2[(size_t)(i * 2 + c) * ND + n];
}

__global__ __launch_bounds__(256) void k_transpose(const float* __restrict__ predTemp,
                                                   float* __restrict__ out) {
    __shared__ float tile[NS * NITER];
    const int b = blockIdx.x >> 6;
    const int j0 = (blockIdx.x & 63) * 64;
    for (int i = threadIdx.x; i < 3200; i += 256) {
        const int tt = i >> 6, jj = i & 63;
        tile[jj * NITER + tt] = predTemp[((size_t)b * NITER + tt) * NOUT + j0 + jj];
    }
    __syncthreads();
    float* dst = out + ((size_t)b * NOUT + j0) * NITER;
    for (int i = threadIdx.x; i < 3200; i += 256) dst[i] = tile[i];
}

extern "C" void kernel_launch(void* const* d_in, const int* in_sizes, int n_in,
                              void* d_out, int out_size, void* d_ws, size_t ws_size,
                              hipStream_t stream) {
    const float* x        = (const float*)d_in[0];
    const float* kv_w     = (const float*)d_in[1];
    const float* kv_b     = (const float*)d_in[2];
    const float* kv_ln_g  = (const float*)d_in[3];
    const float* kv_ln_b  = (const float*)d_in[4];
    const float* q_w      = (const float*)d_in[5];
    const float* q_b      = (const float*)d_in[6];
    const float* wq       = (const float*)d_in[7];
    const float* wk       = (const float*)d_in[8];
    const float* wv       = (const float*)d_in[9];
    const float* wo       = (const float*)d_in[10];
    const float* bq       = (const float*)d_in[11];
    const float* bk       = (const float*)d_in[12];
    const float* bv       = (const float*)d_in[13];
    const float* bo       = (const float*)d_in[14];
    const float* syn_w    = (const float*)d_in[15];
    const float* syn_b    = (const float*)d_in[16];
    const float* syn_ln_g = (const float*)d_in[17];
    const float* syn_ln_b = (const float*)d_in[18];
    const float* nlm1_w   = (const float*)d_in[19];
    const float* nlm1_b   = (const float*)d_in[20];
    const float* nlm2_w   = (const float*)d_in[21];
    const float* nlm2_b   = (const float*)d_in[22];
    const float* start_a  = (const float*)d_in[23];
    const float* start_tr = (const float*)d_in[24];
    const float* dec_a    = (const float*)d_in[25];
    const float* dec_o    = (const float*)d_in[26];
    const float* out_w    = (const float*)d_in[27];
    const float* out_b    = (const float*)d_in[28];
    const int* ial        = (const int*)d_in[29];
    const int* iar        = (const int*)d_in[30];
    const int* iol        = (const int*)d_in[31];
    const int* ior        = (const int*)d_in[32];
    float* out = (float*)d_out;

    float* ws = (float*)d_ws;
    size_t off = 0;
    auto alloc = [&](size_t n) { float* p = ws + off; off += n; return p; };
    float* actT    = alloc((size_t)ND * NB);            // 131072
    float* oT      = alloc((size_t)NE * NB);            // 32768
    bf16_t* kp_t   = (bf16_t*)alloc((size_t)NB * NE * NS / 2);
    bf16_t* vp_t   = (bf16_t*)alloc((size_t)NB * NE * NS / 2);
    float* W_qq    = alloc((size_t)NE * NE);            // 262144
    float* woT     = alloc((size_t)NE * NE);            // 262144 (prologue only)
    bf16_t* bwoSyn = (bf16_t*)alloc((size_t)NE * NOUT / 2);    // 1048576 f-slots
    bf16_t* bsynw  = (bf16_t*)alloc((size_t)(NKSYN - NE) * NOUT / 2);  // 4194304 f-slots
    bf16_t* boutw  = (bf16_t*)alloc((size_t)NE * NOUT / 2);
    bf16_t* bw1t   = (bf16_t*)alloc((size_t)ND * NM * 64 / 2); // 1638400 f-slots
    float* sbe     = alloc(NOUT);
    float* b_qq    = alloc(NE);
    float* r_a     = alloc(NE);
    float* r_o     = alloc(NE);
    float* aA      = alloc((size_t)2 * NB * NE);        // zero span start
    float* bA      = alloc((size_t)2 * NB * NE);
    float* aO      = alloc((size_t)2 * NB * NE);
    float* bO      = alloc((size_t)2 * NB * NE);
    float* trace2  = alloc((size_t)NM * ND * NB);       // 3276800
    float* part    = alloc((size_t)8 * NB * NOUT);      // 2097152 (shared syn/out)
    float* w2t     = alloc((size_t)ND * 64);            // 131072
    int tmode = 0;
    float* predTemp = nullptr;
    if ((off + (size_t)PRED_TOTAL) * sizeof(float) <= ws_size) {
        predTemp = alloc((size_t)PRED_TOTAL);
        tmode = 1;
    }

    k_p0<<<1, 512, 0, stream>>>(dec_a, dec_o, q_b, wq, bq, r_a, r_o, b_qq);
    k_wqq<<<1024, 256, 0, stream>>>(q_w, wq, W_qq);
    k_woT<<<64, 256, 0, stream>>>(wo, woT);
    k_woSyn<<<512, 256, 0, stream>>>(woT, syn_w, bwoSyn);
    k_sbe<<<16, 256, 0, stream>>>(syn_b, bo, syn_w, sbe);
    k_cvt_synw<<<(2048 * 4096) / 256, 256, 0, stream>>>(syn_w, bsynw);
    k_cvt_outw<<<(512 * 4096) / 256, 256, 0, stream>>>(out_w, boutw);
    k_init_trace2<<<(NM * ND * NB) / 256, 256, 0, stream>>>(start_tr, trace2);
    k_init_state<<<(INIT_TOTAL + 255) / 256, 256, 0, stream>>>(start_a, actT, aA);
    k_p1<<<NB * NS, 512, 0, stream>>>(x, kv_w, kv_b, kv_ln_g, kv_ln_b, wk, bk, wv, bv, kp_t, vp_t);
    k_w1t<<<800, 256, 0, stream>>>(nlm1_w, bw1t);
    k_w2t<<<(ND * 64) / 256, 256, 0, stream>>>(nlm2_w, w2t);

    for (int t = 0; t < NITER; ++t) {
        k_front_final<<<256, 512, 0, stream>>>(actT, oT, aA, bA, r_a, ial, iar, W_qq, b_qq,
                                               kp_t, vp_t, part, out_b, out, predTemp,
                                               1, (t > 0) ? 1 : 0, t - 1, tmode, t);
        k_gemm_syn<<<512, 256, 0, stream>>>(oT, actT, bwoSyn, bsynw, part);
        k_glu_ln<<<NB, 256, 0, stream>>>(part, sbe, syn_ln_g, syn_ln_b, trace2, t % NM);
        k_nlm<<<512, 256, 0, stream>>>(trace2, bw1t, nlm1_b, w2t, nlm2_b, actT, t % NM);
        k_out<<<512, 256, 0, stream>>>(actT, aO, bO, r_o, iol, ior, boutw, part, t);
    }
    // final entropy/prediction for t = 49
    k_front_final<<<256, 512, 0, stream>>>(actT, oT, aA, bA, r_a, ial, iar, W_qq, b_qq,
                                           kp_t, vp_t, part, out_b, out, predTemp,
                                           0, 1, NITER - 1, tmode, NITER);
    if (tmode) k_transpose<<<NB * 64, 256, 0, stream>>>(predTemp, out);
}

// Round 11
// 6158.482 us; speedup vs baseline: 3.5061x; 1.0944x over previous
//
#include <hip/hip_runtime.h>
#include <math.h>

#define NB 64
#define ND 2048
#define NE 512
#define NM 25
#define NOUT 4096
#define NHEADS 8
#define NDH 64
#define NS 64
#define NITER 50
#define NKSYN 2560
#define PRED_TOTAL (NB * NOUT * NITER)   /* 13107200 */

typedef unsigned short bf16_t;

__device__ __forceinline__ float sigm(float x) { return 1.f / (1.f + expf(-x)); }

__device__ __forceinline__ bf16_t f2bf(float f) {
    unsigned u = __float_as_uint(f);
    unsigned r = (u + 0x7FFFu + ((u >> 16) & 1u)) >> 16;
    return (bf16_t)r;
}
__device__ __forceinline__ float bf2f(bf16_t h) {
    return __uint_as_float(((unsigned)h) << 16);
}

__device__ __forceinline__ float wredsum(float v) {
#pragma unroll
    for (int o = 32; o; o >>= 1) v += __shfl_xor(v, o);
    return v;
}
__device__ __forceinline__ float wredmax(float v) {
#pragma unroll
    for (int o = 32; o; o >>= 1) v = fmaxf(v, __shfl_xor(v, o));
    return v;
}

template <int OP>
__device__ __forceinline__ float blockReduce(float v, float* red) {
    const int tid = threadIdx.x, lane = tid & 63, wid = tid >> 6;
    v = (OP == 0) ? wredsum(v) : wredmax(v);
    __syncthreads();
    if (lane == 0) red[wid] = v;
    __syncthreads();
    if (tid == 0) {
        const int nw = blockDim.x >> 6;
        float r = red[0];
        for (int w = 1; w < nw; ++w) r = (OP == 0) ? r + red[w] : fmaxf(r, red[w]);
        red[0] = r;
    }
    __syncthreads();
    return red[0];
}

// ---------------- per-step kernels (4 dispatches/step) ----------------

// OF: out(t-1) + front(t). grid 256 x 512.
// out: 2 units/block (unit = bid*2 + t>>8), kp 8 x jt 64 decomposition.
// front: jt = bid>>6 (0..3), b = bid&63; writes oT; jt0 persists aA/bA dbuf.
// Both consume actT(t-1) only -> independent, no internal ordering needed.
__global__ __launch_bounds__(512) void k_of(
        const float* __restrict__ actT, float* __restrict__ oT,
        float* __restrict__ aA, float* __restrict__ bA,
        const float* __restrict__ r_a,
        const int* __restrict__ ial, const int* __restrict__ iar,
        const float* __restrict__ W_qq, const float* __restrict__ b_qq,
        const bf16_t* __restrict__ kp_t, const bf16_t* __restrict__ vp_t,
        float* __restrict__ aO, float* __restrict__ bO,
        const float* __restrict__ r_o,
        const int* __restrict__ iol, const int* __restrict__ ior,
        const float* __restrict__ out_w, float* __restrict__ part_out,
        int doOut, int doFront, int it) {
    __shared__ float syncL[2][4096];
    __shared__ float syncS[512];
    __shared__ float partK[512];
    __shared__ float qhS[128];
    __shared__ float attnS[128];
    const int bid = blockIdx.x;
    const int t = threadIdx.x;
    const int lane = t & 63, wv = t >> 6;

    if (doOut) {
        const int itO = it - 1;
        const int srcO = itO & 1, dstO = srcO ^ 1;
        const int half = t >> 8, t2 = t & 255;
        const int unit = bid * 2 + half;
        const int kp = unit >> 6, jt2 = unit & 63;
        float* sL = syncL[half];
#pragma unroll
        for (int c = 0; c < 16; ++c) {
            const int idx = t2 + c * 256;
            const int il = idx >> 6, bb = idx & 63;
            const int i = kp * 64 + il;
            const float pl = actT[iol[i] * NB + bb];
            const float prr = actT[ior[i] * NB + bb];
            const float r = r_o[i];
            const float aN = r * aO[srcO * 32768 + i * NB + bb] + pl * prr;
            const float bN = r * bO[srcO * 32768 + i * NB + bb] + 1.f;
            if (jt2 == 0) {
                aO[dstO * 32768 + i * NB + bb] = aN;
                bO[dstO * 32768 + i * NB + bb] = bN;
            }
            sL[il * 64 + bb] = aN * rsqrtf(bN);
        }
        __syncthreads();
        const int bb = t2 & 63;
        const int j0 = jt2 * 64 + __builtin_amdgcn_readfirstlane((t2 >> 6) & 3) * 16;
        float acc[16];
#pragma unroll
        for (int q = 0; q < 16; ++q) acc[q] = 0.f;
#pragma unroll 4
        for (int k = 0; k < 64; ++k) {
            const float sv = sL[k * 64 + bb];
            const float* wrow = out_w + (size_t)(kp * 64 + k) * NOUT + j0;  // uniform
#pragma unroll
            for (int q = 0; q < 16; ++q) acc[q] = fmaf(sv, wrow[q], acc[q]);
        }
        float* dstp = part_out + ((size_t)(kp * NB + bb)) * NOUT + j0;
#pragma unroll
        for (int q = 0; q < 16; ++q) dstp[q] = acc[q];
    }
    if (!doFront) return;
    if (doOut) __syncthreads();

    const int jt = bid >> 6, b = bid & 63;
    const int src = it & 1, dst = src ^ 1;
    // front phase 1: action sync (all blocks compute; jt0 persists dbuf)
    {
        const int i = t;
        const float pl = actT[ial[i] * NB + b];
        const float prr = actT[iar[i] * NB + b];
        const float r = r_a[i];
        const float aN = r * aA[src * 32768 + b * NE + i] + pl * prr;
        const float bN = r * bA[src * 32768 + b * NE + i] + 1.f;
        if (jt == 0) {
            aA[dst * 32768 + b * NE + i] = aN;
            bA[dst * 32768 + b * NE + i] = bN;
        }
        syncS[i] = aN * rsqrtf(bN);
    }
    __syncthreads();
    // phase 2: qh j-slice [jt*128, +128), k split 4-way
    {
        const int g = t >> 7, l = t & 127;
        const int j = jt * 128 + l;
        float acc = 0.f;
        const int kk0 = g * 128;
#pragma unroll 4
        for (int k = kk0; k < kk0 + 128; ++k)
            acc = fmaf(syncS[k], W_qq[k * NE + j], acc);
        partK[g * 128 + l] = acc;
    }
    __syncthreads();
    if (t < 128) {
        qhS[t] = b_qq[jt * 128 + t] + partK[t] + partK[128 + t] + partK[256 + t] + partK[384 + t];
    }
    __syncthreads();
    // phase 3: scores + softmax for heads 2jt, 2jt+1 (waves 0-1)
    if (wv < 2) {
        const int h = jt * 2 + wv, s = lane;
        const bf16_t* kpp = kp_t + ((size_t)(b * NHEADS + h) * NDH) * NS + s;
        float sc = 0.f;
#pragma unroll 8
        for (int d = 0; d < NDH; ++d) sc = fmaf(qhS[wv * 64 + d], bf2f(kpp[d * NS]), sc);
        sc *= 0.125f;
        const float mxv = wredmax(sc);
        const float ev = expf(sc - mxv);
        const float sm = wredsum(ev);
        attnS[wv * 64 + s] = ev / sm;
    }
    __syncthreads();
    // phase 4: o = attn @ V -> oT[e][b]
    if (wv < 2) {
        const int h = jt * 2 + wv, d = lane;
        const bf16_t* vpp = vp_t + ((size_t)(b * NHEADS + h) * NS) * NDH + d;
        float o = 0.f;
#pragma unroll 8
        for (int s2 = 0; s2 < NS; ++s2) o = fmaf(attnS[wv * 64 + s2], bf2f(vpp[s2 * NDH]), o);
        oT[(size_t)(h * NDH + d) * NB + b] = o;
    }
}

// SF: synGEMM(t) on blocks <1024 + final(t-1) on blocks 1024..1087. grid 1088 x 256.
__global__ __launch_bounds__(256) void k_sf(
        const float* __restrict__ oT, const float* __restrict__ actT,
        const float* __restrict__ woSyn, const float* __restrict__ syn_w,
        float* __restrict__ part_syn,
        const float* __restrict__ part_out, const float* __restrict__ out_b,
        float* __restrict__ out, float* __restrict__ predTemp,
        int doGemm, int doFinal, int tt, int tmode) {
    const int bid = blockIdx.x;
    const int t = threadIdx.x;
    if (bid < 1024) {
        if (!doGemm) return;
        const int kp = bid >> 6, jt = bid & 63;
        const int j = jt * 64 + (t & 63);
        const int b0 = __builtin_amdgcn_readfirstlane(t >> 6) * 16;
        float acc[16];
#pragma unroll
        for (int q = 0; q < 16; ++q) acc[q] = 0.f;
        const int k0 = kp * 160;
#pragma unroll 4
        for (int k = k0; k < k0 + 160; ++k) {
            const float w = (k < NE) ? woSyn[(size_t)k * NOUT + j]
                                     : syn_w[(size_t)k * NOUT + j];
            const float* pk = (k < NE) ? (oT + k * NB + b0)
                                       : (actT + (k - NE) * NB + b0);   // uniform
#pragma unroll
            for (int q = 0; q < 16; ++q) acc[q] = fmaf(pk[q], w, acc[q]);
        }
#pragma unroll
        for (int q = 0; q < 16; ++q)
            part_syn[((size_t)(kp * NB + b0 + q)) * NOUT + j] = acc[q];
    } else {
        if (!doFinal) return;
        __shared__ float red[8];
        const int b = bid - 1024;
        float pr[16];
        float lmax = -1e30f;
#pragma unroll
        for (int c = 0; c < 16; ++c) {
            const int j = t + c * 256;
            float v = out_b[j];
#pragma unroll
            for (int kp = 0; kp < 8; ++kp) v += part_out[((size_t)(kp * NB + b)) * NOUT + j];
            pr[c] = v;
            lmax = fmaxf(lmax, v);
        }
        const float mx = blockReduce<1>(lmax, red);
        float ls = 0.f;
#pragma unroll
        for (int c = 0; c < 16; ++c) ls += expf(pr[c] - mx);
        const float se = blockReduce<0>(ls, red);
        const float logZ = mx + logf(se);
        float le = 0.f;
#pragma unroll
        for (int c = 0; c < 16; ++c) { const float lp = pr[c] - logZ; le += expf(lp) * lp; }
        const float ent = blockReduce<0>(le, red);
        const float ne = -ent * 0.12022458674074694f;  // 1/ln(4096)
        if (tmode) {
#pragma unroll
            for (int c = 0; c < 16; ++c)
                predTemp[((size_t)b * NITER + tt) * NOUT + t + c * 256] = pr[c];
        } else {
#pragma unroll
            for (int c = 0; c < 16; ++c) {
                const int j = t + c * 256;
                out[((size_t)b * NOUT + j) * NITER + tt] = pr[c];
            }
        }
        if (t == 0) {
            out[PRED_TOTAL + b * 100 + tt] = ne;
            out[PRED_TOTAL + b * 100 + 50 + tt] = 1.f - ne;
        }
    }
}

// KC: reduce 16 partials + bias_eff + GLU + LN -> trace2[pos]. grid 64 x 256.
__global__ __launch_bounds__(256) void k_glu_ln(const float* __restrict__ part,
                                                const float* __restrict__ sbe,
                                                const float* __restrict__ ln_g,
                                                const float* __restrict__ ln_b,
                                                float* __restrict__ trace2, int pos) {
    __shared__ float red[8];
    const int b = blockIdx.x;
    const int t = threadIdx.x;
    float g[8];
    float ssum = 0.f;
#pragma unroll
    for (int c = 0; c < 8; ++c) {
        const int n = t + c * 256;
        float ya = sbe[n], yb = sbe[n + ND];
#pragma unroll
        for (int kp = 0; kp < 16; ++kp) {
            ya += part[((size_t)(kp * NB + b)) * NOUT + n];
            yb += part[((size_t)(kp * NB + b)) * NOUT + n + ND];
        }
        g[c] = ya * sigm(yb);
        ssum += g[c];
    }
    const float mean = blockReduce<0>(ssum, red) * (1.f / ND);
    float vsum = 0.f;
#pragma unroll
    for (int c = 0; c < 8; ++c) { const float d = g[c] - mean; vsum += d * d; }
    const float var = blockReduce<0>(vsum, red) * (1.f / ND);
    const float rs = rsqrtf(var + 1e-5f);
#pragma unroll
    for (int c = 0; c < 8; ++c) {
        const int n = t + c * 256;
        const float st = (g[c] - mean) * rs * ln_g[n] + ln_b[n];
        trace2[((size_t)pos * ND + n) * NB + b] = st;
    }
}

// KD: per-neuron NLMs -> actT. grid 512 x 256 (1 neuron per wave). lane = b.
__global__ __launch_bounds__(256, 2) void k_nlm(const float* __restrict__ trace2,
                                                const float* __restrict__ w1t,
                                                const float* __restrict__ b1,
                                                const float* __restrict__ w2t,
                                                const float* __restrict__ b2,
                                                float* __restrict__ actT, int pos) {
    const int b = threadIdx.x & 63;
    const int wvu = __builtin_amdgcn_readfirstlane(threadIdx.x >> 6);
    const int n = blockIdx.x * 4 + wvu;                    // uniform per wave
    const float* brow = b1 + n * 64;
    float acc[64];
#pragma unroll
    for (int q = 0; q < 64; ++q) acc[q] = brow[q];
    int phys = (pos + 1 < NM) ? pos + 1 : 0;
    float tr = trace2[((size_t)phys * ND + n) * NB + b];
#pragma unroll 1
    for (int m = 0; m < NM; ++m) {
        const int physN = (phys + 1 < NM) ? phys + 1 : 0;
        float trn = 0.f;
        if (m + 1 < NM) trn = trace2[((size_t)physN * ND + n) * NB + b];
        const float* wrow = w1t + ((size_t)n * NM + m) * 64;   // uniform -> s_load
#pragma unroll
        for (int q = 0; q < 64; ++q) acc[q] = fmaf(tr, wrow[q], acc[q]);
        tr = trn; phys = physN;
    }
    const float* w2r = w2t + n * 64;                            // uniform
    float z0 = b2[n * 2 + 0], z1 = b2[n * 2 + 1];
#pragma unroll
    for (int i = 0; i < 32; ++i) {
        const float hv = acc[i] * sigm(acc[32 + i]);
        z0 = fmaf(hv, w2r[i], z0);
        z1 = fmaf(hv, w2r[32 + i], z1);
    }
    actT[n * NB + b] = z0 * sigm(z1);
}

// ---------------- one-time precompute kernels ----------------

__global__ __launch_bounds__(512) void k_p0(const float* __restrict__ dec_a,
                                            const float* __restrict__ dec_o,
                                            const float* __restrict__ q_b,
                                            const float* __restrict__ wq,
                                            const float* __restrict__ bq,
                                            float* __restrict__ r_a, float* __restrict__ r_o,
                                            float* __restrict__ b_qq) {
    const int t = threadIdx.x;
    r_a[t] = expf(-fminf(fmaxf(dec_a[t], 0.f), 15.f));
    r_o[t] = expf(-fminf(fmaxf(dec_o[t], 0.f), 15.f));
    float acc = bq[t];
#pragma unroll 4
    for (int k = 0; k < NE; ++k) acc = fmaf(q_b[k], wq[k * NE + t], acc);
    b_qq[t] = acc;
}

__global__ __launch_bounds__(256) void k_wqq(const float* __restrict__ q_w,
                                             const float* __restrict__ wq,
                                             float* __restrict__ W_qq) {
    const int r = blockIdx.x >> 1;
    const int c = ((blockIdx.x & 1) << 8) + threadIdx.x;
    float acc = 0.f;
#pragma unroll 4
    for (int k = 0; k < NE; ++k) acc = fmaf(q_w[r * NE + k], wq[k * NE + c], acc);
    W_qq[r * NE + c] = acc;
}

__global__ __launch_bounds__(256) void k_woT(const float* __restrict__ wo,
                                             float* __restrict__ woT) {
    __shared__ float tile[64][65];
    const int te = blockIdx.x >> 3, tj = blockIdx.x & 7;
    for (int i = threadIdx.x; i < 4096; i += 256) {
        const int r = i >> 6, c = i & 63;
        tile[r][c] = wo[(size_t)(te * 64 + r) * NE + tj * 64 + c];
    }
    __syncthreads();
    for (int i = threadIdx.x; i < 4096; i += 256) {
        const int r = i >> 6, c = i & 63;
        woT[(size_t)(tj * 64 + r) * NE + te * 64 + c] = tile[c][r];
    }
}

__global__ __launch_bounds__(256) void k_woSyn(const float* __restrict__ woT,
                                               const float* __restrict__ syn_w,
                                               float* __restrict__ woSyn) {
    const int eg = blockIdx.x >> 6, ct = blockIdx.x & 63;
    const int c = ct * 64 + (threadIdx.x & 63);
    const int e0 = eg * 64 + __builtin_amdgcn_readfirstlane(threadIdx.x >> 6) * 16;
    float acc[16];
#pragma unroll
    for (int q = 0; q < 16; ++q) acc[q] = 0.f;
#pragma unroll 4
    for (int jp = 0; jp < NE; ++jp) {
        const float wv = syn_w[(size_t)jp * NOUT + c];
        const float* er = woT + (size_t)jp * NE + e0;
#pragma unroll
        for (int q = 0; q < 16; ++q) acc[q] = fmaf(er[q], wv, acc[q]);
    }
#pragma unroll
    for (int q = 0; q < 16; ++q)
        woSyn[(size_t)(e0 + q) * NOUT + c] = acc[q];
}

__global__ __launch_bounds__(256) void k_sbe(const float* __restrict__ syn_b,
                                             const float* __restrict__ bo,
                                             const float* __restrict__ syn_w,
                                             float* __restrict__ sbe) {
    const int c = blockIdx.x * 256 + threadIdx.x;
    float acc = syn_b[c];
#pragma unroll 4
    for (int jp = 0; jp < NE; ++jp)
        acc = fmaf(bo[jp], syn_w[(size_t)jp * NOUT + c], acc);
    sbe[c] = acc;
}

__global__ __launch_bounds__(256) void k_init_trace2(const float* __restrict__ st,
                                                     float* __restrict__ trace2) {
    const int idx = blockIdx.x * 256 + threadIdx.x;
    const int n = (idx >> 6) & (ND - 1);
    const int m = idx >> 17;
    trace2[idx] = st[n * NM + m];
}

#define INIT_TOTAL (NB * ND + 8 * NB * NE)
__global__ __launch_bounds__(256) void k_init_state(const float* __restrict__ sa,
                                                    float* __restrict__ actT,
                                                    float* __restrict__ zeroBase) {
    const int idx = blockIdx.x * 256 + threadIdx.x;
    if (idx >= INIT_TOTAL) return;
    if (idx < NB * ND) {
        const int b = idx & 63, n = idx >> 6;
        actT[n * NB + b] = sa[n];
    } else {
        zeroBase[idx - NB * ND] = 0.f;
    }
}

__global__ __launch_bounds__(512) void k_p1(const float* __restrict__ x,
                                            const float* __restrict__ kv_w,
                                            const float* __restrict__ kv_b,
                                            const float* __restrict__ ln_g,
                                            const float* __restrict__ ln_b,
                                            const float* __restrict__ wk,
                                            const float* __restrict__ bk,
                                            const float* __restrict__ wv,
                                            const float* __restrict__ bv,
                                            bf16_t* __restrict__ kp_t,
                                            bf16_t* __restrict__ vp_t) {
    __shared__ float kvS[NE];
    __shared__ float red[8];
    const int b = blockIdx.x >> 6, s = blockIdx.x & 63;
    const int e = threadIdx.x;
    float acc = kv_b[e];
#pragma unroll
    for (int c = 0; c < 12; ++c) acc = fmaf(x[b * 768 + c * 64 + s], kv_w[c * NE + e], acc);
    const float m = blockReduce<0>(acc, red) * (1.f / NE);
    const float d = acc - m;
    const float v = blockReduce<0>(d * d, red) * (1.f / NE);
    kvS[e] = d * rsqrtf(v + 1e-5f) * ln_g[e] + ln_b[e];
    __syncthreads();
    const int j = e;
    float kpv = bk[j], vpv = bv[j];
#pragma unroll 2
    for (int k = 0; k < NE; k += 4) {
        const float4 kv4 = *(const float4*)(kvS + k);
        kpv = fmaf(kv4.x, wk[(k + 0) * NE + j], kpv);
        kpv = fmaf(kv4.y, wk[(k + 1) * NE + j], kpv);
        kpv = fmaf(kv4.z, wk[(k + 2) * NE + j], kpv);
        kpv = fmaf(kv4.w, wk[(k + 3) * NE + j], kpv);
        vpv = fmaf(kv4.x, wv[(k + 0) * NE + j], vpv);
        vpv = fmaf(kv4.y, wv[(k + 1) * NE + j], vpv);
        vpv = fmaf(kv4.z, wv[(k + 2) * NE + j], vpv);
        vpv = fmaf(kv4.w, wv[(k + 3) * NE + j], vpv);
    }
    const int h = j >> 6, dd = j & 63;
    kp_t[((size_t)(b * NHEADS + h) * NDH + dd) * NS + s] = f2bf(kpv);
    vp_t[((size_t)(b * NHEADS + h) * NS + s) * NDH + dd] = f2bf(vpv);
}

__global__ __launch_bounds__(256) void k_w1t(const float* __restrict__ w1,
                                             float* __restrict__ w1t) {
    __shared__ float tile[64][65];
    const int m = blockIdx.x >> 5, n0 = (blockIdx.x & 31) << 6;
    for (int i = threadIdx.x; i < 4096; i += 256) {
        const int hh = i >> 6, nn = i & 63;
        tile[hh][nn] = w1[(size_t)(m * 64 + hh) * ND + n0 + nn];
    }
    __syncthreads();
    for (int i = threadIdx.x; i < 4096; i += 256) {
        const int nn = i >> 6, hh = i & 63;
        w1t[((size_t)(n0 + nn) * NM + m) * 64 + hh] = tile[hh][nn];
    }
}

__global__ __launch_bounds__(256) void k_w2t(const float* __restrict__ w2,
                                             float* __restrict__ w2t) {
    const int idx = blockIdx.x * 256 + threadIdx.x;
    const int i = idx & 31;
    const int c = (idx >> 5) & 1;
    const int n = idx >> 6;
    w2t[idx] = w2[(size_t)(i * 2 + c) * ND + n];
}

__global__ __launch_bounds__(256) void k_transpose(const float* __restrict__ predTemp,
                                                   float* __restrict__ out) {
    __shared__ float tile[NS * NITER];
    const int b = blockIdx.x >> 6;
    const int j0 = (blockIdx.x & 63) * 64;
    for (int i = threadIdx.x; i < 3200; i += 256) {
        const int tt = i >> 6, jj = i & 63;
        tile[jj * NITER + tt] = predTemp[((size_t)b * NITER + tt) * NOUT + j0 + jj];
    }
    __syncthreads();
    float* dst = out + ((size_t)b * NOUT + j0) * NITER;
    for (int i = threadIdx.x; i < 3200; i += 256) dst[i] = tile[i];
}

extern "C" void kernel_launch(void* const* d_in, const int* in_sizes, int n_in,
                              void* d_out, int out_size, void* d_ws, size_t ws_size,
                              hipStream_t stream) {
    const float* x        = (const float*)d_in[0];
    const float* kv_w     = (const float*)d_in[1];
    const float* kv_b     = (const float*)d_in[2];
    const float* kv_ln_g  = (const float*)d_in[3];
    const float* kv_ln_b  = (const float*)d_in[4];
    const float* q_w      = (const float*)d_in[5];
    const float* q_b      = (const float*)d_in[6];
    const float* wq       = (const float*)d_in[7];
    const float* wk       = (const float*)d_in[8];
    const float* wv       = (const float*)d_in[9];
    const float* wo       = (const float*)d_in[10];
    const float* bq       = (const float*)d_in[11];
    const float* bk       = (const float*)d_in[12];
    const float* bv       = (const float*)d_in[13];
    const float* bo       = (const float*)d_in[14];
    const float* syn_w    = (const float*)d_in[15];
    const float* syn_b    = (const float*)d_in[16];
    const float* syn_ln_g = (const float*)d_in[17];
    const float* syn_ln_b = (const float*)d_in[18];
    const float* nlm1_w   = (const float*)d_in[19];
    const float* nlm1_b   = (const float*)d_in[20];
    const float* nlm2_w   = (const float*)d_in[21];
    const float* nlm2_b   = (const float*)d_in[22];
    const float* start_a  = (const float*)d_in[23];
    const float* start_tr = (const float*)d_in[24];
    const float* dec_a    = (const float*)d_in[25];
    const float* dec_o    = (const float*)d_in[26];
    const float* out_w    = (const float*)d_in[27];
    const float* out_b    = (const float*)d_in[28];
    const int* ial        = (const int*)d_in[29];
    const int* iar        = (const int*)d_in[30];
    const int* iol        = (const int*)d_in[31];
    const int* ior        = (const int*)d_in[32];
    float* out = (float*)d_out;

    float* ws = (float*)d_ws;
    size_t off = 0;
    auto alloc = [&](size_t n) { float* p = ws + off; off += n; return p; };
    float* actT     = alloc((size_t)ND * NB);
    float* oT       = alloc((size_t)NE * NB);
    bf16_t* kp_t    = (bf16_t*)alloc((size_t)NB * NE * NS / 2);
    bf16_t* vp_t    = (bf16_t*)alloc((size_t)NB * NE * NS / 2);
    float* W_qq     = alloc((size_t)NE * NE);
    float* woT      = alloc((size_t)NE * NE);
    float* woSyn    = alloc((size_t)NE * NOUT);
    float* sbe      = alloc(NOUT);
    float* b_qq     = alloc(NE);
    float* r_a      = alloc(NE);
    float* r_o      = alloc(NE);
    float* aA       = alloc((size_t)2 * NB * NE);       // zero span start
    float* bA       = alloc((size_t)2 * NB * NE);
    float* aO       = alloc((size_t)2 * NB * NE);
    float* bO       = alloc((size_t)2 * NB * NE);
    float* trace2   = alloc((size_t)NM * ND * NB);
    float* part_syn = alloc((size_t)16 * NB * NOUT);    // 4194304
    float* part_out = alloc((size_t)8 * NB * NOUT);     // 2097152
    float* w1t      = alloc((size_t)ND * NM * 64);
    float* w2t      = alloc((size_t)ND * 64);
    int tmode = 0;
    float* predTemp = nullptr;
    if ((off + (size_t)PRED_TOTAL) * sizeof(float) <= ws_size) {
        predTemp = alloc((size_t)PRED_TOTAL);
        tmode = 1;
    }

    k_p0<<<1, 512, 0, stream>>>(dec_a, dec_o, q_b, wq, bq, r_a, r_o, b_qq);
    k_wqq<<<1024, 256, 0, stream>>>(q_w, wq, W_qq);
    k_woT<<<64, 256, 0, stream>>>(wo, woT);
    k_woSyn<<<512, 256, 0, stream>>>(woT, syn_w, woSyn);
    k_sbe<<<16, 256, 0, stream>>>(syn_b, bo, syn_w, sbe);
    k_init_trace2<<<(NM * ND * NB) / 256, 256, 0, stream>>>(start_tr, trace2);
    k_init_state<<<(INIT_TOTAL + 255) / 256, 256, 0, stream>>>(start_a, actT, aA);
    k_p1<<<NB * NS, 512, 0, stream>>>(x, kv_w, kv_b, kv_ln_g, kv_ln_b, wk, bk, wv, bv, kp_t, vp_t);
    k_w1t<<<800, 256, 0, stream>>>(nlm1_w, w1t);
    k_w2t<<<(ND * 64) / 256, 256, 0, stream>>>(nlm2_w, w2t);

    for (int t = 0; t < NITER; ++t) {
        k_of<<<256, 512, 0, stream>>>(actT, oT, aA, bA, r_a, ial, iar, W_qq, b_qq,
                                      kp_t, vp_t, aO, bO, r_o, iol, ior, out_w, part_out,
                                      (t > 0) ? 1 : 0, 1, t);
        k_sf<<<1088, 256, 0, stream>>>(oT, actT, woSyn, syn_w, part_syn,
                                       part_out, out_b, out, predTemp,
                                       1, (t > 0) ? 1 : 0, t - 1, tmode);
        k_glu_ln<<<NB, 256, 0, stream>>>(part_syn, sbe, syn_ln_g, syn_ln_b, trace2, t % NM);
        k_nlm<<<512, 256, 0, stream>>>(trace2, w1t, nlm1_b, w2t, nlm2_b, actT, t % NM);
    }
    // tail: out(49) then final(49)
    k_of<<<256, 512, 0, stream>>>(actT, oT, aA, bA, r_a, ial, iar, W_qq, b_qq,
                                  kp_t, vp_t, aO, bO, r_o, iol, ior, out_w, part_out,
                                  1, 0, NITER);
    k_sf<<<1088, 256, 0, stream>>>(oT, actT, woSyn, syn_w, part_syn,
                                   part_out, out_b, out, predTemp,
                                   0, 1, NITER - 1, tmode);
    if (tmode) k_transpose<<<NB * 64, 256, 0, stream>>>(predTemp, out);
}

// Round 12
// 5608.613 us; speedup vs baseline: 3.8498x; 1.0980x over previous
//
#include <hip/hip_runtime.h>
#include <math.h>

#define NB 64
#define ND 2048
#define NE 512
#define NM 25
#define NOUT 4096
#define NHEADS 8
#define NDH 64
#define NS 64
#define NITER 50
#define NKSYN 2560
#define PRED_TOTAL (NB * NOUT * NITER)   /* 13107200 */

typedef unsigned short bf16_t;

__device__ __forceinline__ float sigm(float x) { return 1.f / (1.f + expf(-x)); }

__device__ __forceinline__ bf16_t f2bf(float f) {
    unsigned u = __float_as_uint(f);
    unsigned r = (u + 0x7FFFu + ((u >> 16) & 1u)) >> 16;
    return (bf16_t)r;
}
__device__ __forceinline__ float bf2f(bf16_t h) {
    return __uint_as_float(((unsigned)h) << 16);
}

__device__ __forceinline__ float wredsum(float v) {
#pragma unroll
    for (int o = 32; o; o >>= 1) v += __shfl_xor(v, o);
    return v;
}
__device__ __forceinline__ float wredmax(float v) {
#pragma unroll
    for (int o = 32; o; o >>= 1) v = fmaxf(v, __shfl_xor(v, o));
    return v;
}

template <int OP>
__device__ __forceinline__ float blockReduce(float v, float* red) {
    const int tid = threadIdx.x, lane = tid & 63, wid = tid >> 6;
    v = (OP == 0) ? wredsum(v) : wredmax(v);
    __syncthreads();
    if (lane == 0) red[wid] = v;
    __syncthreads();
    if (tid == 0) {
        const int nw = blockDim.x >> 6;
        float r = red[0];
        for (int w = 1; w < nw; ++w) r = (OP == 0) ? r + red[w] : fmaxf(r, red[w]);
        red[0] = r;
    }
    __syncthreads();
    return red[0];
}

// ---------------- per-step kernels (r8 structure, 5 dispatches/step) --------

// KA: grid 256 (jt 4 x b 64) x 512. final(tt) on jt==0 blocks first, then front.
__global__ __launch_bounds__(512) void k_front_final(
        const float* __restrict__ actT, float* __restrict__ oT,
        float* __restrict__ aA, float* __restrict__ bA,
        const float* __restrict__ r_a,
        const int* __restrict__ ial, const int* __restrict__ iar,
        const float* __restrict__ W_qq, const float* __restrict__ b_qq,
        const bf16_t* __restrict__ kp_t, const bf16_t* __restrict__ vp_t,
        const float* __restrict__ part, const float* __restrict__ out_b,
        float* __restrict__ out, float* __restrict__ predTemp,
        int doFront, int doFinal, int tt, int tmode, int it) {
    __shared__ float syncS[512];
    __shared__ float partK[512];
    __shared__ float qhS[128];
    __shared__ float attnS[128];
    __shared__ float red[8];
    const int bid = blockIdx.x;
    const int jt = bid >> 6, b = bid & 63;
    const int t = threadIdx.x;
    const int lane = t & 63, wv = t >> 6;

    if (doFinal && jt == 0) {
        float pr[8];
        float lmax = -1e30f;
#pragma unroll
        for (int c = 0; c < 8; ++c) {
            const int j = t + c * 512;
            float v = out_b[j];
#pragma unroll
            for (int kp = 0; kp < 8; ++kp) v += part[((size_t)(kp * NB + b)) * NOUT + j];
            pr[c] = v;
            lmax = fmaxf(lmax, v);
        }
        const float mx = blockReduce<1>(lmax, red);
        float ls = 0.f;
#pragma unroll
        for (int c = 0; c < 8; ++c) ls += expf(pr[c] - mx);
        const float se = blockReduce<0>(ls, red);
        const float logZ = mx + logf(se);
        float le = 0.f;
#pragma unroll
        for (int c = 0; c < 8; ++c) { const float lp = pr[c] - logZ; le += expf(lp) * lp; }
        const float ent = blockReduce<0>(le, red);
        const float ne = -ent * 0.12022458674074694f;  // 1/ln(4096)
        if (tmode) {
#pragma unroll
            for (int c = 0; c < 8; ++c)
                predTemp[((size_t)b * NITER + tt) * NOUT + t + c * 512] = pr[c];
        } else {
#pragma unroll
            for (int c = 0; c < 8; ++c) {
                const int j = t + c * 512;
                out[((size_t)b * NOUT + j) * NITER + tt] = pr[c];
            }
        }
        if (t == 0) {
            out[PRED_TOTAL + b * 100 + tt] = ne;
            out[PRED_TOTAL + b * 100 + 50 + tt] = 1.f - ne;
        }
    }
    if (!doFront) return;

    const int src = it & 1, dst = src ^ 1;
    // phase 1: action sync (all blocks compute; jt0 persists dbuf)
    {
        const int i = t;
        const float pl = actT[ial[i] * NB + b];
        const float prr = actT[iar[i] * NB + b];
        const float r = r_a[i];
        const float aN = r * aA[src * 32768 + b * NE + i] + pl * prr;
        const float bN = r * bA[src * 32768 + b * NE + i] + 1.f;
        if (jt == 0) {
            aA[dst * 32768 + b * NE + i] = aN;
            bA[dst * 32768 + b * NE + i] = bN;
        }
        syncS[i] = aN * rsqrtf(bN);
    }
    __syncthreads();
    // phase 2: qh j-slice [jt*128, +128), k split 4-way
    {
        const int g = t >> 7, l = t & 127;
        const int j = jt * 128 + l;
        float acc = 0.f;
        const int kk0 = g * 128;
#pragma unroll 4
        for (int k = kk0; k < kk0 + 128; ++k)
            acc = fmaf(syncS[k], W_qq[k * NE + j], acc);
        partK[g * 128 + l] = acc;
    }
    __syncthreads();
    if (t < 128) {
        qhS[t] = b_qq[jt * 128 + t] + partK[t] + partK[128 + t] + partK[256 + t] + partK[384 + t];
    }
    __syncthreads();
    // phase 3: scores + softmax for heads 2jt, 2jt+1 (waves 0-1)
    if (wv < 2) {
        const int h = jt * 2 + wv, s = lane;
        const bf16_t* kpp = kp_t + ((size_t)(b * NHEADS + h) * NDH) * NS + s;
        float sc = 0.f;
#pragma unroll 8
        for (int d = 0; d < NDH; ++d) sc = fmaf(qhS[wv * 64 + d], bf2f(kpp[d * NS]), sc);
        sc *= 0.125f;
        const float mxv = wredmax(sc);
        const float ev = expf(sc - mxv);
        const float sm = wredsum(ev);
        attnS[wv * 64 + s] = ev / sm;
    }
    __syncthreads();
    // phase 4: o = attn @ V -> oT[e][b]
    if (wv < 2) {
        const int h = jt * 2 + wv, d = lane;
        const bf16_t* vpp = vp_t + ((size_t)(b * NHEADS + h) * NS) * NDH + d;
        float o = 0.f;
#pragma unroll 8
        for (int s2 = 0; s2 < NS; ++s2) o = fmaf(attnS[wv * 64 + s2], bf2f(vpp[s2 * NDH]), o);
        oT[(size_t)(h * NDH + d) * NB + b] = o;
    }
}

// KB: syn GEMM partials. grid 1024 (kp 16 x jt 64) x 256, 4 blocks/CU.
__global__ __launch_bounds__(256, 4) void k_gemm_syn(const float* __restrict__ oT,
                                                     const float* __restrict__ actT,
                                                     const float* __restrict__ woSyn,
                                                     const float* __restrict__ syn_w,
                                                     float* __restrict__ part) {
    const int kp = blockIdx.x >> 6, jt = blockIdx.x & 63;
    const int j = jt * 64 + (threadIdx.x & 63);
    const int b0 = __builtin_amdgcn_readfirstlane(threadIdx.x >> 6) * 16;
    float acc[16];
#pragma unroll
    for (int q = 0; q < 16; ++q) acc[q] = 0.f;
    const int k0 = kp * 160;
#pragma unroll 4
    for (int k = k0; k < k0 + 160; ++k) {
        const float w = (k < NE) ? woSyn[(size_t)k * NOUT + j]
                                 : syn_w[(size_t)k * NOUT + j];
        const float* pk = (k < NE) ? (oT + k * NB + b0)
                                   : (actT + (k - NE) * NB + b0);   // uniform -> s_load
#pragma unroll
        for (int q = 0; q < 16; ++q) acc[q] = fmaf(pk[q], w, acc[q]);
    }
#pragma unroll
    for (int q = 0; q < 16; ++q)
        part[((size_t)(kp * NB + b0 + q)) * NOUT + j] = acc[q];
}

// KC: reduce 16 partials + bias_eff + GLU + LN -> trace2[pos]. grid 64 x 512.
__global__ __launch_bounds__(512) void k_glu_ln(const float* __restrict__ part,
                                                const float* __restrict__ sbe,
                                                const float* __restrict__ ln_g,
                                                const float* __restrict__ ln_b,
                                                float* __restrict__ trace2, int pos) {
    __shared__ float red[8];
    const int b = blockIdx.x;
    const int t = threadIdx.x;
    float g[4];
    float ssum = 0.f;
#pragma unroll
    for (int c = 0; c < 4; ++c) {
        const int n = t + c * 512;
        float ya = sbe[n], yb = sbe[n + ND];
#pragma unroll
        for (int kp = 0; kp < 16; ++kp) {
            ya += part[((size_t)(kp * NB + b)) * NOUT + n];
            yb += part[((size_t)(kp * NB + b)) * NOUT + n + ND];
        }
        g[c] = ya * sigm(yb);
        ssum += g[c];
    }
    const float mean = blockReduce<0>(ssum, red) * (1.f / ND);
    float vsum = 0.f;
#pragma unroll
    for (int c = 0; c < 4; ++c) { const float d = g[c] - mean; vsum += d * d; }
    const float var = blockReduce<0>(vsum, red) * (1.f / ND);
    const float rs = rsqrtf(var + 1e-5f);
#pragma unroll
    for (int c = 0; c < 4; ++c) {
        const int n = t + c * 512;
        const float st = (g[c] - mean) * rs * ln_g[n] + ln_b[n];
        trace2[((size_t)pos * ND + n) * NB + b] = st;
    }
}

// KD: per-neuron NLMs -> actT. grid 512 x 256 (1 neuron per wave). lane = b.
__global__ __launch_bounds__(256, 2) void k_nlm(const float* __restrict__ trace2,
                                                const float* __restrict__ w1t,
                                                const float* __restrict__ b1,
                                                const float* __restrict__ w2t,
                                                const float* __restrict__ b2,
                                                float* __restrict__ actT, int pos) {
    const int b = threadIdx.x & 63;
    const int wvu = __builtin_amdgcn_readfirstlane(threadIdx.x >> 6);
    const int n = blockIdx.x * 4 + wvu;                    // uniform per wave
    const float* brow = b1 + n * 64;
    float acc[64];
#pragma unroll
    for (int q = 0; q < 64; ++q) acc[q] = brow[q];
    int phys = (pos + 1 < NM) ? pos + 1 : 0;
    float tr = trace2[((size_t)phys * ND + n) * NB + b];
#pragma unroll 1
    for (int m = 0; m < NM; ++m) {
        const int physN = (phys + 1 < NM) ? phys + 1 : 0;
        float trn = 0.f;
        if (m + 1 < NM) trn = trace2[((size_t)physN * ND + n) * NB + b];
        const float* wrow = w1t + ((size_t)n * NM + m) * 64;   // uniform -> s_load
#pragma unroll
        for (int q = 0; q < 64; ++q) acc[q] = fmaf(tr, wrow[q], acc[q]);
        tr = trn; phys = physN;
    }
    const float* w2r = w2t + n * 64;                            // uniform
    float z0 = b2[n * 2 + 0], z1 = b2[n * 2 + 1];
#pragma unroll
    for (int i = 0; i < 32; ++i) {
        const float hv = acc[i] * sigm(acc[32 + i]);
        z0 = fmaf(hv, w2r[i], z0);
        z1 = fmaf(hv, w2r[32 + i], z1);
    }
    actT[n * NB + b] = z0 * sigm(z1);
}

// KE: output sync + out GEMM partials. grid 512 (kp 8 x jt 64) x 256.
__global__ __launch_bounds__(256) void k_out(const float* __restrict__ actT,
                                             float* __restrict__ aO, float* __restrict__ bO,
                                             const float* __restrict__ r_o,
                                             const int* __restrict__ iol,
                                             const int* __restrict__ ior,
                                             const float* __restrict__ out_w,
                                             float* __restrict__ part, int it) {
    __shared__ float syncL[4096];  // [64 k][64 b]
    const int kp = blockIdx.x >> 6, jt = blockIdx.x & 63;
    const int t = threadIdx.x;
    const int src = it & 1, dst = src ^ 1;
#pragma unroll
    for (int c = 0; c < 16; ++c) {
        const int idx = t + c * 256;
        const int il = idx >> 6, b = idx & 63;
        const int i = kp * 64 + il;
        const float pl = actT[iol[i] * NB + b];
        const float prr = actT[ior[i] * NB + b];
        const float r = r_o[i];
        const float aN = r * aO[src * 32768 + i * NB + b] + pl * prr;
        const float bN = r * bO[src * 32768 + i * NB + b] + 1.f;
        if (jt == 0) {
            aO[dst * 32768 + i * NB + b] = aN;
            bO[dst * 32768 + i * NB + b] = bN;
        }
        syncL[il * 64 + b] = aN * rsqrtf(bN);
    }
    __syncthreads();
    const int b = t & 63;
    const int j0 = jt * 64 + __builtin_amdgcn_readfirstlane(t >> 6) * 16;
    float acc[16];
#pragma unroll
    for (int q = 0; q < 16; ++q) acc[q] = 0.f;
#pragma unroll 4
    for (int k = 0; k < 64; ++k) {
        const float sv = syncL[k * 64 + b];
        const float* wrow = out_w + (size_t)(kp * 64 + k) * NOUT + j0;  // uniform
#pragma unroll
        for (int q = 0; q < 16; ++q) acc[q] = fmaf(sv, wrow[q], acc[q]);
    }
    float* dstp = part + ((size_t)(kp * NB + b)) * NOUT + j0;
#pragma unroll
    for (int q = 0; q < 16; ++q) dstp[q] = acc[q];
}

// ---------------- one-time precompute kernels ----------------

__global__ __launch_bounds__(512) void k_p0(const float* __restrict__ dec_a,
                                            const float* __restrict__ dec_o,
                                            const float* __restrict__ q_b,
                                            const float* __restrict__ wq,
                                            const float* __restrict__ bq,
                                            float* __restrict__ r_a, float* __restrict__ r_o,
                                            float* __restrict__ b_qq) {
    const int t = threadIdx.x;
    r_a[t] = expf(-fminf(fmaxf(dec_a[t], 0.f), 15.f));
    r_o[t] = expf(-fminf(fmaxf(dec_o[t], 0.f), 15.f));
    float acc = bq[t];
#pragma unroll 4
    for (int k = 0; k < NE; ++k) acc = fmaf(q_b[k], wq[k * NE + t], acc);
    b_qq[t] = acc;
}

__global__ __launch_bounds__(256) void k_wqq(const float* __restrict__ q_w,
                                             const float* __restrict__ wq,
                                             float* __restrict__ W_qq) {
    const int r = blockIdx.x >> 1;
    const int c = ((blockIdx.x & 1) << 8) + threadIdx.x;
    float acc = 0.f;
#pragma unroll 4
    for (int k = 0; k < NE; ++k) acc = fmaf(q_w[r * NE + k], wq[k * NE + c], acc);
    W_qq[r * NE + c] = acc;
}

__global__ __launch_bounds__(256) void k_woT(const float* __restrict__ wo,
                                             float* __restrict__ woT) {
    __shared__ float tile[64][65];
    const int te = blockIdx.x >> 3, tj = blockIdx.x & 7;
    for (int i = threadIdx.x; i < 4096; i += 256) {
        const int r = i >> 6, c = i & 63;
        tile[r][c] = wo[(size_t)(te * 64 + r) * NE + tj * 64 + c];
    }
    __syncthreads();
    for (int i = threadIdx.x; i < 4096; i += 256) {
        const int r = i >> 6, c = i & 63;
        woT[(size_t)(tj * 64 + r) * NE + te * 64 + c] = tile[c][r];
    }
}

__global__ __launch_bounds__(256) void k_woSyn(const float* __restrict__ woT,
                                               const float* __restrict__ syn_w,
                                               float* __restrict__ woSyn) {
    const int eg = blockIdx.x >> 6, ct = blockIdx.x & 63;
    const int c = ct * 64 + (threadIdx.x & 63);
    const int e0 = eg * 64 + __builtin_amdgcn_readfirstlane(threadIdx.x >> 6) * 16;
    float acc[16];
#pragma unroll
    for (int q = 0; q < 16; ++q) acc[q] = 0.f;
#pragma unroll 4
    for (int jp = 0; jp < NE; ++jp) {
        const float wv = syn_w[(size_t)jp * NOUT + c];
        const float* er = woT + (size_t)jp * NE + e0;
#pragma unroll
        for (int q = 0; q < 16; ++q) acc[q] = fmaf(er[q], wv, acc[q]);
    }
#pragma unroll
    for (int q = 0; q < 16; ++q)
        woSyn[(size_t)(e0 + q) * NOUT + c] = acc[q];
}

__global__ __launch_bounds__(256) void k_sbe(const float* __restrict__ syn_b,
                                             const float* __restrict__ bo,
                                             const float* __restrict__ syn_w,
                                             float* __restrict__ sbe) {
    const int c = blockIdx.x * 256 + threadIdx.x;
    float acc = syn_b[c];
#pragma unroll 4
    for (int jp = 0; jp < NE; ++jp)
        acc = fmaf(bo[jp], syn_w[(size_t)jp * NOUT + c], acc);
    sbe[c] = acc;
}

__global__ __launch_bounds__(256) void k_init_trace2(const float* __restrict__ st,
                                                     float* __restrict__ trace2) {
    const int idx = blockIdx.x * 256 + threadIdx.x;
    const int n = (idx >> 6) & (ND - 1);
    const int m = idx >> 17;
    trace2[idx] = st[n * NM + m];
}

#define INIT_TOTAL (NB * ND + 8 * NB * NE)
__global__ __launch_bounds__(256) void k_init_state(const float* __restrict__ sa,
                                                    float* __restrict__ actT,
                                                    float* __restrict__ zeroBase) {
    const int idx = blockIdx.x * 256 + threadIdx.x;
    if (idx >= INIT_TOTAL) return;
    if (idx < NB * ND) {
        const int b = idx & 63, n = idx >> 6;
        actT[n * NB + b] = sa[n];
    } else {
        zeroBase[idx - NB * ND] = 0.f;
    }
}

// k_p1 v2: kv = LN(feats @ kv_w + kv_b); K/V projections -> bf16 caches.
// grid 256 (b 64 x sg 4, 16 tokens each) x 512. Weights read once per block
// (512 MB total, L2-resident) vs r11's per-token blocks (8 GB). LDS kv tile
// kvT[e][tok] padded to 17 to avoid bank conflicts.
__global__ __launch_bounds__(512) void k_p1(const float* __restrict__ x,
                                            const float* __restrict__ kv_w,
                                            const float* __restrict__ kv_b,
                                            const float* __restrict__ ln_g,
                                            const float* __restrict__ ln_b,
                                            const float* __restrict__ wk,
                                            const float* __restrict__ bk,
                                            const float* __restrict__ wv,
                                            const float* __restrict__ bv,
                                            bf16_t* __restrict__ kp_t,
                                            bf16_t* __restrict__ vp_t) {
    __shared__ float kvT[NE][17];     // [e][tok]
    __shared__ float mS[16], rS[16];
    const int b = blockIdx.x >> 2, s0 = (blockIdx.x & 3) * 16;
    const int t = threadIdx.x;
    const int lane = t & 63, wvi = t >> 6;

    // phase 1: raw kv for 16 tokens
    {
        float w[12];
#pragma unroll
        for (int c = 0; c < 12; ++c) w[c] = kv_w[c * NE + t];
        const float kb = kv_b[t];
#pragma unroll
        for (int tok = 0; tok < 16; ++tok) {
            float acc = kb;
#pragma unroll
            for (int c = 0; c < 12; ++c)
                acc = fmaf(x[b * 768 + c * 64 + s0 + tok], w[c], acc);
            kvT[t][tok] = acc;
        }
    }
    __syncthreads();
    // phase 2: LN stats (wave wvi handles tokens 2wvi, 2wvi+1)
#pragma unroll
    for (int q = 0; q < 2; ++q) {
        const int tok = wvi * 2 + q;
        float s = 0.f, ss = 0.f;
#pragma unroll
        for (int i = 0; i < 8; ++i) {
            const float v = kvT[lane * 8 + i][tok];
            s += v; ss = fmaf(v, v, ss);
        }
        s = wredsum(s); ss = wredsum(ss);
        if (lane == 0) {
            const float mean = s * (1.f / NE);
            mS[tok] = mean;
            rS[tok] = rsqrtf(ss * (1.f / NE) - mean * mean + 1e-5f);
        }
    }
    __syncthreads();
    // phase 3: normalize in LDS
    {
        const float g = ln_g[t], bb2 = ln_b[t];
#pragma unroll
        for (int tok = 0; tok < 16; ++tok)
            kvT[t][tok] = (kvT[t][tok] - mS[tok]) * rS[tok] * g + bb2;
    }
    __syncthreads();
    // phase 4: K/V projection, thread j handles 16 tokens
    {
        const int j = t;
        float kpv[16], vpv[16];
        const float bk_ = bk[j], bv_ = bv[j];
#pragma unroll
        for (int tok = 0; tok < 16; ++tok) { kpv[tok] = bk_; vpv[tok] = bv_; }
        for (int k = 0; k < NE; ++k) {
            const float wkv = wk[k * NE + j];
            const float wvv = wv[k * NE + j];
            const float* kr = &kvT[k][0];     // same addr all lanes -> broadcast
#pragma unroll
            for (int tok = 0; tok < 16; ++tok) {
                const float kvv = kr[tok];
                kpv[tok] = fmaf(kvv, wkv, kpv[tok]);
                vpv[tok] = fmaf(kvv, wvv, vpv[tok]);
            }
        }
        const int h = j >> 6, dd = j & 63;
#pragma unroll
        for (int tok = 0; tok < 16; ++tok) {
            const int s = s0 + tok;
            kp_t[((size_t)(b * NHEADS + h) * NDH + dd) * NS + s] = f2bf(kpv[tok]);
            vp_t[((size_t)(b * NHEADS + h) * NS + s) * NDH + dd] = f2bf(vpv[tok]);
        }
    }
}

__global__ __launch_bounds__(256) void k_w1t(const float* __restrict__ w1,
                                             float* __restrict__ w1t) {
    __shared__ float tile[64][65];
    const int m = blockIdx.x >> 5, n0 = (blockIdx.x & 31) << 6;
    for (int i = threadIdx.x; i < 4096; i += 256) {
        const int hh = i >> 6, nn = i & 63;
        tile[hh][nn] = w1[(size_t)(m * 64 + hh) * ND + n0 + nn];
    }
    __syncthreads();
    for (int i = threadIdx.x; i < 4096; i += 256) {
        const int nn = i >> 6, hh = i & 63;
        w1t[((size_t)(n0 + nn) * NM + m) * 64 + hh] = tile[hh][nn];
    }
}

__global__ __launch_bounds__(256) void k_w2t(const float* __restrict__ w2,
                                             float* __restrict__ w2t) {
    const int idx = blockIdx.x * 256 + threadIdx.x;
    const int i = idx & 31;
    const int c = (idx >> 5) & 1;
    const int n = idx >> 6;
    w2t[idx] = w2[(size_t)(i * 2 + c) * ND + n];
}

__global__ __launch_bounds__(256) void k_transpose(const float* __restrict__ predTemp,
                                                   float* __restrict__ out) {
    __shared__ float tile[NS * NITER];
    const int b = blockIdx.x >> 6;
    const int j0 = (blockIdx.x & 63) * 64;
    for (int i = threadIdx.x; i < 3200; i += 256) {
        const int tt = i >> 6, jj = i & 63;
        tile[jj * NITER + tt] = predTemp[((size_t)b * NITER + tt) * NOUT + j0 + jj];
    }
    __syncthreads();
    float* dst = out + ((size_t)b * NOUT + j0) * NITER;
    for (int i = threadIdx.x; i < 3200; i += 256) dst[i] = tile[i];
}

extern "C" void kernel_launch(void* const* d_in, const int* in_sizes, int n_in,
                              void* d_out, int out_size, void* d_ws, size_t ws_size,
                              hipStream_t stream) {
    const float* x        = (const float*)d_in[0];
    const float* kv_w     = (const float*)d_in[1];
    const float* kv_b     = (const float*)d_in[2];
    const float* kv_ln_g  = (const float*)d_in[3];
    const float* kv_ln_b  = (const float*)d_in[4];
    const float* q_w      = (const float*)d_in[5];
    const float* q_b      = (const float*)d_in[6];
    const float* wq       = (const float*)d_in[7];
    const float* wk       = (const float*)d_in[8];
    const float* wv       = (const float*)d_in[9];
    const float* wo       = (const float*)d_in[10];
    const float* bq       = (const float*)d_in[11];
    const float* bk       = (const float*)d_in[12];
    const float* bv       = (const float*)d_in[13];
    const float* bo       = (const float*)d_in[14];
    const float* syn_w    = (const float*)d_in[15];
    const float* syn_b    = (const float*)d_in[16];
    const float* syn_ln_g = (const float*)d_in[17];
    const float* syn_ln_b = (const float*)d_in[18];
    const float* nlm1_w   = (const float*)d_in[19];
    const float* nlm1_b   = (const float*)d_in[20];
    const float* nlm2_w   = (const float*)d_in[21];
    const float* nlm2_b   = (const float*)d_in[22];
    const float* start_a  = (const float*)d_in[23];
    const float* start_tr = (const float*)d_in[24];
    const float* dec_a    = (const float*)d_in[25];
    const float* dec_o    = (const float*)d_in[26];
    const float* out_w    = (const float*)d_in[27];
    const float* out_b    = (const float*)d_in[28];
    const int* ial        = (const int*)d_in[29];
    const int* iar        = (const int*)d_in[30];
    const int* iol        = (const int*)d_in[31];
    const int* ior        = (const int*)d_in[32];
    float* out = (float*)d_out;

    float* ws = (float*)d_ws;
    size_t off = 0;
    auto alloc = [&](size_t n) { float* p = ws + off; off += n; return p; };
    float* actT   = alloc((size_t)ND * NB);
    float* oT     = alloc((size_t)NE * NB);
    bf16_t* kp_t  = (bf16_t*)alloc((size_t)NB * NE * NS / 2);
    bf16_t* vp_t  = (bf16_t*)alloc((size_t)NB * NE * NS / 2);
    float* W_qq   = alloc((size_t)NE * NE);
    float* woT    = alloc((size_t)NE * NE);
    float* woSyn  = alloc((size_t)NE * NOUT);
    float* sbe    = alloc(NOUT);
    float* b_qq   = alloc(NE);
    float* r_a    = alloc(NE);
    float* r_o    = alloc(NE);
    float* aA     = alloc((size_t)2 * NB * NE);         // zero span start
    float* bA     = alloc((size_t)2 * NB * NE);
    float* aO     = alloc((size_t)2 * NB * NE);
    float* bO     = alloc((size_t)2 * NB * NE);
    float* trace2 = alloc((size_t)NM * ND * NB);
    float* part   = alloc((size_t)16 * NB * NOUT);      // shared syn(16)/out(8)
    float* w1t    = alloc((size_t)ND * NM * 64);
    float* w2t    = alloc((size_t)ND * 64);
    int tmode = 0;
    float* predTemp = nullptr;
    if ((off + (size_t)PRED_TOTAL) * sizeof(float) <= ws_size) {
        predTemp = alloc((size_t)PRED_TOTAL);
        tmode = 1;
    }

    k_p0<<<1, 512, 0, stream>>>(dec_a, dec_o, q_b, wq, bq, r_a, r_o, b_qq);
    k_wqq<<<1024, 256, 0, stream>>>(q_w, wq, W_qq);
    k_woT<<<64, 256, 0, stream>>>(wo, woT);
    k_woSyn<<<512, 256, 0, stream>>>(woT, syn_w, woSyn);
    k_sbe<<<16, 256, 0, stream>>>(syn_b, bo, syn_w, sbe);
    k_init_trace2<<<(NM * ND * NB) / 256, 256, 0, stream>>>(start_tr, trace2);
    k_init_state<<<(INIT_TOTAL + 255) / 256, 256, 0, stream>>>(start_a, actT, aA);
    k_p1<<<256, 512, 0, stream>>>(x, kv_w, kv_b, kv_ln_g, kv_ln_b, wk, bk, wv, bv, kp_t, vp_t);
    k_w1t<<<800, 256, 0, stream>>>(nlm1_w, w1t);
    k_w2t<<<(ND * 64) / 256, 256, 0, stream>>>(nlm2_w, w2t);

    for (int t = 0; t < NITER; ++t) {
        k_front_final<<<256, 512, 0, stream>>>(actT, oT, aA, bA, r_a, ial, iar, W_qq, b_qq,
                                               kp_t, vp_t, part, out_b, out, predTemp,
                                               1, (t > 0) ? 1 : 0, t - 1, tmode, t);
        k_gemm_syn<<<1024, 256, 0, stream>>>(oT, actT, woSyn, syn_w, part);
        k_glu_ln<<<NB, 512, 0, stream>>>(part, sbe, syn_ln_g, syn_ln_b, trace2, t % NM);
        k_nlm<<<512, 256, 0, stream>>>(trace2, w1t, nlm1_b, w2t, nlm2_b, actT, t % NM);
        k_out<<<512, 256, 0, stream>>>(actT, aO, bO, r_o, iol, ior, out_w, part, t);
    }
    // final entropy/prediction for t = 49
    k_front_final<<<256, 512, 0, stream>>>(actT, oT, aA, bA, r_a, ial, iar, W_qq, b_qq,
                                           kp_t, vp_t, part, out_b, out, predTemp,
                                           0, 1, NITER - 1, tmode, NITER);
    if (tmode) k_transpose<<<NB * 64, 256, 0, stream>>>(predTemp, out);
}

// Round 13
// 4424.855 us; speedup vs baseline: 4.8798x; 1.2675x over previous
//
#include <hip/hip_runtime.h>
#include <math.h>

#define NB 64
#define ND 2048
#define NE 512
#define NM 25
#define NOUT 4096
#define NHEADS 8
#define NDH 64
#define NS 64
#define NITER 50
#define NKSYN 2560
#define PRED_TOTAL (NB * NOUT * NITER)   /* 13107200 */

typedef unsigned short bf16_t;
typedef __attribute__((ext_vector_type(8))) short short8;
typedef __attribute__((ext_vector_type(4))) float f32x4;

__device__ __forceinline__ float sigm(float x) { return 1.f / (1.f + expf(-x)); }

__device__ __forceinline__ bf16_t f2bf(float f) {
    unsigned u = __float_as_uint(f);
    unsigned r = (u + 0x7FFFu + ((u >> 16) & 1u)) >> 16;
    return (bf16_t)r;
}
__device__ __forceinline__ float bf2f(bf16_t h) {
    return __uint_as_float(((unsigned)h) << 16);
}

__device__ __forceinline__ float wredsum(float v) {
#pragma unroll
    for (int o = 32; o; o >>= 1) v += __shfl_xor(v, o);
    return v;
}
__device__ __forceinline__ float wredmax(float v) {
#pragma unroll
    for (int o = 32; o; o >>= 1) v = fmaxf(v, __shfl_xor(v, o));
    return v;
}

template <int OP>
__device__ __forceinline__ float blockReduce(float v, float* red) {
    const int tid = threadIdx.x, lane = tid & 63, wid = tid >> 6;
    v = (OP == 0) ? wredsum(v) : wredmax(v);
    __syncthreads();
    if (lane == 0) red[wid] = v;
    __syncthreads();
    if (tid == 0) {
        const int nw = blockDim.x >> 6;
        float r = red[0];
        for (int w = 1; w < nw; ++w) r = (OP == 0) ? r + red[w] : fmaxf(r, red[w]);
        red[0] = r;
    }
    __syncthreads();
    return red[0];
}

// ---------------- per-step kernels (5 dispatches/step) ----------------

// KA: grid 256 (jt 4 x b 64) x 512. final(tt) on jt==0 blocks first, then front.
// front phase 4 now writes o directly into actB rows [0,512) as bf16.
__global__ __launch_bounds__(512) void k_front_final(
        const float* __restrict__ actT, bf16_t* __restrict__ actB,
        float* __restrict__ aA, float* __restrict__ bA,
        const float* __restrict__ r_a,
        const int* __restrict__ ial, const int* __restrict__ iar,
        const float* __restrict__ W_qq, const float* __restrict__ b_qq,
        const bf16_t* __restrict__ kp_t, const bf16_t* __restrict__ vp_t,
        const float* __restrict__ part, const float* __restrict__ out_b,
        float* __restrict__ out, float* __restrict__ predTemp,
        int doFront, int doFinal, int tt, int tmode, int it) {
    __shared__ float syncS[512];
    __shared__ float partK[512];
    __shared__ float qhS[128];
    __shared__ float attnS[128];
    __shared__ float red[8];
    const int bid = blockIdx.x;
    const int jt = bid >> 6, b = bid & 63;
    const int t = threadIdx.x;
    const int lane = t & 63, wv = t >> 6;

    if (doFinal && jt == 0) {
        float pr[8];
        float lmax = -1e30f;
#pragma unroll
        for (int c = 0; c < 8; ++c) {
            const int j = t + c * 512;
            float v = out_b[j];
#pragma unroll
            for (int kp = 0; kp < 8; ++kp) v += part[((size_t)(kp * NB + b)) * NOUT + j];
            pr[c] = v;
            lmax = fmaxf(lmax, v);
        }
        const float mx = blockReduce<1>(lmax, red);
        float ls = 0.f;
#pragma unroll
        for (int c = 0; c < 8; ++c) ls += expf(pr[c] - mx);
        const float se = blockReduce<0>(ls, red);
        const float logZ = mx + logf(se);
        float le = 0.f;
#pragma unroll
        for (int c = 0; c < 8; ++c) { const float lp = pr[c] - logZ; le += expf(lp) * lp; }
        const float ent = blockReduce<0>(le, red);
        const float ne = -ent * 0.12022458674074694f;  // 1/ln(4096)
        if (tmode) {
#pragma unroll
            for (int c = 0; c < 8; ++c)
                predTemp[((size_t)b * NITER + tt) * NOUT + t + c * 512] = pr[c];
        } else {
#pragma unroll
            for (int c = 0; c < 8; ++c) {
                const int j = t + c * 512;
                out[((size_t)b * NOUT + j) * NITER + tt] = pr[c];
            }
        }
        if (t == 0) {
            out[PRED_TOTAL + b * 100 + tt] = ne;
            out[PRED_TOTAL + b * 100 + 50 + tt] = 1.f - ne;
        }
    }
    if (!doFront) return;

    const int src = it & 1, dst = src ^ 1;
    // phase 1: action sync (all blocks compute; jt0 persists dbuf)
    {
        const int i = t;
        const float pl = actT[ial[i] * NB + b];
        const float prr = actT[iar[i] * NB + b];
        const float r = r_a[i];
        const float aN = r * aA[src * 32768 + b * NE + i] + pl * prr;
        const float bN = r * bA[src * 32768 + b * NE + i] + 1.f;
        if (jt == 0) {
            aA[dst * 32768 + b * NE + i] = aN;
            bA[dst * 32768 + b * NE + i] = bN;
        }
        syncS[i] = aN * rsqrtf(bN);
    }
    __syncthreads();
    // phase 2: qh j-slice [jt*128, +128), k split 4-way
    {
        const int g = t >> 7, l = t & 127;
        const int j = jt * 128 + l;
        float acc = 0.f;
        const int kk0 = g * 128;
#pragma unroll 4
        for (int k = kk0; k < kk0 + 128; ++k)
            acc = fmaf(syncS[k], W_qq[k * NE + j], acc);
        partK[g * 128 + l] = acc;
    }
    __syncthreads();
    if (t < 128) {
        qhS[t] = b_qq[jt * 128 + t] + partK[t] + partK[128 + t] + partK[256 + t] + partK[384 + t];
    }
    __syncthreads();
    // phase 3: scores + softmax for heads 2jt, 2jt+1 (waves 0-1)
    if (wv < 2) {
        const int h = jt * 2 + wv, s = lane;
        const bf16_t* kpp = kp_t + ((size_t)(b * NHEADS + h) * NDH) * NS + s;
        float sc = 0.f;
#pragma unroll 8
        for (int d = 0; d < NDH; ++d) sc = fmaf(qhS[wv * 64 + d], bf2f(kpp[d * NS]), sc);
        sc *= 0.125f;
        const float mxv = wredmax(sc);
        const float ev = expf(sc - mxv);
        const float sm = wredsum(ev);
        attnS[wv * 64 + s] = ev / sm;
    }
    __syncthreads();
    // phase 4: o = attn @ V -> actB[b][h*64+d] (bf16, contiguous per wave)
    if (wv < 2) {
        const int h = jt * 2 + wv, d = lane;
        const bf16_t* vpp = vp_t + ((size_t)(b * NHEADS + h) * NS) * NDH + d;
        float o = 0.f;
#pragma unroll 8
        for (int s2 = 0; s2 < NS; ++s2) o = fmaf(attnS[wv * 64 + s2], bf2f(vpp[s2 * NDH]), o);
        actB[(size_t)b * NKSYN + h * NDH + d] = f2bf(o);
    }
}

// KB: syn GEMM via bf16 MFMA. grid 512 (kp 8 x jt 64) x 256, 2 blocks/CU.
// Wave wv computes batch rows [wv*16, +16) x j-tile [jt*64, +64), K range
// [kp*320, +320) in 10 steps of 32. A = actB (bf16 [b][k], 16B frag loads),
// B = bpack (fragment-preordered bf16, contiguous 16B/lane). fp32 accum.
__global__ __launch_bounds__(256, 2) void k_gemm_syn(const bf16_t* __restrict__ actB,
                                                     const bf16_t* __restrict__ bpack,
                                                     float* __restrict__ part) {
    const int kp = blockIdx.x >> 6, jt = blockIdx.x & 63;
    const int l = threadIdx.x & 63;
    const int wv = threadIdx.x >> 6;
    const int b0 = wv * 16;
    const int row = b0 + (l & 15);
    const int kgrp = l >> 4;
    f32x4 acc[4];
#pragma unroll
    for (int js = 0; js < 4; ++js) acc[js] = (f32x4){0.f, 0.f, 0.f, 0.f};
    const int ks0 = kp * 10;
#pragma unroll 2
    for (int ks = 0; ks < 10; ++ks) {
        const int kk = (ks0 + ks) * 32;
        const short8 av = *(const short8*)(actB + (size_t)row * NKSYN + kk + kgrp * 8);
#pragma unroll
        for (int js = 0; js < 4; ++js) {
            const short8 bv = *(const short8*)(bpack +
                ((((size_t)(jt * 4 + js)) * 80 + ks0 + ks) * 64 + l) * 8);
            acc[js] = __builtin_amdgcn_mfma_f32_16x16x32_bf16(av, bv, acc[js], 0, 0, 0);
        }
    }
#pragma unroll
    for (int js = 0; js < 4; ++js) {
#pragma unroll
        for (int r = 0; r < 4; ++r) {
            const int b = b0 + kgrp * 4 + r;
            const int j = jt * 64 + js * 16 + (l & 15);
            part[((size_t)(kp * NB + b)) * NOUT + j] = acc[js][r];
        }
    }
}

// KC: reduce 8 partials + bias_eff + GLU + LN -> trace2[pos]. grid 64 x 512.
__global__ __launch_bounds__(512) void k_glu_ln(const float* __restrict__ part,
                                                const float* __restrict__ sbe,
                                                const float* __restrict__ ln_g,
                                                const float* __restrict__ ln_b,
                                                float* __restrict__ trace2, int pos) {
    __shared__ float red[8];
    const int b = blockIdx.x;
    const int t = threadIdx.x;
    float g[4];
    float ssum = 0.f;
#pragma unroll
    for (int c = 0; c < 4; ++c) {
        const int n = t + c * 512;
        float ya = sbe[n], yb = sbe[n + ND];
#pragma unroll
        for (int kp = 0; kp < 8; ++kp) {
            ya += part[((size_t)(kp * NB + b)) * NOUT + n];
            yb += part[((size_t)(kp * NB + b)) * NOUT + n + ND];
        }
        g[c] = ya * sigm(yb);
        ssum += g[c];
    }
    const float mean = blockReduce<0>(ssum, red) * (1.f / ND);
    float vsum = 0.f;
#pragma unroll
    for (int c = 0; c < 4; ++c) { const float d = g[c] - mean; vsum += d * d; }
    const float var = blockReduce<0>(vsum, red) * (1.f / ND);
    const float rs = rsqrtf(var + 1e-5f);
#pragma unroll
    for (int c = 0; c < 4; ++c) {
        const int n = t + c * 512;
        const float st = (g[c] - mean) * rs * ln_g[n] + ln_b[n];
        trace2[((size_t)pos * ND + n) * NB + b] = st;
    }
}

// KD: per-neuron NLMs -> actT (fp32, for gathers) + actB rows [512,2560) (bf16,
// for MFMA gemm). grid 512 x 256 (1 neuron per wave). lane = b.
__global__ __launch_bounds__(256, 2) void k_nlm(const float* __restrict__ trace2,
                                                const float* __restrict__ w1t,
                                                const float* __restrict__ b1,
                                                const float* __restrict__ w2t,
                                                const float* __restrict__ b2,
                                                float* __restrict__ actT,
                                                bf16_t* __restrict__ actB, int pos) {
    __shared__ float tileA[4][64];
    const int b = threadIdx.x & 63;
    const int wvu = __builtin_amdgcn_readfirstlane(threadIdx.x >> 6);
    const int n = blockIdx.x * 4 + wvu;                    // uniform per wave
    const float* brow = b1 + n * 64;
    float acc[64];
#pragma unroll
    for (int q = 0; q < 64; ++q) acc[q] = brow[q];
    int phys = (pos + 1 < NM) ? pos + 1 : 0;
    float tr = trace2[((size_t)phys * ND + n) * NB + b];
#pragma unroll 1
    for (int m = 0; m < NM; ++m) {
        const int physN = (phys + 1 < NM) ? phys + 1 : 0;
        float trn = 0.f;
        if (m + 1 < NM) trn = trace2[((size_t)physN * ND + n) * NB + b];
        const float* wrow = w1t + ((size_t)n * NM + m) * 64;   // uniform -> s_load
#pragma unroll
        for (int q = 0; q < 64; ++q) acc[q] = fmaf(tr, wrow[q], acc[q]);
        tr = trn; phys = physN;
    }
    const float* w2r = w2t + n * 64;                            // uniform
    float z0 = b2[n * 2 + 0], z1 = b2[n * 2 + 1];
#pragma unroll
    for (int i = 0; i < 32; ++i) {
        const float hv = acc[i] * sigm(acc[32 + i]);
        z0 = fmaf(hv, w2r[i], z0);
        z1 = fmaf(hv, w2r[32 + i], z1);
    }
    const float val = z0 * sigm(z1);
    actT[n * NB + b] = val;
    tileA[wvu][b] = val;
    __syncthreads();
    const int bb = threadIdx.x >> 2, nn = threadIdx.x & 3;
    actB[(size_t)bb * NKSYN + NE + blockIdx.x * 4 + nn] = f2bf(tileA[nn][bb]);
}

// KE: output sync + out GEMM partials. grid 512 (kp 8 x jt 64) x 256.
__global__ __launch_bounds__(256) void k_out(const float* __restrict__ actT,
                                             float* __restrict__ aO, float* __restrict__ bO,
                                             const float* __restrict__ r_o,
                                             const int* __restrict__ iol,
                                             const int* __restrict__ ior,
                                             const float* __restrict__ out_w,
                                             float* __restrict__ part, int it) {
    __shared__ float syncL[4096];  // [64 k][64 b]
    const int kp = blockIdx.x >> 6, jt = blockIdx.x & 63;
    const int t = threadIdx.x;
    const int src = it & 1, dst = src ^ 1;
#pragma unroll
    for (int c = 0; c < 16; ++c) {
        const int idx = t + c * 256;
        const int il = idx >> 6, b = idx & 63;
        const int i = kp * 64 + il;
        const float pl = actT[iol[i] * NB + b];
        const float prr = actT[ior[i] * NB + b];
        const float r = r_o[i];
        const float aN = r * aO[src * 32768 + i * NB + b] + pl * prr;
        const float bN = r * bO[src * 32768 + i * NB + b] + 1.f;
        if (jt == 0) {
            aO[dst * 32768 + i * NB + b] = aN;
            bO[dst * 32768 + i * NB + b] = bN;
        }
        syncL[il * 64 + b] = aN * rsqrtf(bN);
    }
    __syncthreads();
    const int b = t & 63;
    const int j0 = jt * 64 + __builtin_amdgcn_readfirstlane(t >> 6) * 16;
    float acc[16];
#pragma unroll
    for (int q = 0; q < 16; ++q) acc[q] = 0.f;
#pragma unroll 4
    for (int k = 0; k < 64; ++k) {
        const float sv = syncL[k * 64 + b];
        const float* wrow = out_w + (size_t)(kp * 64 + k) * NOUT + j0;  // uniform
#pragma unroll
        for (int q = 0; q < 16; ++q) acc[q] = fmaf(sv, wrow[q], acc[q]);
    }
    float* dstp = part + ((size_t)(kp * NB + b)) * NOUT + j0;
#pragma unroll
    for (int q = 0; q < 16; ++q) dstp[q] = acc[q];
}

// ---------------- one-time precompute kernels ----------------

__global__ __launch_bounds__(512) void k_p0(const float* __restrict__ dec_a,
                                            const float* __restrict__ dec_o,
                                            const float* __restrict__ q_b,
                                            const float* __restrict__ wq,
                                            const float* __restrict__ bq,
                                            float* __restrict__ r_a, float* __restrict__ r_o,
                                            float* __restrict__ b_qq) {
    const int t = threadIdx.x;
    r_a[t] = expf(-fminf(fmaxf(dec_a[t], 0.f), 15.f));
    r_o[t] = expf(-fminf(fmaxf(dec_o[t], 0.f), 15.f));
    float acc = bq[t];
#pragma unroll 4
    for (int k = 0; k < NE; ++k) acc = fmaf(q_b[k], wq[k * NE + t], acc);
    b_qq[t] = acc;
}

__global__ __launch_bounds__(256) void k_wqq(const float* __restrict__ q_w,
                                             const float* __restrict__ wq,
                                             float* __restrict__ W_qq) {
    const int r = blockIdx.x >> 1;
    const int c = ((blockIdx.x & 1) << 8) + threadIdx.x;
    float acc = 0.f;
#pragma unroll 4
    for (int k = 0; k < NE; ++k) acc = fmaf(q_w[r * NE + k], wq[k * NE + c], acc);
    W_qq[r * NE + c] = acc;
}

__global__ __launch_bounds__(256) void k_woT(const float* __restrict__ wo,
                                             float* __restrict__ woT) {
    __shared__ float tile[64][65];
    const int te = blockIdx.x >> 3, tj = blockIdx.x & 7;
    for (int i = threadIdx.x; i < 4096; i += 256) {
        const int r = i >> 6, c = i & 63;
        tile[r][c] = wo[(size_t)(te * 64 + r) * NE + tj * 64 + c];
    }
    __syncthreads();
    for (int i = threadIdx.x; i < 4096; i += 256) {
        const int r = i >> 6, c = i & 63;
        woT[(size_t)(tj * 64 + r) * NE + te * 64 + c] = tile[c][r];
    }
}

__global__ __launch_bounds__(256) void k_woSyn(const float* __restrict__ woT,
                                               const float* __restrict__ syn_w,
                                               float* __restrict__ woSyn) {
    const int eg = blockIdx.x >> 6, ct = blockIdx.x & 63;
    const int c = ct * 64 + (threadIdx.x & 63);
    const int e0 = eg * 64 + __builtin_amdgcn_readfirstlane(threadIdx.x >> 6) * 16;
    float acc[16];
#pragma unroll
    for (int q = 0; q < 16; ++q) acc[q] = 0.f;
#pragma unroll 4
    for (int jp = 0; jp < NE; ++jp) {
        const float wv = syn_w[(size_t)jp * NOUT + c];
        const float* er = woT + (size_t)jp * NE + e0;
#pragma unroll
        for (int q = 0; q < 16; ++q) acc[q] = fmaf(er[q], wv, acc[q]);
    }
#pragma unroll
    for (int q = 0; q < 16; ++q)
        woSyn[(size_t)(e0 + q) * NOUT + c] = acc[q];
}

__global__ __launch_bounds__(256) void k_sbe(const float* __restrict__ syn_b,
                                             const float* __restrict__ bo,
                                             const float* __restrict__ syn_w,
                                             float* __restrict__ sbe) {
    const int c = blockIdx.x * 256 + threadIdx.x;
    float acc = syn_b[c];
#pragma unroll 4
    for (int jp = 0; jp < NE; ++jp)
        acc = fmaf(bo[jp], syn_w[(size_t)jp * NOUT + c], acc);
    sbe[c] = acc;
}

// Pack combined weights [woSyn(rows<512); syn_w(rows 512+)] into MFMA B-fragment
// order: bpack[((jt16*80 + ks)*64 + lane)*8 + e] = W[ks*32 + (lane>>4)*8 + e][jt16*16 + (lane&15)]
__global__ __launch_bounds__(256) void k_bpack(const float* __restrict__ woSyn,
                                               const float* __restrict__ syn_w,
                                               bf16_t* __restrict__ bpack) {
    const size_t idx = (size_t)blockIdx.x * 256 + threadIdx.x;   // < 2560*4096
    const int e = (int)(idx & 7);
    const int l = (int)((idx >> 3) & 63);
    const int rest = (int)(idx >> 9);
    const int ksg = rest % 80;
    const int jt16 = rest / 80;
    const int k = ksg * 32 + (l >> 4) * 8 + e;
    const int j = jt16 * 16 + (l & 15);
    const float v = (k < NE) ? woSyn[(size_t)k * NOUT + j]
                             : syn_w[(size_t)k * NOUT + j];
    bpack[idx] = f2bf(v);
}

__global__ __launch_bounds__(256) void k_init_trace2(const float* __restrict__ st,
                                                     float* __restrict__ trace2) {
    const int idx = blockIdx.x * 256 + threadIdx.x;
    const int n = (idx >> 6) & (ND - 1);
    const int m = idx >> 17;
    trace2[idx] = st[n * NM + m];
}

#define INIT_TOTAL (NB * ND + 8 * NB * NE)
__global__ __launch_bounds__(256) void k_init_state(const float* __restrict__ sa,
                                                    float* __restrict__ actT,
                                                    bf16_t* __restrict__ actB,
                                                    float* __restrict__ zeroBase) {
    const int idx = blockIdx.x * 256 + threadIdx.x;
    if (idx >= INIT_TOTAL) return;
    if (idx < NB * ND) {
        const int b = idx & 63, n = idx >> 6;
        actT[n * NB + b] = sa[n];
        actB[(size_t)b * NKSYN + NE + n] = f2bf(sa[n]);
    } else {
        zeroBase[idx - NB * ND] = 0.f;
    }
}

// k_p1 v2: kv = LN(feats @ kv_w + kv_b); K/V projections -> bf16 caches.
__global__ __launch_bounds__(512) void k_p1(const float* __restrict__ x,
                                            const float* __restrict__ kv_w,
                                            const float* __restrict__ kv_b,
                                            const float* __restrict__ ln_g,
                                            const float* __restrict__ ln_b,
                                            const float* __restrict__ wk,
                                            const float* __restrict__ bk,
                                            const float* __restrict__ wv,
                                            const float* __restrict__ bv,
                                            bf16_t* __restrict__ kp_t,
                                            bf16_t* __restrict__ vp_t) {
    __shared__ float kvT[NE][17];     // [e][tok]
    __shared__ float mS[16], rS[16];
    const int b = blockIdx.x >> 2, s0 = (blockIdx.x & 3) * 16;
    const int t = threadIdx.x;
    const int lane = t & 63, wvi = t >> 6;

    {
        float w[12];
#pragma unroll
        for (int c = 0; c < 12; ++c) w[c] = kv_w[c * NE + t];
        const float kb = kv_b[t];
#pragma unroll
        for (int tok = 0; tok < 16; ++tok) {
            float acc = kb;
#pragma unroll
            for (int c = 0; c < 12; ++c)
                acc = fmaf(x[b * 768 + c * 64 + s0 + tok], w[c], acc);
            kvT[t][tok] = acc;
        }
    }
    __syncthreads();
#pragma unroll
    for (int q = 0; q < 2; ++q) {
        const int tok = wvi * 2 + q;
        float s = 0.f, ss = 0.f;
#pragma unroll
        for (int i = 0; i < 8; ++i) {
            const float v = kvT[lane * 8 + i][tok];
            s += v; ss = fmaf(v, v, ss);
        }
        s = wredsum(s); ss = wredsum(ss);
        if (lane == 0) {
            const float mean = s * (1.f / NE);
            mS[tok] = mean;
            rS[tok] = rsqrtf(ss * (1.f / NE) - mean * mean + 1e-5f);
        }
    }
    __syncthreads();
    {
        const float g = ln_g[t], bb2 = ln_b[t];
#pragma unroll
        for (int tok = 0; tok < 16; ++tok)
            kvT[t][tok] = (kvT[t][tok] - mS[tok]) * rS[tok] * g + bb2;
    }
    __syncthreads();
    {
        const int j = t;
        float kpv[16], vpv[16];
        const float bk_ = bk[j], bv_ = bv[j];
#pragma unroll
        for (int tok = 0; tok < 16; ++tok) { kpv[tok] = bk_; vpv[tok] = bv_; }
        for (int k = 0; k < NE; ++k) {
            const float wkv = wk[k * NE + j];
            const float wvv = wv[k * NE + j];
            const float* kr = &kvT[k][0];
#pragma unroll
            for (int tok = 0; tok < 16; ++tok) {
                const float kvv = kr[tok];
                kpv[tok] = fmaf(kvv, wkv, kpv[tok]);
                vpv[tok] = fmaf(kvv, wvv, vpv[tok]);
            }
        }
        const int h = j >> 6, dd = j & 63;
#pragma unroll
        for (int tok = 0; tok < 16; ++tok) {
            const int s = s0 + tok;
            kp_t[((size_t)(b * NHEADS + h) * NDH + dd) * NS + s] = f2bf(kpv[tok]);
            vp_t[((size_t)(b * NHEADS + h) * NS + s) * NDH + dd] = f2bf(vpv[tok]);
        }
    }
}

__global__ __launch_bounds__(256) void k_w1t(const float* __restrict__ w1,
                                             float* __restrict__ w1t) {
    __shared__ float tile[64][65];
    const int m = blockIdx.x >> 5, n0 = (blockIdx.x & 31) << 6;
    for (int i = threadIdx.x; i < 4096; i += 256) {
        const int hh = i >> 6, nn = i & 63;
        tile[hh][nn] = w1[(size_t)(m * 64 + hh) * ND + n0 + nn];
    }
    __syncthreads();
    for (int i = threadIdx.x; i < 4096; i += 256) {
        const int nn = i >> 6, hh = i & 63;
        w1t[((size_t)(n0 + nn) * NM + m) * 64 + hh] = tile[hh][nn];
    }
}

__global__ __launch_bounds__(256) void k_w2t(const float* __restrict__ w2,
                                             float* __restrict__ w2t) {
    const int idx = blockIdx.x * 256 + threadIdx.x;
    const int i = idx & 31;
    const int c = (idx >> 5) & 1;
    const int n = idx >> 6;
    w2t[idx] = w2[(size_t)(i * 2 + c) * ND + n];
}

__global__ __launch_bounds__(256) void k_transpose(const float* __restrict__ predTemp,
                                                   float* __restrict__ out) {
    __shared__ float tile[NS * NITER];
    const int b = blockIdx.x >> 6;
    const int j0 = (blockIdx.x & 63) * 64;
    for (int i = threadIdx.x; i < 3200; i += 256) {
        const int tt = i >> 6, jj = i & 63;
        tile[jj * NITER + tt] = predTemp[((size_t)b * NITER + tt) * NOUT + j0 + jj];
    }
    __syncthreads();
    float* dst = out + ((size_t)b * NOUT + j0) * NITER;
    for (int i = threadIdx.x; i < 3200; i += 256) dst[i] = tile[i];
}

extern "C" void kernel_launch(void* const* d_in, const int* in_sizes, int n_in,
                              void* d_out, int out_size, void* d_ws, size_t ws_size,
                              hipStream_t stream) {
    const float* x        = (const float*)d_in[0];
    const float* kv_w     = (const float*)d_in[1];
    const float* kv_b     = (const float*)d_in[2];
    const float* kv_ln_g  = (const float*)d_in[3];
    const float* kv_ln_b  = (const float*)d_in[4];
    const float* q_w      = (const float*)d_in[5];
    const float* q_b      = (const float*)d_in[6];
    const float* wq       = (const float*)d_in[7];
    const float* wk       = (const float*)d_in[8];
    const float* wv       = (const float*)d_in[9];
    const float* wo       = (const float*)d_in[10];
    const float* bq       = (const float*)d_in[11];
    const float* bk       = (const float*)d_in[12];
    const float* bv       = (const float*)d_in[13];
    const float* bo       = (const float*)d_in[14];
    const float* syn_w    = (const float*)d_in[15];
    const float* syn_b    = (const float*)d_in[16];
    const float* syn_ln_g = (const float*)d_in[17];
    const float* syn_ln_b = (const float*)d_in[18];
    const float* nlm1_w   = (const float*)d_in[19];
    const float* nlm1_b   = (const float*)d_in[20];
    const float* nlm2_w   = (const float*)d_in[21];
    const float* nlm2_b   = (const float*)d_in[22];
    const float* start_a  = (const float*)d_in[23];
    const float* start_tr = (const float*)d_in[24];
    const float* dec_a    = (const float*)d_in[25];
    const float* dec_o    = (const float*)d_in[26];
    const float* out_w    = (const float*)d_in[27];
    const float* out_b    = (const float*)d_in[28];
    const int* ial        = (const int*)d_in[29];
    const int* iar        = (const int*)d_in[30];
    const int* iol        = (const int*)d_in[31];
    const int* ior        = (const int*)d_in[32];
    float* out = (float*)d_out;

    float* ws = (float*)d_ws;
    size_t off = 0;
    auto alloc = [&](size_t n) { float* p = ws + off; off += n; return p; };
    float* actT   = alloc((size_t)ND * NB);
    bf16_t* actB  = (bf16_t*)alloc((size_t)NB * NKSYN / 2);    // 81920 f-slots
    bf16_t* kp_t  = (bf16_t*)alloc((size_t)NB * NE * NS / 2);
    bf16_t* vp_t  = (bf16_t*)alloc((size_t)NB * NE * NS / 2);
    float* W_qq   = alloc((size_t)NE * NE);
    float* woT    = alloc((size_t)NE * NE);
    float* woSyn  = alloc((size_t)NE * NOUT);
    bf16_t* bpack = (bf16_t*)alloc((size_t)NKSYN * NOUT / 2); // 5242880 f-slots
    float* sbe    = alloc(NOUT);
    float* b_qq   = alloc(NE);
    float* r_a    = alloc(NE);
    float* r_o    = alloc(NE);
    float* aA     = alloc((size_t)2 * NB * NE);         // zero span start
    float* bA     = alloc((size_t)2 * NB * NE);
    float* aO     = alloc((size_t)2 * NB * NE);
    float* bO     = alloc((size_t)2 * NB * NE);
    float* trace2 = alloc((size_t)NM * ND * NB);
    float* part   = alloc((size_t)8 * NB * NOUT);       // shared syn/out (8 partials)
    float* w1t    = alloc((size_t)ND * NM * 64);
    float* w2t    = alloc((size_t)ND * 64);
    int tmode = 0;
    float* predTemp = nullptr;
    if ((off + (size_t)PRED_TOTAL) * sizeof(float) <= ws_size) {
        predTemp = alloc((size_t)PRED_TOTAL);
        tmode = 1;
    }

    k_p0<<<1, 512, 0, stream>>>(dec_a, dec_o, q_b, wq, bq, r_a, r_o, b_qq);
    k_wqq<<<1024, 256, 0, stream>>>(q_w, wq, W_qq);
    k_woT<<<64, 256, 0, stream>>>(wo, woT);
    k_woSyn<<<512, 256, 0, stream>>>(woT, syn_w, woSyn);
    k_sbe<<<16, 256, 0, stream>>>(syn_b, bo, syn_w, sbe);
    k_bpack<<<(NKSYN * NOUT) / 256, 256, 0, stream>>>(woSyn, syn_w, bpack);
    k_init_trace2<<<(NM * ND * NB) / 256, 256, 0, stream>>>(start_tr, trace2);
    k_init_state<<<(INIT_TOTAL + 255) / 256, 256, 0, stream>>>(start_a, actT, actB, aA);
    k_p1<<<256, 512, 0, stream>>>(x, kv_w, kv_b, kv_ln_g, kv_ln_b, wk, bk, wv, bv, kp_t, vp_t);
    k_w1t<<<800, 256, 0, stream>>>(nlm1_w, w1t);
    k_w2t<<<(ND * 64) / 256, 256, 0, stream>>>(nlm2_w, w2t);

    for (int t = 0; t < NITER; ++t) {
        k_front_final<<<256, 512, 0, stream>>>(actT, actB, aA, bA, r_a, ial, iar, W_qq, b_qq,
                                               kp_t, vp_t, part, out_b, out, predTemp,
                                               1, (t > 0) ? 1 : 0, t - 1, tmode, t);
        k_gemm_syn<<<512, 256, 0, stream>>>(actB, bpack, part);
        k_glu_ln<<<NB, 512, 0, stream>>>(part, sbe, syn_ln_g, syn_ln_b, trace2, t % NM);
        k_nlm<<<512, 256, 0, stream>>>(trace2, w1t, nlm1_b, w2t, nlm2_b, actT, actB, t % NM);
        k_out<<<512, 256, 0, stream>>>(actT, aO, bO, r_o, iol, ior, out_w, part, t);
    }
    // final entropy/prediction for t = 49
    k_front_final<<<256, 512, 0, stream>>>(actT, actB, aA, bA, r_a, ial, iar, W_qq, b_qq,
                                           kp_t, vp_t, part, out_b, out, predTemp,
                                           0, 1, NITER - 1, tmode, NITER);
    if (tmode) k_transpose<<<NB * 64, 256, 0, stream>>>(predTemp, out);
}

// Round 14
// 3948.213 us; speedup vs baseline: 5.4689x; 1.1207x over previous
//
#include <hip/hip_runtime.h>
#include <math.h>

#define NB 64
#define ND 2048
#define NE 512
#define NM 25
#define NOUT 4096
#define NHEADS 8
#define NDH 64
#define NS 64
#define NITER 50
#define NKSYN 2560
#define PRED_TOTAL (NB * NOUT * NITER)   /* 13107200 */

typedef unsigned short bf16_t;
typedef __attribute__((ext_vector_type(8))) short short8;
typedef __attribute__((ext_vector_type(4))) float f32x4;

__device__ __forceinline__ float sigm(float x) { return 1.f / (1.f + expf(-x)); }

__device__ __forceinline__ bf16_t f2bf(float f) {
    unsigned u = __float_as_uint(f);
    unsigned r = (u + 0x7FFFu + ((u >> 16) & 1u)) >> 16;
    return (bf16_t)r;
}
__device__ __forceinline__ float bf2f(bf16_t h) {
    return __uint_as_float(((unsigned)h) << 16);
}

__device__ __forceinline__ float wredsum(float v) {
#pragma unroll
    for (int o = 32; o; o >>= 1) v += __shfl_xor(v, o);
    return v;
}
__device__ __forceinline__ float wredmax(float v) {
#pragma unroll
    for (int o = 32; o; o >>= 1) v = fmaxf(v, __shfl_xor(v, o));
    return v;
}

template <int OP>
__device__ __forceinline__ float blockReduce(float v, float* red) {
    const int tid = threadIdx.x, lane = tid & 63, wid = tid >> 6;
    v = (OP == 0) ? wredsum(v) : wredmax(v);
    __syncthreads();
    if (lane == 0) red[wid] = v;
    __syncthreads();
    if (tid == 0) {
        const int nw = blockDim.x >> 6;
        float r = red[0];
        for (int w = 1; w < nw; ++w) r = (OP == 0) ? r + red[w] : fmaxf(r, red[w]);
        red[0] = r;
    }
    __syncthreads();
    return red[0];
}

// ---------------- per-step kernels (4 dispatches/step) ----------------

// K1: front(t) on blocks [0,256) + out(t-1) on blocks [256,512). 512 thr.
// Block-partitioned fusion: both consume only actT(t-1) -> run concurrently.
__global__ __launch_bounds__(512) void k_fo(
        const float* __restrict__ actT, bf16_t* __restrict__ actB,
        float* __restrict__ aA, float* __restrict__ bA,
        const float* __restrict__ r_a,
        const int* __restrict__ ial, const int* __restrict__ iar,
        const float* __restrict__ W_qq, const float* __restrict__ b_qq,
        const bf16_t* __restrict__ kp_t, const bf16_t* __restrict__ vp_t,
        float* __restrict__ aO, float* __restrict__ bO,
        const float* __restrict__ r_o,
        const int* __restrict__ iol, const int* __restrict__ ior,
        const float* __restrict__ out_w, float* __restrict__ part_out,
        int doFront, int doOut, int it) {
    __shared__ float lds[8192];
    const int bid = blockIdx.x;
    const int t = threadIdx.x;
    const int lane = t & 63, wv = t >> 6;

    if (bid >= 256) {
        // ---- out(t-1): 2 units per block (thread halves) ----
        if (!doOut) return;
        const int itO = it - 1;
        const int srcO = itO & 1, dstO = srcO ^ 1;
        const int half = t >> 8, t2 = t & 255;
        const int unit = (bid - 256) * 2 + half;
        const int kp = unit >> 6, jt2 = unit & 63;
        float* sL = lds + half * 4096;   // [64 k][64 b]
#pragma unroll
        for (int c = 0; c < 16; ++c) {
            const int idx = t2 + c * 256;
            const int il = idx >> 6, bb = idx & 63;
            const int i = kp * 64 + il;
            const float pl = actT[iol[i] * NB + bb];
            const float prr = actT[ior[i] * NB + bb];
            const float r = r_o[i];
            const float aN = r * aO[srcO * 32768 + i * NB + bb] + pl * prr;
            const float bN = r * bO[srcO * 32768 + i * NB + bb] + 1.f;
            if (jt2 == 0) {
                aO[dstO * 32768 + i * NB + bb] = aN;
                bO[dstO * 32768 + i * NB + bb] = bN;
            }
            sL[il * 64 + bb] = aN * rsqrtf(bN);
        }
        __syncthreads();
        const int bb = t2 & 63;
        const int j0 = jt2 * 64 + __builtin_amdgcn_readfirstlane((t2 >> 6) & 3) * 16;
        float acc[16];
#pragma unroll
        for (int q = 0; q < 16; ++q) acc[q] = 0.f;
#pragma unroll 4
        for (int k = 0; k < 64; ++k) {
            const float sv = sL[k * 64 + bb];
            const float* wrow = out_w + (size_t)(kp * 64 + k) * NOUT + j0;  // uniform
#pragma unroll
            for (int q = 0; q < 16; ++q) acc[q] = fmaf(sv, wrow[q], acc[q]);
        }
        float* dstp = part_out + ((size_t)(kp * NB + bb)) * NOUT + j0;
#pragma unroll
        for (int q = 0; q < 16; ++q) dstp[q] = acc[q];
        return;
    }

    // ---- front(t) ----
    if (!doFront) return;
    float* syncS = lds;
    float* partK = lds + 512;
    float* qhS = lds + 1024;
    float* attnS = lds + 1152;
    const int jt = bid >> 6, b = bid & 63;
    const int src = it & 1, dst = src ^ 1;
    // phase 1: action sync (all blocks compute; jt0 persists dbuf)
    {
        const int i = t;
        const float pl = actT[ial[i] * NB + b];
        const float prr = actT[iar[i] * NB + b];
        const float r = r_a[i];
        const float aN = r * aA[src * 32768 + b * NE + i] + pl * prr;
        const float bN = r * bA[src * 32768 + b * NE + i] + 1.f;
        if (jt == 0) {
            aA[dst * 32768 + b * NE + i] = aN;
            bA[dst * 32768 + b * NE + i] = bN;
        }
        syncS[i] = aN * rsqrtf(bN);
    }
    __syncthreads();
    // phase 2: qh j-slice [jt*128, +128), k split 4-way
    {
        const int g = t >> 7, l = t & 127;
        const int j = jt * 128 + l;
        float acc = 0.f;
        const int kk0 = g * 128;
#pragma unroll 4
        for (int k = kk0; k < kk0 + 128; ++k)
            acc = fmaf(syncS[k], W_qq[k * NE + j], acc);
        partK[g * 128 + l] = acc;
    }
    __syncthreads();
    if (t < 128) {
        qhS[t] = b_qq[jt * 128 + t] + partK[t] + partK[128 + t] + partK[256 + t] + partK[384 + t];
    }
    __syncthreads();
    // phase 3: scores + softmax for heads 2jt, 2jt+1 (waves 0-1)
    if (wv < 2) {
        const int h = jt * 2 + wv, s = lane;
        const bf16_t* kpp = kp_t + ((size_t)(b * NHEADS + h) * NDH) * NS + s;
        float sc = 0.f;
#pragma unroll 8
        for (int d = 0; d < NDH; ++d) sc = fmaf(qhS[wv * 64 + d], bf2f(kpp[d * NS]), sc);
        sc *= 0.125f;
        const float mxv = wredmax(sc);
        const float ev = expf(sc - mxv);
        const float sm = wredsum(ev);
        attnS[wv * 64 + s] = ev / sm;
    }
    __syncthreads();
    // phase 4: o = attn @ V -> actB[b][h*64+d] (bf16)
    if (wv < 2) {
        const int h = jt * 2 + wv, d = lane;
        const bf16_t* vpp = vp_t + ((size_t)(b * NHEADS + h) * NS) * NDH + d;
        float o = 0.f;
#pragma unroll 8
        for (int s2 = 0; s2 < NS; ++s2) o = fmaf(attnS[wv * 64 + s2], bf2f(vpp[s2 * NDH]), o);
        actB[(size_t)b * NKSYN + h * NDH + d] = f2bf(o);
    }
}

// K2: syn MFMA GEMM(t) on blocks [0,512) + final(t-1) on blocks [512,576). 256 thr.
__global__ __launch_bounds__(256) void k_gf(
        const bf16_t* __restrict__ actB, const bf16_t* __restrict__ bpack,
        float* __restrict__ part_syn,
        const float* __restrict__ part_out, const float* __restrict__ out_b,
        float* __restrict__ out, float* __restrict__ predTemp,
        int doGemm, int doFinal, int tt, int tmode) {
    __shared__ float red[8];
    const int bid = blockIdx.x;
    const int t = threadIdx.x;
    if (bid < 512) {
        if (!doGemm) return;
        const int kp = bid >> 6, jt = bid & 63;
        const int l = t & 63;
        const int wv = t >> 6;
        const int b0 = wv * 16;
        const int row = b0 + (l & 15);
        const int kgrp = l >> 4;
        f32x4 acc[4];
#pragma unroll
        for (int js = 0; js < 4; ++js) acc[js] = (f32x4){0.f, 0.f, 0.f, 0.f};
        const int ks0 = kp * 10;
#pragma unroll 2
        for (int ks = 0; ks < 10; ++ks) {
            const int kk = (ks0 + ks) * 32;
            const short8 av = *(const short8*)(actB + (size_t)row * NKSYN + kk + kgrp * 8);
#pragma unroll
            for (int js = 0; js < 4; ++js) {
                const short8 bv = *(const short8*)(bpack +
                    ((((size_t)(jt * 4 + js)) * 80 + ks0 + ks) * 64 + l) * 8);
                acc[js] = __builtin_amdgcn_mfma_f32_16x16x32_bf16(av, bv, acc[js], 0, 0, 0);
            }
        }
#pragma unroll
        for (int js = 0; js < 4; ++js) {
#pragma unroll
            for (int r = 0; r < 4; ++r) {
                const int b = b0 + kgrp * 4 + r;
                const int j = jt * 64 + js * 16 + (l & 15);
                part_syn[((size_t)(kp * NB + b)) * NOUT + j] = acc[js][r];
            }
        }
    } else {
        if (!doFinal) return;
        const int b = bid - 512;
        float pr[16];
        float lmax = -1e30f;
#pragma unroll
        for (int c = 0; c < 16; ++c) {
            const int j = t + c * 256;
            float v = out_b[j];
#pragma unroll
            for (int kp = 0; kp < 8; ++kp) v += part_out[((size_t)(kp * NB + b)) * NOUT + j];
            pr[c] = v;
            lmax = fmaxf(lmax, v);
        }
        const float mx = blockReduce<1>(lmax, red);
        float ls = 0.f;
#pragma unroll
        for (int c = 0; c < 16; ++c) ls += expf(pr[c] - mx);
        const float se = blockReduce<0>(ls, red);
        const float logZ = mx + logf(se);
        float le = 0.f;
#pragma unroll
        for (int c = 0; c < 16; ++c) { const float lp = pr[c] - logZ; le += expf(lp) * lp; }
        const float ent = blockReduce<0>(le, red);
        const float ne = -ent * 0.12022458674074694f;  // 1/ln(4096)
        if (tmode) {
#pragma unroll
            for (int c = 0; c < 16; ++c)
                predTemp[((size_t)b * NITER + tt) * NOUT + t + c * 256] = pr[c];
        } else {
#pragma unroll
            for (int c = 0; c < 16; ++c) {
                const int j = t + c * 256;
                out[((size_t)b * NOUT + j) * NITER + tt] = pr[c];
            }
        }
        if (t == 0) {
            out[PRED_TOTAL + b * 100 + tt] = ne;
            out[PRED_TOTAL + b * 100 + 50 + tt] = 1.f - ne;
        }
    }
}

// K3: reduce 8 partials + bias_eff + GLU + LN -> trace2[pos]. grid 64 x 512.
__global__ __launch_bounds__(512) void k_glu_ln(const float* __restrict__ part,
                                                const float* __restrict__ sbe,
                                                const float* __restrict__ ln_g,
                                                const float* __restrict__ ln_b,
                                                float* __restrict__ trace2, int pos) {
    __shared__ float red[8];
    const int b = blockIdx.x;
    const int t = threadIdx.x;
    float g[4];
    float ssum = 0.f;
#pragma unroll
    for (int c = 0; c < 4; ++c) {
        const int n = t + c * 512;
        float ya = sbe[n], yb = sbe[n + ND];
#pragma unroll
        for (int kp = 0; kp < 8; ++kp) {
            ya += part[((size_t)(kp * NB + b)) * NOUT + n];
            yb += part[((size_t)(kp * NB + b)) * NOUT + n + ND];
        }
        g[c] = ya * sigm(yb);
        ssum += g[c];
    }
    const float mean = blockReduce<0>(ssum, red) * (1.f / ND);
    float vsum = 0.f;
#pragma unroll
    for (int c = 0; c < 4; ++c) { const float d = g[c] - mean; vsum += d * d; }
    const float var = blockReduce<0>(vsum, red) * (1.f / ND);
    const float rs = rsqrtf(var + 1e-5f);
#pragma unroll
    for (int c = 0; c < 4; ++c) {
        const int n = t + c * 512;
        const float st = (g[c] - mean) * rs * ln_g[n] + ln_b[n];
        trace2[((size_t)pos * ND + n) * NB + b] = st;
    }
}

// K4: per-neuron NLMs -> actT + actB rows [512,2560). grid 512 x 256. lane = b.
__global__ __launch_bounds__(256, 2) void k_nlm(const float* __restrict__ trace2,
                                                const float* __restrict__ w1t,
                                                const float* __restrict__ b1,
                                                const float* __restrict__ w2t,
                                                const float* __restrict__ b2,
                                                float* __restrict__ actT,
                                                bf16_t* __restrict__ actB, int pos) {
    __shared__ float tileA[4][64];
    const int b = threadIdx.x & 63;
    const int wvu = __builtin_amdgcn_readfirstlane(threadIdx.x >> 6);
    const int n = blockIdx.x * 4 + wvu;                    // uniform per wave
    const float* brow = b1 + n * 64;
    float acc[64];
#pragma unroll
    for (int q = 0; q < 64; ++q) acc[q] = brow[q];
    int phys = (pos + 1 < NM) ? pos + 1 : 0;
    float tr = trace2[((size_t)phys * ND + n) * NB + b];
#pragma unroll 1
    for (int m = 0; m < NM; ++m) {
        const int physN = (phys + 1 < NM) ? phys + 1 : 0;
        float trn = 0.f;
        if (m + 1 < NM) trn = trace2[((size_t)physN * ND + n) * NB + b];
        const float* wrow = w1t + ((size_t)n * NM + m) * 64;   // uniform -> s_load
#pragma unroll
        for (int q = 0; q < 64; ++q) acc[q] = fmaf(tr, wrow[q], acc[q]);
        tr = trn; phys = physN;
    }
    const float* w2r = w2t + n * 64;                            // uniform
    float z0 = b2[n * 2 + 0], z1 = b2[n * 2 + 1];
#pragma unroll
    for (int i = 0; i < 32; ++i) {
        const float hv = acc[i] * sigm(acc[32 + i]);
        z0 = fmaf(hv, w2r[i], z0);
        z1 = fmaf(hv, w2r[32 + i], z1);
    }
    const float val = z0 * sigm(z1);
    actT[n * NB + b] = val;
    tileA[wvu][b] = val;
    __syncthreads();
    const int bb = threadIdx.x >> 2, nn = threadIdx.x & 3;
    actB[(size_t)bb * NKSYN + NE + blockIdx.x * 4 + nn] = f2bf(tileA[nn][bb]);
}

// ---------------- one-time precompute kernels ----------------

__global__ __launch_bounds__(512) void k_p0(const float* __restrict__ dec_a,
                                            const float* __restrict__ dec_o,
                                            const float* __restrict__ q_b,
                                            const float* __restrict__ wq,
                                            const float* __restrict__ bq,
                                            float* __restrict__ r_a, float* __restrict__ r_o,
                                            float* __restrict__ b_qq) {
    const int t = threadIdx.x;
    r_a[t] = expf(-fminf(fmaxf(dec_a[t], 0.f), 15.f));
    r_o[t] = expf(-fminf(fmaxf(dec_o[t], 0.f), 15.f));
    float acc = bq[t];
#pragma unroll 4
    for (int k = 0; k < NE; ++k) acc = fmaf(q_b[k], wq[k * NE + t], acc);
    b_qq[t] = acc;
}

__global__ __launch_bounds__(256) void k_wqq(const float* __restrict__ q_w,
                                             const float* __restrict__ wq,
                                             float* __restrict__ W_qq) {
    const int r = blockIdx.x >> 1;
    const int c = ((blockIdx.x & 1) << 8) + threadIdx.x;
    float acc = 0.f;
#pragma unroll 4
    for (int k = 0; k < NE; ++k) acc = fmaf(q_w[r * NE + k], wq[k * NE + c], acc);
    W_qq[r * NE + c] = acc;
}

__global__ __launch_bounds__(256) void k_woT(const float* __restrict__ wo,
                                             float* __restrict__ woT) {
    __shared__ float tile[64][65];
    const int te = blockIdx.x >> 3, tj = blockIdx.x & 7;
    for (int i = threadIdx.x; i < 4096; i += 256) {
        const int r = i >> 6, c = i & 63;
        tile[r][c] = wo[(size_t)(te * 64 + r) * NE + tj * 64 + c];
    }
    __syncthreads();
    for (int i = threadIdx.x; i < 4096; i += 256) {
        const int r = i >> 6, c = i & 63;
        woT[(size_t)(tj * 64 + r) * NE + te * 64 + c] = tile[c][r];
    }
}

__global__ __launch_bounds__(256) void k_woSyn(const float* __restrict__ woT,
                                               const float* __restrict__ syn_w,
                                               float* __restrict__ woSyn) {
    const int eg = blockIdx.x >> 6, ct = blockIdx.x & 63;
    const int c = ct * 64 + (threadIdx.x & 63);
    const int e0 = eg * 64 + __builtin_amdgcn_readfirstlane(threadIdx.x >> 6) * 16;
    float acc[16];
#pragma unroll
    for (int q = 0; q < 16; ++q) acc[q] = 0.f;
#pragma unroll 4
    for (int jp = 0; jp < NE; ++jp) {
        const float wv = syn_w[(size_t)jp * NOUT + c];
        const float* er = woT + (size_t)jp * NE + e0;
#pragma unroll
        for (int q = 0; q < 16; ++q) acc[q] = fmaf(er[q], wv, acc[q]);
    }
#pragma unroll
    for (int q = 0; q < 16; ++q)
        woSyn[(size_t)(e0 + q) * NOUT + c] = acc[q];
}

__global__ __launch_bounds__(256) void k_sbe(const float* __restrict__ syn_b,
                                             const float* __restrict__ bo,
                                             const float* __restrict__ syn_w,
                                             float* __restrict__ sbe) {
    const int c = blockIdx.x * 256 + threadIdx.x;
    float acc = syn_b[c];
#pragma unroll 4
    for (int jp = 0; jp < NE; ++jp)
        acc = fmaf(bo[jp], syn_w[(size_t)jp * NOUT + c], acc);
    sbe[c] = acc;
}

// Tiled fragment-pack of combined weights [woSyn rows<512; syn_w rows 512+].
// grid 5120 (ksg 80 x bj 64) x 256. Coalesced tile read, contiguous chunk write.
__global__ __launch_bounds__(256) void k_bpack(const float* __restrict__ woSyn,
                                               const float* __restrict__ syn_w,
                                               bf16_t* __restrict__ bpack) {
    __shared__ float tile[32][65];
    const int ksg = blockIdx.x >> 6;        // k-group of 32
    const int bj = blockIdx.x & 63;         // j-tile of 64
    const int k0 = ksg * 32, j0 = bj * 64;
    for (int i = threadIdx.x; i < 2048; i += 256) {
        const int kk = i >> 6, jj = i & 63;
        const int k = k0 + kk;
        tile[kk][jj] = (k < NE) ? woSyn[(size_t)k * NOUT + j0 + jj]
                                : syn_w[(size_t)k * NOUT + j0 + jj];
    }
    __syncthreads();
    for (int i = threadIdx.x; i < 2048; i += 256) {
        const int j16 = i >> 9;             // 0..3
        const int ii = i & 511;
        const int e = ii & 7, l = ii >> 3;
        const int kk = (l >> 4) * 8 + e;
        const int jj = j16 * 16 + (l & 15);
        bpack[(((size_t)(bj * 4 + j16) * 80 + ksg) * 64) * 8 + ii] = f2bf(tile[kk][jj]);
    }
}

__global__ __launch_bounds__(256) void k_init_trace2(const float* __restrict__ st,
                                                     float* __restrict__ trace2) {
    const int idx = blockIdx.x * 256 + threadIdx.x;
    const int n = (idx >> 6) & (ND - 1);
    const int m = idx >> 17;
    trace2[idx] = st[n * NM + m];
}

#define INIT_TOTAL (NB * ND + 8 * NB * NE)
__global__ __launch_bounds__(256) void k_init_state(const float* __restrict__ sa,
                                                    float* __restrict__ actT,
                                                    bf16_t* __restrict__ actB,
                                                    float* __restrict__ zeroBase) {
    const int idx = blockIdx.x * 256 + threadIdx.x;
    if (idx >= INIT_TOTAL) return;
    if (idx < NB * ND) {
        const int b = idx & 63, n = idx >> 6;
        actT[n * NB + b] = sa[n];
        actB[(size_t)b * NKSYN + NE + n] = f2bf(sa[n]);
    } else {
        zeroBase[idx - NB * ND] = 0.f;
    }
}

// k_p1: kv = LN(feats @ kv_w + kv_b); K/V projections -> bf16 caches.
__global__ __launch_bounds__(512) void k_p1(const float* __restrict__ x,
                                            const float* __restrict__ kv_w,
                                            const float* __restrict__ kv_b,
                                            const float* __restrict__ ln_g,
                                            const float* __restrict__ ln_b,
                                            const float* __restrict__ wk,
                                            const float* __restrict__ bk,
                                            const float* __restrict__ wv,
                                            const float* __restrict__ bv,
                                            bf16_t* __restrict__ kp_t,
                                            bf16_t* __restrict__ vp_t) {
    __shared__ float kvT[NE][17];     // [e][tok]
    __shared__ float mS[16], rS[16];
    const int b = blockIdx.x >> 2, s0 = (blockIdx.x & 3) * 16;
    const int t = threadIdx.x;
    const int lane = t & 63, wvi = t >> 6;

    {
        float w[12];
#pragma unroll
        for (int c = 0; c < 12; ++c) w[c] = kv_w[c * NE + t];
        const float kb = kv_b[t];
#pragma unroll
        for (int tok = 0; tok < 16; ++tok) {
            float acc = kb;
#pragma unroll
            for (int c = 0; c < 12; ++c)
                acc = fmaf(x[b * 768 + c * 64 + s0 + tok], w[c], acc);
            kvT[t][tok] = acc;
        }
    }
    __syncthreads();
#pragma unroll
    for (int q = 0; q < 2; ++q) {
        const int tok = wvi * 2 + q;
        float s = 0.f, ss = 0.f;
#pragma unroll
        for (int i = 0; i < 8; ++i) {
            const float v = kvT[lane * 8 + i][tok];
            s += v; ss = fmaf(v, v, ss);
        }
        s = wredsum(s); ss = wredsum(ss);
        if (lane == 0) {
            const float mean = s * (1.f / NE);
            mS[tok] = mean;
            rS[tok] = rsqrtf(ss * (1.f / NE) - mean * mean + 1e-5f);
        }
    }
    __syncthreads();
    {
        const float g = ln_g[t], bb2 = ln_b[t];
#pragma unroll
        for (int tok = 0; tok < 16; ++tok)
            kvT[t][tok] = (kvT[t][tok] - mS[tok]) * rS[tok] * g + bb2;
    }
    __syncthreads();
    {
        const int j = t;
        float kpv[16], vpv[16];
        const float bk_ = bk[j], bv_ = bv[j];
#pragma unroll
        for (int tok = 0; tok < 16; ++tok) { kpv[tok] = bk_; vpv[tok] = bv_; }
        for (int k = 0; k < NE; ++k) {
            const float wkv = wk[k * NE + j];
            const float wvv = wv[k * NE + j];
            const float* kr = &kvT[k][0];
#pragma unroll
            for (int tok = 0; tok < 16; ++tok) {
                const float kvv = kr[tok];
                kpv[tok] = fmaf(kvv, wkv, kpv[tok]);
                vpv[tok] = fmaf(kvv, wvv, vpv[tok]);
            }
        }
        const int h = j >> 6, dd = j & 63;
#pragma unroll
        for (int tok = 0; tok < 16; ++tok) {
            const int s = s0 + tok;
            kp_t[((size_t)(b * NHEADS + h) * NDH + dd) * NS + s] = f2bf(kpv[tok]);
            vp_t[((size_t)(b * NHEADS + h) * NS + s) * NDH + dd] = f2bf(vpv[tok]);
        }
    }
}

__global__ __launch_bounds__(256) void k_w1t(const float* __restrict__ w1,
                                             float* __restrict__ w1t) {
    __shared__ float tile[64][65];
    const int m = blockIdx.x >> 5, n0 = (blockIdx.x & 31) << 6;
    for (int i = threadIdx.x; i < 4096; i += 256) {
        const int hh = i >> 6, nn = i & 63;
        tile[hh][nn] = w1[(size_t)(m * 64 + hh) * ND + n0 + nn];
    }
    __syncthreads();
    for (int i = threadIdx.x; i < 4096; i += 256) {
        const int nn = i >> 6, hh = i & 63;
        w1t[((size_t)(n0 + nn) * NM + m) * 64 + hh] = tile[hh][nn];
    }
}

__global__ __launch_bounds__(256) void k_w2t(const float* __restrict__ w2,
                                             float* __restrict__ w2t) {
    const int idx = blockIdx.x * 256 + threadIdx.x;
    const int i = idx & 31;
    const int c = (idx >> 5) & 1;
    const int n = idx >> 6;
    w2t[idx] = w2[(size_t)(i * 2 + c) * ND + n];
}

__global__ __launch_bounds__(256) void k_transpose(const float* __restrict__ predTemp,
                                                   float* __restrict__ out) {
    __shared__ float tile[NS * NITER];
    const int b = blockIdx.x >> 6;
    const int j0 = (blockIdx.x & 63) * 64;
    for (int i = threadIdx.x; i < 3200; i += 256) {
        const int tt = i >> 6, jj = i & 63;
        tile[jj * NITER + tt] = predTemp[((size_t)b * NITER + tt) * NOUT + j0 + jj];
    }
    __syncthreads();
    float* dst = out + ((size_t)b * NOUT + j0) * NITER;
    for (int i = threadIdx.x; i < 3200; i += 256) dst[i] = tile[i];
}

extern "C" void kernel_launch(void* const* d_in, const int* in_sizes, int n_in,
                              void* d_out, int out_size, void* d_ws, size_t ws_size,
                              hipStream_t stream) {
    const float* x        = (const float*)d_in[0];
    const float* kv_w     = (const float*)d_in[1];
    const float* kv_b     = (const float*)d_in[2];
    const float* kv_ln_g  = (const float*)d_in[3];
    const float* kv_ln_b  = (const float*)d_in[4];
    const float* q_w      = (const float*)d_in[5];
    const float* q_b      = (const float*)d_in[6];
    const float* wq       = (const float*)d_in[7];
    const float* wk       = (const float*)d_in[8];
    const float* wv       = (const float*)d_in[9];
    const float* wo       = (const float*)d_in[10];
    const float* bq       = (const float*)d_in[11];
    const float* bk       = (const float*)d_in[12];
    const float* bv       = (const float*)d_in[13];
    const float* bo       = (const float*)d_in[14];
    const float* syn_w    = (const float*)d_in[15];
    const float* syn_b    = (const float*)d_in[16];
    const float* syn_ln_g = (const float*)d_in[17];
    const float* syn_ln_b = (const float*)d_in[18];
    const float* nlm1_w   = (const float*)d_in[19];
    const float* nlm1_b   = (const float*)d_in[20];
    const float* nlm2_w   = (const float*)d_in[21];
    const float* nlm2_b   = (const float*)d_in[22];
    const float* start_a  = (const float*)d_in[23];
    const float* start_tr = (const float*)d_in[24];
    const float* dec_a    = (const float*)d_in[25];
    const float* dec_o    = (const float*)d_in[26];
    const float* out_w    = (const float*)d_in[27];
    const float* out_b    = (const float*)d_in[28];
    const int* ial        = (const int*)d_in[29];
    const int* iar        = (const int*)d_in[30];
    const int* iol        = (const int*)d_in[31];
    const int* ior        = (const int*)d_in[32];
    float* out = (float*)d_out;

    float* ws = (float*)d_ws;
    size_t off = 0;
    auto alloc = [&](size_t n) { float* p = ws + off; off += n; return p; };
    float* actT     = alloc((size_t)ND * NB);
    bf16_t* actB    = (bf16_t*)alloc((size_t)NB * NKSYN / 2);
    bf16_t* kp_t    = (bf16_t*)alloc((size_t)NB * NE * NS / 2);
    bf16_t* vp_t    = (bf16_t*)alloc((size_t)NB * NE * NS / 2);
    float* W_qq     = alloc((size_t)NE * NE);
    float* woT      = alloc((size_t)NE * NE);
    float* woSyn    = alloc((size_t)NE * NOUT);
    bf16_t* bpack   = (bf16_t*)alloc((size_t)NKSYN * NOUT / 2);
    float* sbe      = alloc(NOUT);
    float* b_qq     = alloc(NE);
    float* r_a      = alloc(NE);
    float* r_o      = alloc(NE);
    float* aA       = alloc((size_t)2 * NB * NE);       // zero span start
    float* bA       = alloc((size_t)2 * NB * NE);
    float* aO       = alloc((size_t)2 * NB * NE);
    float* bO       = alloc((size_t)2 * NB * NE);
    float* trace2   = alloc((size_t)NM * ND * NB);
    float* part_syn = alloc((size_t)8 * NB * NOUT);
    float* part_out = alloc((size_t)8 * NB * NOUT);
    float* w1t      = alloc((size_t)ND * NM * 64);
    float* w2t      = alloc((size_t)ND * 64);
    int tmode = 0;
    float* predTemp = nullptr;
    if ((off + (size_t)PRED_TOTAL) * sizeof(float) <= ws_size) {
        predTemp = alloc((size_t)PRED_TOTAL);
        tmode = 1;
    }

    k_p0<<<1, 512, 0, stream>>>(dec_a, dec_o, q_b, wq, bq, r_a, r_o, b_qq);
    k_wqq<<<1024, 256, 0, stream>>>(q_w, wq, W_qq);
    k_woT<<<64, 256, 0, stream>>>(wo, woT);
    k_woSyn<<<512, 256, 0, stream>>>(woT, syn_w, woSyn);
    k_sbe<<<16, 256, 0, stream>>>(syn_b, bo, syn_w, sbe);
    k_bpack<<<5120, 256, 0, stream>>>(woSyn, syn_w, bpack);
    k_init_trace2<<<(NM * ND * NB) / 256, 256, 0, stream>>>(start_tr, trace2);
    k_init_state<<<(INIT_TOTAL + 255) / 256, 256, 0, stream>>>(start_a, actT, actB, aA);
    k_p1<<<256, 512, 0, stream>>>(x, kv_w, kv_b, kv_ln_g, kv_ln_b, wk, bk, wv, bv, kp_t, vp_t);
    k_w1t<<<800, 256, 0, stream>>>(nlm1_w, w1t);
    k_w2t<<<(ND * 64) / 256, 256, 0, stream>>>(nlm2_w, w2t);

    for (int t = 0; t < NITER; ++t) {
        k_fo<<<512, 512, 0, stream>>>(actT, actB, aA, bA, r_a, ial, iar, W_qq, b_qq,
                                      kp_t, vp_t, aO, bO, r_o, iol, ior, out_w, part_out,
                                      1, (t > 0) ? 1 : 0, t);
        k_gf<<<576, 256, 0, stream>>>(actB, bpack, part_syn, part_out, out_b, out, predTemp,
                                      1, (t > 0) ? 1 : 0, t - 1, tmode);
        k_glu_ln<<<NB, 512, 0, stream>>>(part_syn, sbe, syn_ln_g, syn_ln_b, trace2, t % NM);
        k_nlm<<<512, 256, 0, stream>>>(trace2, w1t, nlm1_b, w2t, nlm2_b, actT, actB, t % NM);
    }
    // tail: out(49) then final(49)
    k_fo<<<512, 512, 0, stream>>>(actT, actB, aA, bA, r_a, ial, iar, W_qq, b_qq,
                                  kp_t, vp_t, aO, bO, r_o, iol, ior, out_w, part_out,
                                  0, 1, NITER);
    k_gf<<<576, 256, 0, stream>>>(actB, bpack, part_syn, part_out, out_b, out, predTemp,
                                  0, 1, NITER - 1, tmode);
    if (tmode) k_transpose<<<NB * 64, 256, 0, stream>>>(predTemp, out);
}

// Round 15
// 3868.878 us; speedup vs baseline: 5.5810x; 1.0205x over previous
//
#include <hip/hip_runtime.h>
#include <math.h>

#define NB 64
#define ND 2048
#define NE 512
#define NM 25
#define NOUT 4096
#define NHEADS 8
#define NDH 64
#define NS 64
#define NITER 50
#define NKSYN 2560
#define PRED_TOTAL (NB * NOUT * NITER)   /* 13107200 */

typedef unsigned short bf16_t;
typedef __attribute__((ext_vector_type(8))) short short8;
typedef __attribute__((ext_vector_type(4))) float f32x4;

__device__ __forceinline__ float sigm(float x) { return 1.f / (1.f + expf(-x)); }

__device__ __forceinline__ bf16_t f2bf(float f) {
    unsigned u = __float_as_uint(f);
    unsigned r = (u + 0x7FFFu + ((u >> 16) & 1u)) >> 16;
    return (bf16_t)r;
}
__device__ __forceinline__ float bf2f(bf16_t h) {
    return __uint_as_float(((unsigned)h) << 16);
}

__device__ __forceinline__ float wredsum(float v) {
#pragma unroll
    for (int o = 32; o; o >>= 1) v += __shfl_xor(v, o);
    return v;
}
__device__ __forceinline__ float wredmax(float v) {
#pragma unroll
    for (int o = 32; o; o >>= 1) v = fmaxf(v, __shfl_xor(v, o));
    return v;
}

template <int OP>
__device__ __forceinline__ float blockReduce(float v, float* red) {
    const int tid = threadIdx.x, lane = tid & 63, wid = tid >> 6;
    v = (OP == 0) ? wredsum(v) : wredmax(v);
    __syncthreads();
    if (lane == 0) red[wid] = v;
    __syncthreads();
    if (tid == 0) {
        const int nw = blockDim.x >> 6;
        float r = red[0];
        for (int w = 1; w < nw; ++w) r = (OP == 0) ? r + red[w] : fmaxf(r, red[w]);
        red[0] = r;
    }
    __syncthreads();
    return red[0];
}

// ---------------- per-step kernels (4 dispatches/step) ----------------

// K1: front(t) on blocks [0,256) + out(t-1) on blocks [256,512). 512 thr.
__global__ __launch_bounds__(512) void k_fo(
        const float* __restrict__ actT, bf16_t* __restrict__ actB,
        float* __restrict__ aA, float* __restrict__ bA,
        const float* __restrict__ r_a,
        const int* __restrict__ ial, const int* __restrict__ iar,
        const float* __restrict__ W_qq, const float* __restrict__ b_qq,
        const bf16_t* __restrict__ kvp,
        float* __restrict__ aO, float* __restrict__ bO,
        const float* __restrict__ r_o,
        const int* __restrict__ iol, const int* __restrict__ ior,
        const float* __restrict__ out_w, float* __restrict__ part_out,
        int doFront, int doOut, int it) {
    __shared__ float lds[8192];
    const int bid = blockIdx.x;
    const int t = threadIdx.x;
    const int lane = t & 63, wv = t >> 6;

    if (bid >= 256) {
        // ---- out(t-1): 2 units per block (thread halves) ----
        if (!doOut) return;
        const int itO = it - 1;
        const int srcO = itO & 1, dstO = srcO ^ 1;
        const int half = t >> 8, t2 = t & 255;
        const int unit = (bid - 256) * 2 + half;
        const int kp = unit >> 6, jt2 = unit & 63;
        float* sL = lds + half * 4096;   // [64 k][64 b]
#pragma unroll
        for (int c = 0; c < 16; ++c) {
            const int idx = t2 + c * 256;
            const int il = idx >> 6, bb = idx & 63;
            const int i = kp * 64 + il;
            const float pl = actT[iol[i] * NB + bb];
            const float prr = actT[ior[i] * NB + bb];
            const float r = r_o[i];
            const float aN = r * aO[srcO * 32768 + i * NB + bb] + pl * prr;
            const float bN = r * bO[srcO * 32768 + i * NB + bb] + 1.f;
            if (jt2 == 0) {
                aO[dstO * 32768 + i * NB + bb] = aN;
                bO[dstO * 32768 + i * NB + bb] = bN;
            }
            sL[il * 64 + bb] = aN * rsqrtf(bN);
        }
        __syncthreads();
        const int bb = t2 & 63;
        const int j0 = jt2 * 64 + __builtin_amdgcn_readfirstlane((t2 >> 6) & 3) * 16;
        float acc[16];
#pragma unroll
        for (int q = 0; q < 16; ++q) acc[q] = 0.f;
#pragma unroll 4
        for (int k = 0; k < 64; ++k) {
            const float sv = sL[k * 64 + bb];
            const float* wrow = out_w + (size_t)(kp * 64 + k) * NOUT + j0;  // uniform
#pragma unroll
            for (int q = 0; q < 16; ++q) acc[q] = fmaf(sv, wrow[q], acc[q]);
        }
        float* dstp = part_out + ((size_t)(kp * NB + bb)) * NOUT + j0;
#pragma unroll
        for (int q = 0; q < 16; ++q) dstp[q] = acc[q];
        return;
    }

    // ---- front(t) ----
    if (!doFront) return;
    float* syncS = lds;
    float* partK = lds + 512;
    float* qhS = lds + 1024;
    float* attnS = lds + 1152;
    const int jt = bid >> 6, b = bid & 63;
    const int src = it & 1, dst = src ^ 1;
    // phase 1: action sync (all blocks compute; jt0 persists dbuf)
    {
        const int i = t;
        const float pl = actT[ial[i] * NB + b];
        const float prr = actT[iar[i] * NB + b];
        const float r = r_a[i];
        const float aN = r * aA[src * 32768 + b * NE + i] + pl * prr;
        const float bN = r * bA[src * 32768 + b * NE + i] + 1.f;
        if (jt == 0) {
            aA[dst * 32768 + b * NE + i] = aN;
            bA[dst * 32768 + b * NE + i] = bN;
        }
        syncS[i] = aN * rsqrtf(bN);
    }
    __syncthreads();
    // phase 2: qh j-slice [jt*128, +128), k split 4-way
    {
        const int g = t >> 7, l = t & 127;
        const int j = jt * 128 + l;
        float acc = 0.f;
        const int kk0 = g * 128;
#pragma unroll 4
        for (int k = kk0; k < kk0 + 128; ++k)
            acc = fmaf(syncS[k], W_qq[k * NE + j], acc);
        partK[g * 128 + l] = acc;
    }
    __syncthreads();
    if (t < 128) {
        qhS[t] = b_qq[jt * 128 + t] + partK[t] + partK[128 + t] + partK[256 + t] + partK[384 + t];
    }
    __syncthreads();
    // phase 3: scores + softmax for heads 2jt, 2jt+1 (waves 0-1).
    // K rows contiguous per lane in kvp layout.
    if (wv < 2) {
        const int h = jt * 2 + wv, s = lane;
        const bf16_t* kpp = kvp + ((size_t)(b * NS + s) * 1024 + h * NDH);
        float sc = 0.f;
#pragma unroll 8
        for (int d = 0; d < NDH; ++d) sc = fmaf(qhS[wv * 64 + d], bf2f(kpp[d]), sc);
        sc *= 0.125f;
        const float mxv = wredmax(sc);
        const float ev = expf(sc - mxv);
        const float sm = wredsum(ev);
        attnS[wv * 64 + s] = ev / sm;
    }
    __syncthreads();
    // phase 4: o = attn @ V -> actB[b][h*64+d] (bf16). V columns coalesced.
    if (wv < 2) {
        const int h = jt * 2 + wv, d = lane;
        const bf16_t* vpp = kvp + ((size_t)(b * NS) * 1024 + NE + h * NDH + d);
        float o = 0.f;
#pragma unroll 8
        for (int s2 = 0; s2 < NS; ++s2) o = fmaf(attnS[wv * 64 + s2], bf2f(vpp[(size_t)s2 * 1024]), o);
        actB[(size_t)b * NKSYN + h * NDH + d] = f2bf(o);
    }
}

// K2: syn MFMA GEMM(t) on blocks [0,512) + final(t-1) on blocks [512,576). 256 thr.
__global__ __launch_bounds__(256) void k_gf(
        const bf16_t* __restrict__ actB, const bf16_t* __restrict__ bpack,
        float* __restrict__ part_syn,
        const float* __restrict__ part_out, const float* __restrict__ out_b,
        float* __restrict__ out, float* __restrict__ predTemp,
        int doGemm, int doFinal, int tt, int tmode) {
    __shared__ float red[8];
    const int bid = blockIdx.x;
    const int t = threadIdx.x;
    if (bid < 512) {
        if (!doGemm) return;
        const int kp = bid >> 6, jt = bid & 63;
        const int l = t & 63;
        const int wv = t >> 6;
        const int b0 = wv * 16;
        const int row = b0 + (l & 15);
        const int kgrp = l >> 4;
        f32x4 acc[4];
#pragma unroll
        for (int js = 0; js < 4; ++js) acc[js] = (f32x4){0.f, 0.f, 0.f, 0.f};
        const int ks0 = kp * 10;
#pragma unroll 2
        for (int ks = 0; ks < 10; ++ks) {
            const int kk = (ks0 + ks) * 32;
            const short8 av = *(const short8*)(actB + (size_t)row * NKSYN + kk + kgrp * 8);
#pragma unroll
            for (int js = 0; js < 4; ++js) {
                const short8 bv = *(const short8*)(bpack +
                    ((((size_t)(jt * 4 + js)) * 80 + ks0 + ks) * 64 + l) * 8);
                acc[js] = __builtin_amdgcn_mfma_f32_16x16x32_bf16(av, bv, acc[js], 0, 0, 0);
            }
        }
#pragma unroll
        for (int js = 0; js < 4; ++js) {
#pragma unroll
            for (int r = 0; r < 4; ++r) {
                const int b = b0 + kgrp * 4 + r;
                const int j = jt * 64 + js * 16 + (l & 15);
                part_syn[((size_t)(kp * NB + b)) * NOUT + j] = acc[js][r];
            }
        }
    } else {
        if (!doFinal) return;
        const int b = bid - 512;
        float pr[16];
        float lmax = -1e30f;
#pragma unroll
        for (int c = 0; c < 16; ++c) {
            const int j = t + c * 256;
            float v = out_b[j];
#pragma unroll
            for (int kp = 0; kp < 8; ++kp) v += part_out[((size_t)(kp * NB + b)) * NOUT + j];
            pr[c] = v;
            lmax = fmaxf(lmax, v);
        }
        const float mx = blockReduce<1>(lmax, red);
        float ls = 0.f;
#pragma unroll
        for (int c = 0; c < 16; ++c) ls += expf(pr[c] - mx);
        const float se = blockReduce<0>(ls, red);
        const float logZ = mx + logf(se);
        float le = 0.f;
#pragma unroll
        for (int c = 0; c < 16; ++c) { const float lp = pr[c] - logZ; le += expf(lp) * lp; }
        const float ent = blockReduce<0>(le, red);
        const float ne = -ent * 0.12022458674074694f;  // 1/ln(4096)
        if (tmode) {
#pragma unroll
            for (int c = 0; c < 16; ++c)
                predTemp[((size_t)b * NITER + tt) * NOUT + t + c * 256] = pr[c];
        } else {
#pragma unroll
            for (int c = 0; c < 16; ++c) {
                const int j = t + c * 256;
                out[((size_t)b * NOUT + j) * NITER + tt] = pr[c];
            }
        }
        if (t == 0) {
            out[PRED_TOTAL + b * 100 + tt] = ne;
            out[PRED_TOTAL + b * 100 + 50 + tt] = 1.f - ne;
        }
    }
}

// K3: reduce 8 partials + bias_eff + GLU + LN -> trace2[pos]. grid 64 x 512.
__global__ __launch_bounds__(512) void k_glu_ln(const float* __restrict__ part,
                                                const float* __restrict__ sbe,
                                                const float* __restrict__ ln_g,
                                                const float* __restrict__ ln_b,
                                                float* __restrict__ trace2, int pos) {
    __shared__ float red[8];
    const int b = blockIdx.x;
    const int t = threadIdx.x;
    float g[4];
    float ssum = 0.f;
#pragma unroll
    for (int c = 0; c < 4; ++c) {
        const int n = t + c * 512;
        float ya = sbe[n], yb = sbe[n + ND];
#pragma unroll
        for (int kp = 0; kp < 8; ++kp) {
            ya += part[((size_t)(kp * NB + b)) * NOUT + n];
            yb += part[((size_t)(kp * NB + b)) * NOUT + n + ND];
        }
        g[c] = ya * sigm(yb);
        ssum += g[c];
    }
    const float mean = blockReduce<0>(ssum, red) * (1.f / ND);
    float vsum = 0.f;
#pragma unroll
    for (int c = 0; c < 4; ++c) { const float d = g[c] - mean; vsum += d * d; }
    const float var = blockReduce<0>(vsum, red) * (1.f / ND);
    const float rs = rsqrtf(var + 1e-5f);
#pragma unroll
    for (int c = 0; c < 4; ++c) {
        const int n = t + c * 512;
        const float st = (g[c] - mean) * rs * ln_g[n] + ln_b[n];
        trace2[((size_t)pos * ND + n) * NB + b] = st;
    }
}

// K4: per-neuron NLMs -> actT + actB rows [512,2560). grid 512 x 256. lane = b.
__global__ __launch_bounds__(256, 2) void k_nlm(const float* __restrict__ trace2,
                                                const float* __restrict__ w1t,
                                                const float* __restrict__ b1,
                                                const float* __restrict__ w2t,
                                                const float* __restrict__ b2,
                                                float* __restrict__ actT,
                                                bf16_t* __restrict__ actB, int pos) {
    __shared__ float tileA[4][64];
    const int b = threadIdx.x & 63;
    const int wvu = __builtin_amdgcn_readfirstlane(threadIdx.x >> 6);
    const int n = blockIdx.x * 4 + wvu;                    // uniform per wave
    const float* brow = b1 + n * 64;
    float acc[64];
#pragma unroll
    for (int q = 0; q < 64; ++q) acc[q] = brow[q];
    int phys = (pos + 1 < NM) ? pos + 1 : 0;
    float tr = trace2[((size_t)phys * ND + n) * NB + b];
#pragma unroll 1
    for (int m = 0; m < NM; ++m) {
        const int physN = (phys + 1 < NM) ? phys + 1 : 0;
        float trn = 0.f;
        if (m + 1 < NM) trn = trace2[((size_t)physN * ND + n) * NB + b];
        const float* wrow = w1t + ((size_t)n * NM + m) * 64;   // uniform -> s_load
#pragma unroll
        for (int q = 0; q < 64; ++q) acc[q] = fmaf(tr, wrow[q], acc[q]);
        tr = trn; phys = physN;
    }
    const float* w2r = w2t + n * 64;                            // uniform
    float z0 = b2[n * 2 + 0], z1 = b2[n * 2 + 1];
#pragma unroll
    for (int i = 0; i < 32; ++i) {
        const float hv = acc[i] * sigm(acc[32 + i]);
        z0 = fmaf(hv, w2r[i], z0);
        z1 = fmaf(hv, w2r[32 + i], z1);
    }
    const float val = z0 * sigm(z1);
    actT[n * NB + b] = val;
    tileA[wvu][b] = val;
    __syncthreads();
    const int bb = threadIdx.x >> 2, nn = threadIdx.x & 3;
    actB[(size_t)bb * NKSYN + NE + blockIdx.x * 4 + nn] = f2bf(tileA[nn][bb]);
}

// ---------------- one-time precompute kernels ----------------

__global__ __launch_bounds__(512) void k_p0(const float* __restrict__ dec_a,
                                            const float* __restrict__ dec_o,
                                            const float* __restrict__ q_b,
                                            const float* __restrict__ wq,
                                            const float* __restrict__ bq,
                                            float* __restrict__ r_a, float* __restrict__ r_o,
                                            float* __restrict__ b_qq) {
    const int t = threadIdx.x;
    r_a[t] = expf(-fminf(fmaxf(dec_a[t], 0.f), 15.f));
    r_o[t] = expf(-fminf(fmaxf(dec_o[t], 0.f), 15.f));
    float acc = bq[t];
#pragma unroll 4
    for (int k = 0; k < NE; ++k) acc = fmaf(q_b[k], wq[k * NE + t], acc);
    b_qq[t] = acc;
}

__global__ __launch_bounds__(256) void k_wqq(const float* __restrict__ q_w,
                                             const float* __restrict__ wq,
                                             float* __restrict__ W_qq) {
    const int r = blockIdx.x >> 1;
    const int c = ((blockIdx.x & 1) << 8) + threadIdx.x;
    float acc = 0.f;
#pragma unroll 4
    for (int k = 0; k < NE; ++k) acc = fmaf(q_w[r * NE + k], wq[k * NE + c], acc);
    W_qq[r * NE + c] = acc;
}

__global__ __launch_bounds__(256) void k_woT(const float* __restrict__ wo,
                                             float* __restrict__ woT) {
    __shared__ float tile[64][65];
    const int te = blockIdx.x >> 3, tj = blockIdx.x & 7;
    for (int i = threadIdx.x; i < 4096; i += 256) {
        const int r = i >> 6, c = i & 63;
        tile[r][c] = wo[(size_t)(te * 64 + r) * NE + tj * 64 + c];
    }
    __syncthreads();
    for (int i = threadIdx.x; i < 4096; i += 256) {
        const int r = i >> 6, c = i & 63;
        woT[(size_t)(tj * 64 + r) * NE + te * 64 + c] = tile[c][r];
    }
}

__global__ __launch_bounds__(256) void k_woSyn(const float* __restrict__ woT,
                                               const float* __restrict__ syn_w,
                                               float* __restrict__ woSyn) {
    const int eg = blockIdx.x >> 6, ct = blockIdx.x & 63;
    const int c = ct * 64 + (threadIdx.x & 63);
    const int e0 = eg * 64 + __builtin_amdgcn_readfirstlane(threadIdx.x >> 6) * 16;
    float acc[16];
#pragma unroll
    for (int q = 0; q < 16; ++q) acc[q] = 0.f;
#pragma unroll 4
    for (int jp = 0; jp < NE; ++jp) {
        const float wv = syn_w[(size_t)jp * NOUT + c];
        const float* er = woT + (size_t)jp * NE + e0;
#pragma unroll
        for (int q = 0; q < 16; ++q) acc[q] = fmaf(er[q], wv, acc[q]);
    }
#pragma unroll
    for (int q = 0; q < 16; ++q)
        woSyn[(size_t)(e0 + q) * NOUT + c] = acc[q];
}

__global__ __launch_bounds__(256) void k_sbe(const float* __restrict__ syn_b,
                                             const float* __restrict__ bo,
                                             const float* __restrict__ syn_w,
                                             float* __restrict__ sbe) {
    const int c = blockIdx.x * 256 + threadIdx.x;
    float acc = syn_b[c];
#pragma unroll 4
    for (int jp = 0; jp < NE; ++jp)
        acc = fmaf(bo[jp], syn_w[(size_t)jp * NOUT + c], acc);
    sbe[c] = acc;
}

// Tiled fragment-pack of combined weights [woSyn rows<512; syn_w rows 512+].
__global__ __launch_bounds__(256) void k_bpack(const float* __restrict__ woSyn,
                                               const float* __restrict__ syn_w,
                                               bf16_t* __restrict__ bpack) {
    __shared__ float tile[32][65];
    const int ksg = blockIdx.x >> 6;
    const int bj = blockIdx.x & 63;
    const int k0 = ksg * 32, j0 = bj * 64;
    for (int i = threadIdx.x; i < 2048; i += 256) {
        const int kk = i >> 6, jj = i & 63;
        const int k = k0 + kk;
        tile[kk][jj] = (k < NE) ? woSyn[(size_t)k * NOUT + j0 + jj]
                                : syn_w[(size_t)k * NOUT + j0 + jj];
    }
    __syncthreads();
    for (int i = threadIdx.x; i < 2048; i += 256) {
        const int j16 = i >> 9;
        const int ii = i & 511;
        const int e = ii & 7, l = ii >> 3;
        const int kk = (l >> 4) * 8 + e;
        const int jj = j16 * 16 + (l & 15);
        bpack[(((size_t)(bj * 4 + j16) * 80 + ksg) * 64) * 8 + ii] = f2bf(tile[kk][jj]);
    }
}

// Pack [wk | wv] (512 x 1024) into MFMA B-fragment order. grid 256 (ksg 16 x bj 16).
__global__ __launch_bounds__(256) void k_wkvpack(const float* __restrict__ wk,
                                                 const float* __restrict__ wv,
                                                 bf16_t* __restrict__ wkvpack) {
    __shared__ float tile[32][65];
    const int ksg = blockIdx.x >> 4;
    const int bj = blockIdx.x & 15;
    const int k0 = ksg * 32, j0 = bj * 64;
    for (int i = threadIdx.x; i < 2048; i += 256) {
        const int kk = i >> 6, jj = i & 63;
        const int k = k0 + kk, j = j0 + jj;
        tile[kk][jj] = (j < NE) ? wk[(size_t)k * NE + j] : wv[(size_t)k * NE + (j - NE)];
    }
    __syncthreads();
    for (int i = threadIdx.x; i < 2048; i += 256) {
        const int j16 = i >> 9;
        const int ii = i & 511;
        const int e = ii & 7, l = ii >> 3;
        const int kk = (l >> 4) * 8 + e;
        const int jj = j16 * 16 + (l & 15);
        wkvpack[(((size_t)(bj * 4 + j16) * 16 + ksg) * 64) * 8 + ii] = f2bf(tile[kk][jj]);
    }
}

__global__ __launch_bounds__(256) void k_init_trace2(const float* __restrict__ st,
                                                     float* __restrict__ trace2) {
    const int idx = blockIdx.x * 256 + threadIdx.x;
    const int n = (idx >> 6) & (ND - 1);
    const int m = idx >> 17;
    trace2[idx] = st[n * NM + m];
}

#define INIT_TOTAL (NB * ND + 8 * NB * NE)
__global__ __launch_bounds__(256) void k_init_state(const float* __restrict__ sa,
                                                    float* __restrict__ actT,
                                                    bf16_t* __restrict__ actB,
                                                    float* __restrict__ zeroBase) {
    const int idx = blockIdx.x * 256 + threadIdx.x;
    if (idx >= INIT_TOTAL) return;
    if (idx < NB * ND) {
        const int b = idx & 63, n = idx >> 6;
        actT[n * NB + b] = sa[n];
        actB[(size_t)b * NKSYN + NE + n] = f2bf(sa[n]);
    } else {
        zeroBase[idx - NB * ND] = 0.f;
    }
}

// k_p1a: kvn = LN(feats @ kv_w + kv_b) -> kvnB bf16 [token][e].
// grid 256 (b 64 x sg 4, 16 tokens each) x 512.
__global__ __launch_bounds__(512) void k_p1a(const float* __restrict__ x,
                                             const float* __restrict__ kv_w,
                                             const float* __restrict__ kv_b,
                                             const float* __restrict__ ln_g,
                                             const float* __restrict__ ln_b,
                                             bf16_t* __restrict__ kvnB) {
    __shared__ float kvT[NE][17];     // [e][tok]
    __shared__ float mS[16], rS[16];
    const int b = blockIdx.x >> 2, s0 = (blockIdx.x & 3) * 16;
    const int t = threadIdx.x;
    const int lane = t & 63, wvi = t >> 6;

    {
        float w[12];
#pragma unroll
        for (int c = 0; c < 12; ++c) w[c] = kv_w[c * NE + t];
        const float kb = kv_b[t];
#pragma unroll
        for (int tok = 0; tok < 16; ++tok) {
            float acc = kb;
#pragma unroll
            for (int c = 0; c < 12; ++c)
                acc = fmaf(x[b * 768 + c * 64 + s0 + tok], w[c], acc);
            kvT[t][tok] = acc;
        }
    }
    __syncthreads();
#pragma unroll
    for (int q = 0; q < 2; ++q) {
        const int tok = wvi * 2 + q;
        float s = 0.f, ss = 0.f;
#pragma unroll
        for (int i = 0; i < 8; ++i) {
            const float v = kvT[lane + 64 * i][tok];   // stride-17 rows, 17 odd -> conflict-free
            s += v; ss = fmaf(v, v, ss);
        }
        s = wredsum(s); ss = wredsum(ss);
        if (lane == 0) {
            const float mean = s * (1.f / NE);
            mS[tok] = mean;
            rS[tok] = rsqrtf(ss * (1.f / NE) - mean * mean + 1e-5f);
        }
    }
    __syncthreads();
    {
        const float g = ln_g[t], bb2 = ln_b[t];
#pragma unroll
        for (int tok = 0; tok < 16; ++tok) {
            const float kvn = (kvT[t][tok] - mS[tok]) * rS[tok] * g + bb2;
            kvnB[(size_t)(b * 64 + s0 + tok) * NE + t] = f2bf(kvn);
        }
    }
}

// k_p1b: MFMA GEMM [4096 tokens x 1024 (K|V) x 512] -> kvp bf16 [token][1024].
// grid 1024 (mt 64 x nt 16) x 256.
__global__ __launch_bounds__(256, 2) void k_p1b(const bf16_t* __restrict__ kvnB,
                                                const bf16_t* __restrict__ wkvpack,
                                                const float* __restrict__ bk,
                                                const float* __restrict__ bv,
                                                bf16_t* __restrict__ kvp) {
    const int mt = blockIdx.x >> 4, nt = blockIdx.x & 15;
    const int l = threadIdx.x & 63;
    const int wv = threadIdx.x >> 6;
    const int row0 = mt * 64 + wv * 16;
    const int row = row0 + (l & 15);
    const int kgrp = l >> 4;
    f32x4 acc[4];
#pragma unroll
    for (int js = 0; js < 4; ++js) acc[js] = (f32x4){0.f, 0.f, 0.f, 0.f};
#pragma unroll 2
    for (int ks = 0; ks < 16; ++ks) {
        const short8 av = *(const short8*)(kvnB + (size_t)row * NE + ks * 32 + kgrp * 8);
#pragma unroll
        for (int js = 0; js < 4; ++js) {
            const short8 bv8 = *(const short8*)(wkvpack +
                ((((size_t)(nt * 4 + js)) * 16 + ks) * 64 + l) * 8);
            acc[js] = __builtin_amdgcn_mfma_f32_16x16x32_bf16(av, bv8, acc[js], 0, 0, 0);
        }
    }
#pragma unroll
    for (int js = 0; js < 4; ++js) {
#pragma unroll
        for (int r = 0; r < 4; ++r) {
            const int tok = row0 + kgrp * 4 + r;
            const int j = nt * 64 + js * 16 + (l & 15);
            const float bias = (j < NE) ? bk[j] : bv[j - NE];
            kvp[(size_t)tok * 1024 + j] = f2bf(acc[js][r] + bias);
        }
    }
}

__global__ __launch_bounds__(256) void k_w1t(const float* __restrict__ w1,
                                             float* __restrict__ w1t) {
    __shared__ float tile[64][65];
    const int m = blockIdx.x >> 5, n0 = (blockIdx.x & 31) << 6;
    for (int i = threadIdx.x; i < 4096; i += 256) {
        const int hh = i >> 6, nn = i & 63;
        tile[hh][nn] = w1[(size_t)(m * 64 + hh) * ND + n0 + nn];
    }
    __syncthreads();
    for (int i = threadIdx.x; i < 4096; i += 256) {
        const int nn = i >> 6, hh = i & 63;
        w1t[((size_t)(n0 + nn) * NM + m) * 64 + hh] = tile[hh][nn];
    }
}

__global__ __launch_bounds__(256) void k_w2t(const float* __restrict__ w2,
                                             float* __restrict__ w2t) {
    const int idx = blockIdx.x * 256 + threadIdx.x;
    const int i = idx & 31;
    const int c = (idx >> 5) & 1;
    const int n = idx >> 6;
    w2t[idx] = w2[(size_t)(i * 2 + c) * ND + n];
}

__global__ __launch_bounds__(256) void k_transpose(const float* __restrict__ predTemp,
                                                   float* __restrict__ out) {
    __shared__ float tile[NS * NITER];
    const int b = blockIdx.x >> 6;
    const int j0 = (blockIdx.x & 63) * 64;
    for (int i = threadIdx.x; i < 3200; i += 256) {
        const int tt = i >> 6, jj = i & 63;
        tile[jj * NITER + tt] = predTemp[((size_t)b * NITER + tt) * NOUT + j0 + jj];
    }
    __syncthreads();
    float* dst = out + ((size_t)b * NOUT + j0) * NITER;
    for (int i = threadIdx.x; i < 3200; i += 256) dst[i] = tile[i];
}

extern "C" void kernel_launch(void* const* d_in, const int* in_sizes, int n_in,
                              void* d_out, int out_size, void* d_ws, size_t ws_size,
                              hipStream_t stream) {
    const float* x        = (const float*)d_in[0];
    const float* kv_w     = (const float*)d_in[1];
    const float* kv_b     = (const float*)d_in[2];
    const float* kv_ln_g  = (const float*)d_in[3];
    const float* kv_ln_b  = (const float*)d_in[4];
    const float* q_w      = (const float*)d_in[5];
    const float* q_b      = (const float*)d_in[6];
    const float* wq       = (const float*)d_in[7];
    const float* wk       = (const float*)d_in[8];
    const float* wv       = (const float*)d_in[9];
    const float* wo       = (const float*)d_in[10];
    const float* bq       = (const float*)d_in[11];
    const float* bk       = (const float*)d_in[12];
    const float* bv       = (const float*)d_in[13];
    const float* bo       = (const float*)d_in[14];
    const float* syn_w    = (const float*)d_in[15];
    const float* syn_b    = (const float*)d_in[16];
    const float* syn_ln_g = (const float*)d_in[17];
    const float* syn_ln_b = (const float*)d_in[18];
    const float* nlm1_w   = (const float*)d_in[19];
    const float* nlm1_b   = (const float*)d_in[20];
    const float* nlm2_w   = (const float*)d_in[21];
    const float* nlm2_b   = (const float*)d_in[22];
    const float* start_a  = (const float*)d_in[23];
    const float* start_tr = (const float*)d_in[24];
    const float* dec_a    = (const float*)d_in[25];
    const float* dec_o    = (const float*)d_in[26];
    const float* out_w    = (const float*)d_in[27];
    const float* out_b    = (const float*)d_in[28];
    const int* ial        = (const int*)d_in[29];
    const int* iar        = (const int*)d_in[30];
    const int* iol        = (const int*)d_in[31];
    const int* ior        = (const int*)d_in[32];
    float* out = (float*)d_out;

    float* ws = (float*)d_ws;
    size_t off = 0;
    auto alloc = [&](size_t n) { float* p = ws + off; off += n; return p; };
    float* actT      = alloc((size_t)ND * NB);
    bf16_t* actB     = (bf16_t*)alloc((size_t)NB * NKSYN / 2);
    bf16_t* kvnB     = (bf16_t*)alloc((size_t)NB * NS * NE / 2);      // 1048576 f
    bf16_t* kvp      = (bf16_t*)alloc((size_t)NB * NS * 1024 / 2);    // 2097152 f
    bf16_t* wkvpack  = (bf16_t*)alloc((size_t)NE * 1024 / 2);         // 262144 f
    float* W_qq      = alloc((size_t)NE * NE);
    float* woT       = alloc((size_t)NE * NE);
    float* woSyn     = alloc((size_t)NE * NOUT);
    bf16_t* bpack    = (bf16_t*)alloc((size_t)NKSYN * NOUT / 2);
    float* sbe       = alloc(NOUT);
    float* b_qq      = alloc(NE);
    float* r_a       = alloc(NE);
    float* r_o       = alloc(NE);
    float* aA        = alloc((size_t)2 * NB * NE);      // zero span start
    float* bA        = alloc((size_t)2 * NB * NE);
    float* aO        = alloc((size_t)2 * NB * NE);
    float* bO        = alloc((size_t)2 * NB * NE);
    float* trace2    = alloc((size_t)NM * ND * NB);
    float* part_syn  = alloc((size_t)8 * NB * NOUT);
    float* part_out  = alloc((size_t)8 * NB * NOUT);
    float* w1t       = alloc((size_t)ND * NM * 64);
    float* w2t       = alloc((size_t)ND * 64);
    int tmode = 0;
    float* predTemp = nullptr;
    if ((off + (size_t)PRED_TOTAL) * sizeof(float) <= ws_size) {
        predTemp = alloc((size_t)PRED_TOTAL);
        tmode = 1;
    }

    k_p0<<<1, 512, 0, stream>>>(dec_a, dec_o, q_b, wq, bq, r_a, r_o, b_qq);
    k_wqq<<<1024, 256, 0, stream>>>(q_w, wq, W_qq);
    k_woT<<<64, 256, 0, stream>>>(wo, woT);
    k_woSyn<<<512, 256, 0, stream>>>(woT, syn_w, woSyn);
    k_sbe<<<16, 256, 0, stream>>>(syn_b, bo, syn_w, sbe);
    k_bpack<<<5120, 256, 0, stream>>>(woSyn, syn_w, bpack);
    k_wkvpack<<<256, 256, 0, stream>>>(wk, wv, wkvpack);
    k_init_trace2<<<(NM * ND * NB) / 256, 256, 0, stream>>>(start_tr, trace2);
    k_init_state<<<(INIT_TOTAL + 255) / 256, 256, 0, stream>>>(start_a, actT, actB, aA);
    k_p1a<<<256, 512, 0, stream>>>(x, kv_w, kv_b, kv_ln_g, kv_ln_b, kvnB);
    k_p1b<<<1024, 256, 0, stream>>>(kvnB, wkvpack, bk, bv, kvp);
    k_w1t<<<800, 256, 0, stream>>>(nlm1_w, w1t);
    k_w2t<<<(ND * 64) / 256, 256, 0, stream>>>(nlm2_w, w2t);

    for (int t = 0; t < NITER; ++t) {
        k_fo<<<512, 512, 0, stream>>>(actT, actB, aA, bA, r_a, ial, iar, W_qq, b_qq,
                                      kvp, aO, bO, r_o, iol, ior, out_w, part_out,
                                      1, (t > 0) ? 1 : 0, t);
        k_gf<<<576, 256, 0, stream>>>(actB, bpack, part_syn, part_out, out_b, out, predTemp,
                                      1, (t > 0) ? 1 : 0, t - 1, tmode);
        k_glu_ln<<<NB, 512, 0, stream>>>(part_syn, sbe, syn_ln_g, syn_ln_b, trace2, t % NM);
        k_nlm<<<512, 256, 0, stream>>>(trace2, w1t, nlm1_b, w2t, nlm2_b, actT, actB, t % NM);
    }
    // tail: out(49) then final(49)
    k_fo<<<512, 512, 0, stream>>>(actT, actB, aA, bA, r_a, ial, iar, W_qq, b_qq,
                                  kvp, aO, bO, r_o, iol, ior, out_w, part_out,
                                  0, 1, NITER);
    k_gf<<<576, 256, 0, stream>>>(actB, bpack, part_syn, part_out, out_b, out, predTemp,
                                  0, 1, NITER - 1, tmode);
    if (tmode) k_transpose<<<NB * 64, 256, 0, stream>>>(predTemp, out);
}

// Round 17
// 3566.080 us; speedup vs baseline: 6.0549x; 1.0849x over previous
//
#include <hip/hip_runtime.h>
#include <math.h>

#define NB 64
#define ND 2048
#define NE 512
#define NM 25
#define NOUT 4096
#define NHEADS 8
#define NDH 64
#define NS 64
#define NITER 50
#define NKSYN 2560
#define PRED_TOTAL (NB * NOUT * NITER)   /* 13107200 */

typedef unsigned short bf16_t;
typedef __attribute__((ext_vector_type(8))) short short8;
typedef __attribute__((ext_vector_type(4))) float f32x4;

__device__ __forceinline__ float sigm(float x) { return 1.f / (1.f + expf(-x)); }

__device__ __forceinline__ bf16_t f2bf(float f) {
    unsigned u = __float_as_uint(f);
    unsigned r = (u + 0x7FFFu + ((u >> 16) & 1u)) >> 16;
    return (bf16_t)r;
}
__device__ __forceinline__ float bf2f(bf16_t h) {
    return __uint_as_float(((unsigned)h) << 16);
}

__device__ __forceinline__ float wredsum(float v) {
#pragma unroll
    for (int o = 32; o; o >>= 1) v += __shfl_xor(v, o);
    return v;
}
__device__ __forceinline__ float wredmax(float v) {
#pragma unroll
    for (int o = 32; o; o >>= 1) v = fmaxf(v, __shfl_xor(v, o));
    return v;
}

template <int OP>
__device__ __forceinline__ float blockReduce(float v, float* red) {
    const int tid = threadIdx.x, lane = tid & 63, wid = tid >> 6;
    v = (OP == 0) ? wredsum(v) : wredmax(v);
    __syncthreads();
    if (lane == 0) red[wid] = v;
    __syncthreads();
    if (tid == 0) {
        const int nw = blockDim.x >> 6;
        float r = red[0];
        for (int w = 1; w < nw; ++w) r = (OP == 0) ? r + red[w] : fmaxf(r, red[w]);
        red[0] = r;
    }
    __syncthreads();
    return red[0];
}

// ---------------- per-step kernels (4 dispatches/step) ----------------

// K1: front(t) on blocks [0,256) + out(t-1) on blocks [256,512). 512 thr.
__global__ __launch_bounds__(512) void k_fo(
        const float* __restrict__ actT, bf16_t* __restrict__ actB,
        float* __restrict__ aA, float* __restrict__ bA,
        const float* __restrict__ r_a,
        const int* __restrict__ ial, const int* __restrict__ iar,
        const bf16_t* __restrict__ W_qqb, const float* __restrict__ b_qq,
        const bf16_t* __restrict__ kvp,
        float* __restrict__ aO, float* __restrict__ bO,
        const float* __restrict__ r_o,
        const int* __restrict__ iol, const int* __restrict__ ior,
        const bf16_t* __restrict__ boutw, float* __restrict__ part_out,
        int doFront, int doOut, int it) {
    __shared__ float lds[8192];
    const int bid = blockIdx.x;
    const int t = threadIdx.x;
    const int lane = t & 63, wv = t >> 6;

    if (bid >= 256) {
        // ---- out(t-1): 2 units per block (thread halves), bf16 out_w ----
        if (!doOut) return;
        const int itO = it - 1;
        const int srcO = itO & 1, dstO = srcO ^ 1;
        const int half = t >> 8, t2 = t & 255;
        const int unit = (bid - 256) * 2 + half;
        const int kp = unit >> 6, jt2 = unit & 63;
        float* sL = lds + half * 4096;   // [64 k][64 b]
#pragma unroll
        for (int c = 0; c < 16; ++c) {
            const int idx = t2 + c * 256;
            const int il = idx >> 6, bb = idx & 63;
            const int i = kp * 64 + il;
            const float pl = actT[iol[i] * NB + bb];
            const float prr = actT[ior[i] * NB + bb];
            const float r = r_o[i];
            const float aN = r * aO[srcO * 32768 + i * NB + bb] + pl * prr;
            const float bN = r * bO[srcO * 32768 + i * NB + bb] + 1.f;
            if (jt2 == 0) {
                aO[dstO * 32768 + i * NB + bb] = aN;
                bO[dstO * 32768 + i * NB + bb] = bN;
            }
            sL[il * 64 + bb] = aN * rsqrtf(bN);
        }
        __syncthreads();
        const int bb = t2 & 63;
        const int j0 = jt2 * 64 + __builtin_amdgcn_readfirstlane((t2 >> 6) & 3) * 16;
        float acc[16];
#pragma unroll
        for (int q = 0; q < 16; ++q) acc[q] = 0.f;
#pragma unroll 4
        for (int k = 0; k < 64; ++k) {
            const float sv = sL[k * 64 + bb];
            const unsigned* wrow = (const unsigned*)(boutw + (size_t)(kp * 64 + k) * NOUT + j0);
#pragma unroll
            for (int q = 0; q < 8; ++q) {
                const unsigned u = wrow[q];                    // uniform -> s_load
                const float w0 = __uint_as_float(u << 16);
                const float w1 = __uint_as_float(u & 0xffff0000u);
                acc[2 * q + 0] = fmaf(sv, w0, acc[2 * q + 0]);
                acc[2 * q + 1] = fmaf(sv, w1, acc[2 * q + 1]);
            }
        }
        float* dstp = part_out + ((size_t)(kp * NB + bb)) * NOUT + j0;
#pragma unroll
        for (int q = 0; q < 16; ++q) dstp[q] = acc[q];
        return;
    }

    // ---- front(t) ----
    if (!doFront) return;
    float* syncS = lds;
    float* partK = lds + 512;
    float* qhS = lds + 1024;
    float* attnS = lds + 1152;
    const int jt = bid >> 6, b = bid & 63;
    const int src = it & 1, dst = src ^ 1;
    // phase 1: action sync (all blocks compute; jt0 persists dbuf)
    {
        const int i = t;
        const float pl = actT[ial[i] * NB + b];
        const float prr = actT[iar[i] * NB + b];
        const float r = r_a[i];
        const float aN = r * aA[src * 32768 + b * NE + i] + pl * prr;
        const float bN = r * bA[src * 32768 + b * NE + i] + 1.f;
        if (jt == 0) {
            aA[dst * 32768 + b * NE + i] = aN;
            bA[dst * 32768 + b * NE + i] = bN;
        }
        syncS[i] = aN * rsqrtf(bN);
    }
    __syncthreads();
    // phase 2: qh j-slice [jt*128, +128), k split 4-way, bf16 W_qq
    {
        const int g = t >> 7, l = t & 127;
        const int j = jt * 128 + l;
        float acc = 0.f;
        const int kk0 = g * 128;
#pragma unroll 4
        for (int k = kk0; k < kk0 + 128; ++k)
            acc = fmaf(syncS[k], bf2f(W_qqb[k * NE + j]), acc);
        partK[g * 128 + l] = acc;
    }
    __syncthreads();
    if (t < 128) {
        qhS[t] = b_qq[jt * 128 + t] + partK[t] + partK[128 + t] + partK[256 + t] + partK[384 + t];
    }
    __syncthreads();
    // phase 3: scores + softmax for heads 2jt, 2jt+1 (waves 0-1).
    if (wv < 2) {
        const int h = jt * 2 + wv, s = lane;
        const bf16_t* kpp = kvp + ((size_t)(b * NS + s) * 1024 + h * NDH);
        float sc = 0.f;
#pragma unroll 8
        for (int d = 0; d < NDH; ++d) sc = fmaf(qhS[wv * 64 + d], bf2f(kpp[d]), sc);
        sc *= 0.125f;
        const float mxv = wredmax(sc);
        const float ev = expf(sc - mxv);
        const float sm = wredsum(ev);
        attnS[wv * 64 + s] = ev / sm;
    }
    __syncthreads();
    // phase 4: o = attn @ V -> actB[b][h*64+d] (bf16). V columns coalesced.
    if (wv < 2) {
        const int h = jt * 2 + wv, d = lane;
        const bf16_t* vpp = kvp + ((size_t)(b * NS) * 1024 + NE + h * NDH + d);
        float o = 0.f;
#pragma unroll 8
        for (int s2 = 0; s2 < NS; ++s2) o = fmaf(attnS[wv * 64 + s2], bf2f(vpp[(size_t)s2 * 1024]), o);
        actB[(size_t)b * NKSYN + h * NDH + d] = f2bf(o);
    }
}

// K2: syn MFMA GEMM(t) on blocks [0,512) + final(t-1) on blocks [512,576). 256 thr.
__global__ __launch_bounds__(256) void k_gf(
        const bf16_t* __restrict__ actB, const bf16_t* __restrict__ bpack,
        float* __restrict__ part_syn,
        const float* __restrict__ part_out, const float* __restrict__ out_b,
        float* __restrict__ out, float* __restrict__ predTemp,
        int doGemm, int doFinal, int tt, int tmode) {
    __shared__ float red[8];
    const int bid = blockIdx.x;
    const int t = threadIdx.x;
    if (bid < 512) {
        if (!doGemm) return;
        const int kp = bid >> 6, jt = bid & 63;
        const int l = t & 63;
        const int wv = t >> 6;
        const int b0 = wv * 16;
        const int row = b0 + (l & 15);
        const int kgrp = l >> 4;
        f32x4 acc[4];
#pragma unroll
        for (int js = 0; js < 4; ++js) acc[js] = (f32x4){0.f, 0.f, 0.f, 0.f};
        const int ks0 = kp * 10;
#pragma unroll 2
        for (int ks = 0; ks < 10; ++ks) {
            const int kk = (ks0 + ks) * 32;
            const short8 av = *(const short8*)(actB + (size_t)row * NKSYN + kk + kgrp * 8);
#pragma unroll
            for (int js = 0; js < 4; ++js) {
                const short8 bv = *(const short8*)(bpack +
                    ((((size_t)(jt * 4 + js)) * 80 + ks0 + ks) * 64 + l) * 8);
                acc[js] = __builtin_amdgcn_mfma_f32_16x16x32_bf16(av, bv, acc[js], 0, 0, 0);
            }
        }
#pragma unroll
        for (int js = 0; js < 4; ++js) {
#pragma unroll
            for (int r = 0; r < 4; ++r) {
                const int b = b0 + kgrp * 4 + r;
                const int j = jt * 64 + js * 16 + (l & 15);
                part_syn[((size_t)(kp * NB + b)) * NOUT + j] = acc[js][r];
            }
        }
    } else {
        if (!doFinal) return;
        const int b = bid - 512;
        float pr[16];
        float lmax = -1e30f;
#pragma unroll
        for (int c = 0; c < 16; ++c) {
            const int j = t + c * 256;
            float v = out_b[j];
#pragma unroll
            for (int kp = 0; kp < 8; ++kp) v += part_out[((size_t)(kp * NB + b)) * NOUT + j];
            pr[c] = v;
            lmax = fmaxf(lmax, v);
        }
        const float mx = blockReduce<1>(lmax, red);
        float ls = 0.f;
#pragma unroll
        for (int c = 0; c < 16; ++c) ls += expf(pr[c] - mx);
        const float se = blockReduce<0>(ls, red);
        const float logZ = mx + logf(se);
        float le = 0.f;
#pragma unroll
        for (int c = 0; c < 16; ++c) { const float lp = pr[c] - logZ; le += expf(lp) * lp; }
        const float ent = blockReduce<0>(le, red);
        const float ne = -ent * 0.12022458674074694f;  // 1/ln(4096)
        if (tmode) {
#pragma unroll
            for (int c = 0; c < 16; ++c)
                predTemp[((size_t)b * NITER + tt) * NOUT + t + c * 256] = pr[c];
        } else {
#pragma unroll
            for (int c = 0; c < 16; ++c) {
                const int j = t + c * 256;
                out[((size_t)b * NOUT + j) * NITER + tt] = pr[c];
            }
        }
        if (t == 0) {
            out[PRED_TOTAL + b * 100 + tt] = ne;
            out[PRED_TOTAL + b * 100 + 50 + tt] = 1.f - ne;
        }
    }
}

// K3: reduce 8 partials + GLU -> raw g to trace2[pos]; per-quarter LN stats.
// grid 256 (b 64 x quarter 4) x 512. statsPart[b*4+q] = {sum, sumsq}.
__global__ __launch_bounds__(512) void k_glu(const float* __restrict__ part,
                                             const float* __restrict__ sbe,
                                             float* __restrict__ trace2,
                                             float* __restrict__ statsPart, int pos) {
    __shared__ float red[8];
    const int b = blockIdx.x >> 2, q = blockIdx.x & 3;
    const int t = threadIdx.x;
    const int n = q * 512 + t;
    float ya = sbe[n], yb = sbe[n + ND];
#pragma unroll
    for (int kp = 0; kp < 8; ++kp) {
        ya += part[((size_t)(kp * NB + b)) * NOUT + n];
        yb += part[((size_t)(kp * NB + b)) * NOUT + n + ND];
    }
    const float g = ya * sigm(yb);
    trace2[((size_t)pos * ND + n) * NB + b] = g;         // raw (normalized by k_nlm)
    const float s = blockReduce<0>(g, red);
    const float ss = blockReduce<0>(g * g, red);
    if (t == 0) {
        statsPart[(blockIdx.x) * 2 + 0] = s;
        statsPart[(blockIdx.x) * 2 + 1] = ss;
    }
}

// K4: per-neuron NLMs (bf16 w1t). Normalizes newest trace entry inline using
// quarter-stats and writes it back (owner-exclusive). grid 512 x 256. lane=b.
__global__ __launch_bounds__(256, 2) void k_nlm(float* __restrict__ trace2,
                                                const bf16_t* __restrict__ bw1t,
                                                const float* __restrict__ b1,
                                                const float* __restrict__ w2t,
                                                const float* __restrict__ b2,
                                                const float* __restrict__ statsPart,
                                                const float* __restrict__ ln_g,
                                                const float* __restrict__ ln_b,
                                                float* __restrict__ actT,
                                                bf16_t* __restrict__ actB, int pos) {
    __shared__ float tileA[4][64];
    const int b = threadIdx.x & 63;
    const int wvu = __builtin_amdgcn_readfirstlane(threadIdx.x >> 6);
    const int n = blockIdx.x * 4 + wvu;                    // uniform per wave
    // LN stats for this lane's b
    float ssum = 0.f, ssq = 0.f;
#pragma unroll
    for (int q = 0; q < 4; ++q) {
        ssum += statsPart[(b * 4 + q) * 2 + 0];
        ssq  += statsPart[(b * 4 + q) * 2 + 1];
    }
    const float mean = ssum * (1.f / ND);
    const float rs = rsqrtf(ssq * (1.f / ND) - mean * mean + 1e-5f);

    const float* brow = b1 + n * 64;
    float acc[64];
#pragma unroll
    for (int q = 0; q < 64; ++q) acc[q] = brow[q];
    int phys = (pos + 1 < NM) ? pos + 1 : 0;
    float tr = trace2[((size_t)phys * ND + n) * NB + b];
#pragma unroll 1
    for (int m = 0; m < NM - 1; ++m) {
        const int physN = (phys + 1 < NM) ? phys + 1 : 0;
        float trn = 0.f;
        if (m + 1 < NM - 1) trn = trace2[((size_t)physN * ND + n) * NB + b];
        const unsigned* wrow = (const unsigned*)(bw1t + ((size_t)n * NM + m) * 64);
#pragma unroll
        for (int q = 0; q < 32; ++q) {
            const unsigned u = wrow[q];                    // uniform -> s_load
            const float w0 = __uint_as_float(u << 16);
            const float w1 = __uint_as_float(u & 0xffff0000u);
            acc[2 * q + 0] = fmaf(tr, w0, acc[2 * q + 0]);
            acc[2 * q + 1] = fmaf(tr, w1, acc[2 * q + 1]);
        }
        tr = trn; phys = physN;
    }
    // newest entry (phys == pos): normalize raw g, write back, accumulate
    {
        const float raw = trace2[((size_t)pos * ND + n) * NB + b];
        const float trNew = (raw - mean) * rs * ln_g[n] + ln_b[n];
        trace2[((size_t)pos * ND + n) * NB + b] = trNew;
        const unsigned* wrow = (const unsigned*)(bw1t + ((size_t)n * NM + (NM - 1)) * 64);
#pragma unroll
        for (int q = 0; q < 32; ++q) {
            const unsigned u = wrow[q];
            const float w0 = __uint_as_float(u << 16);
            const float w1 = __uint_as_float(u & 0xffff0000u);
            acc[2 * q + 0] = fmaf(trNew, w0, acc[2 * q + 0]);
            acc[2 * q + 1] = fmaf(trNew, w1, acc[2 * q + 1]);
        }
    }
    const float* w2r = w2t + n * 64;                        // uniform
    float z0 = b2[n * 2 + 0], z1 = b2[n * 2 + 1];
#pragma unroll
    for (int i = 0; i < 32; ++i) {
        const float hv = acc[i] * sigm(acc[32 + i]);
        z0 = fmaf(hv, w2r[i], z0);
        z1 = fmaf(hv, w2r[32 + i], z1);
    }
    const float val = z0 * sigm(z1);
    actT[n * NB + b] = val;
    tileA[wvu][b] = val;
    __syncthreads();
    const int bb = threadIdx.x >> 2, nn = threadIdx.x & 3;
    actB[(size_t)bb * NKSYN + NE + blockIdx.x * 4 + nn] = f2bf(tileA[nn][bb]);
}

// ---------------- one-time precompute kernels ----------------

__global__ __launch_bounds__(512) void k_p0(const float* __restrict__ dec_a,
                                            const float* __restrict__ dec_o,
                                            const float* __restrict__ q_b,
                                            const float* __restrict__ wq,
                                            const float* __restrict__ bq,
                                            float* __restrict__ r_a, float* __restrict__ r_o,
                                            float* __restrict__ b_qq) {
    const int t = threadIdx.x;
    r_a[t] = expf(-fminf(fmaxf(dec_a[t], 0.f), 15.f));
    r_o[t] = expf(-fminf(fmaxf(dec_o[t], 0.f), 15.f));
    float acc = bq[t];
#pragma unroll 4
    for (int k = 0; k < NE; ++k) acc = fmaf(q_b[k], wq[k * NE + t], acc);
    b_qq[t] = acc;
}

// W_qq = q_w @ wq -> bf16 output.
__global__ __launch_bounds__(256) void k_wqq(const float* __restrict__ q_w,
                                             const float* __restrict__ wq,
                                             bf16_t* __restrict__ W_qqb) {
    const int r = blockIdx.x >> 1;
    const int c = ((blockIdx.x & 1) << 8) + threadIdx.x;
    float acc = 0.f;
#pragma unroll 4
    for (int k = 0; k < NE; ++k) acc = fmaf(q_w[r * NE + k], wq[k * NE + c], acc);
    W_qqb[r * NE + c] = f2bf(acc);
}

__global__ __launch_bounds__(256) void k_woT(const float* __restrict__ wo,
                                             float* __restrict__ woT) {
    __shared__ float tile[64][65];
    const int te = blockIdx.x >> 3, tj = blockIdx.x & 7;
    for (int i = threadIdx.x; i < 4096; i += 256) {
        const int r = i >> 6, c = i & 63;
        tile[r][c] = wo[(size_t)(te * 64 + r) * NE + tj * 64 + c];
    }
    __syncthreads();
    for (int i = threadIdx.x; i < 4096; i += 256) {
        const int r = i >> 6, c = i & 63;
        woT[(size_t)(tj * 64 + r) * NE + te * 64 + c] = tile[c][r];
    }
}

// FIX (r16 post-mortem): row group must be WAVE-uniform. grid 1024 = eg 16 x ct 64;
// e0 = eg*32 + waveId*8 (waveId = t>>6 uniform); c = ct*64 + lane.
__global__ __launch_bounds__(256) void k_woSyn(const float* __restrict__ woT,
                                               const float* __restrict__ syn_w,
                                               float* __restrict__ woSyn) {
    const int eg = blockIdx.x >> 6, ct = blockIdx.x & 63;
    const int c = ct * 64 + (threadIdx.x & 63);
    const int e0 = eg * 32 + __builtin_amdgcn_readfirstlane(threadIdx.x >> 6) * 8;
    float acc[8];
#pragma unroll
    for (int q = 0; q < 8; ++q) acc[q] = 0.f;
#pragma unroll 8
    for (int jp = 0; jp < NE; ++jp) {
        const float wv = syn_w[(size_t)jp * NOUT + c];
        const float* er = woT + (size_t)jp * NE + e0;      // uniform -> s_load
#pragma unroll
        for (int q = 0; q < 8; ++q) acc[q] = fmaf(er[q], wv, acc[q]);
    }
#pragma unroll
    for (int q = 0; q < 8; ++q)
        woSyn[(size_t)(e0 + q) * NOUT + c] = acc[q];
}

__global__ __launch_bounds__(256) void k_sbe(const float* __restrict__ syn_b,
                                             const float* __restrict__ bo,
                                             const float* __restrict__ syn_w,
                                             float* __restrict__ sbe) {
    const int c = blockIdx.x * 256 + threadIdx.x;
    float acc = syn_b[c];
#pragma unroll 4
    for (int jp = 0; jp < NE; ++jp)
        acc = fmaf(bo[jp], syn_w[(size_t)jp * NOUT + c], acc);
    sbe[c] = acc;
}

// out_w -> bf16 flat convert.
__global__ __launch_bounds__(256) void k_cvt(const float* __restrict__ s,
                                             bf16_t* __restrict__ d) {
    const size_t i = (size_t)blockIdx.x * 256 + threadIdx.x;
    d[i] = f2bf(s[i]);
}

// Tiled fragment-pack of combined weights [woSyn rows<512; syn_w rows 512+].
__global__ __launch_bounds__(256) void k_bpack(const float* __restrict__ woSyn,
                                               const float* __restrict__ syn_w,
                                               bf16_t* __restrict__ bpack) {
    __shared__ float tile[32][65];
    const int ksg = blockIdx.x >> 6;
    const int bj = blockIdx.x & 63;
    const int k0 = ksg * 32, j0 = bj * 64;
    for (int i = threadIdx.x; i < 2048; i += 256) {
        const int kk = i >> 6, jj = i & 63;
        const int k = k0 + kk;
        tile[kk][jj] = (k < NE) ? woSyn[(size_t)k * NOUT + j0 + jj]
                                : syn_w[(size_t)k * NOUT + j0 + jj];
    }
    __syncthreads();
    for (int i = threadIdx.x; i < 2048; i += 256) {
        const int j16 = i >> 9;
        const int ii = i & 511;
        const int e = ii & 7, l = ii >> 3;
        const int kk = (l >> 4) * 8 + e;
        const int jj = j16 * 16 + (l & 15);
        bpack[(((size_t)(bj * 4 + j16) * 80 + ksg) * 64) * 8 + ii] = f2bf(tile[kk][jj]);
    }
}

// Pack [wk | wv] (512 x 1024) into MFMA B-fragment order. grid 256.
__global__ __launch_bounds__(256) void k_wkvpack(const float* __restrict__ wk,
                                                 const float* __restrict__ wv,
                                                 bf16_t* __restrict__ wkvpack) {
    __shared__ float tile[32][65];
    const int ksg = blockIdx.x >> 4;
    const int bj = blockIdx.x & 15;
    const int k0 = ksg * 32, j0 = bj * 64;
    for (int i = threadIdx.x; i < 2048; i += 256) {
        const int kk = i >> 6, jj = i & 63;
        const int k = k0 + kk, j = j0 + jj;
        tile[kk][jj] = (j < NE) ? wk[(size_t)k * NE + j] : wv[(size_t)k * NE + (j - NE)];
    }
    __syncthreads();
    for (int i = threadIdx.x; i < 2048; i += 256) {
        const int j16 = i >> 9;
        const int ii = i & 511;
        const int e = ii & 7, l = ii >> 3;
        const int kk = (l >> 4) * 8 + e;
        const int jj = j16 * 16 + (l & 15);
        wkvpack[(((size_t)(bj * 4 + j16) * 16 + ksg) * 64) * 8 + ii] = f2bf(tile[kk][jj]);
    }
}

__global__ __launch_bounds__(256) void k_init_trace2(const float* __restrict__ st,
                                                     float* __restrict__ trace2) {
    const int idx = blockIdx.x * 256 + threadIdx.x;
    const int n = (idx >> 6) & (ND - 1);
    const int m = idx >> 17;
    trace2[idx] = st[n * NM + m];
}

#define INIT_TOTAL (NB * ND + 8 * NB * NE)
__global__ __launch_bounds__(256) void k_init_state(const float* __restrict__ sa,
                                                    float* __restrict__ actT,
                                                    bf16_t* __restrict__ actB,
                                                    float* __restrict__ zeroBase) {
    const int idx = blockIdx.x * 256 + threadIdx.x;
    if (idx >= INIT_TOTAL) return;
    if (idx < NB * ND) {
        const int b = idx & 63, n = idx >> 6;
        actT[n * NB + b] = sa[n];
        actB[(size_t)b * NKSYN + NE + n] = f2bf(sa[n]);
    } else {
        zeroBase[idx - NB * ND] = 0.f;
    }
}

// k_p1a: kvn = LN(feats @ kv_w + kv_b) -> kvnB bf16 [token][e].
__global__ __launch_bounds__(512) void k_p1a(const float* __restrict__ x,
                                             const float* __restrict__ kv_w,
                                             const float* __restrict__ kv_b,
                                             const float* __restrict__ ln_g,
                                             const float* __restrict__ ln_b,
                                             bf16_t* __restrict__ kvnB) {
    __shared__ float kvT[NE][17];     // [e][tok]
    __shared__ float mS[16], rS[16];
    const int b = blockIdx.x >> 2, s0 = (blockIdx.x & 3) * 16;
    const int t = threadIdx.x;
    const int lane = t & 63, wvi = t >> 6;

    {
        float w[12];
#pragma unroll
        for (int c = 0; c < 12; ++c) w[c] = kv_w[c * NE + t];
        const float kb = kv_b[t];
#pragma unroll
        for (int tok = 0; tok < 16; ++tok) {
            float acc = kb;
#pragma unroll
            for (int c = 0; c < 12; ++c)
                acc = fmaf(x[b * 768 + c * 64 + s0 + tok], w[c], acc);
            kvT[t][tok] = acc;
        }
    }
    __syncthreads();
#pragma unroll
    for (int q = 0; q < 2; ++q) {
        const int tok = wvi * 2 + q;
        float s = 0.f, ss = 0.f;
#pragma unroll
        for (int i = 0; i < 8; ++i) {
            const float v = kvT[lane + 64 * i][tok];
            s += v; ss = fmaf(v, v, ss);
        }
        s = wredsum(s); ss = wredsum(ss);
        if (lane == 0) {
            const float mean = s * (1.f / NE);
            mS[tok] = mean;
            rS[tok] = rsqrtf(ss * (1.f / NE) - mean * mean + 1e-5f);
        }
    }
    __syncthreads();
    {
        const float g = ln_g[t], bb2 = ln_b[t];
#pragma unroll
        for (int tok = 0; tok < 16; ++tok) {
            const float kvn = (kvT[t][tok] - mS[tok]) * rS[tok] * g + bb2;
            kvnB[(size_t)(b * 64 + s0 + tok) * NE + t] = f2bf(kvn);
        }
    }
}

// k_p1b: MFMA GEMM [4096 tokens x 1024 (K|V) x 512] -> kvp bf16 [token][1024].
__global__ __launch_bounds__(256, 2) void k_p1b(const bf16_t* __restrict__ kvnB,
                                                const bf16_t* __restrict__ wkvpack,
                                                const float* __restrict__ bk,
                                                const float* __restrict__ bv,
                                                bf16_t* __restrict__ kvp) {
    const int mt = blockIdx.x >> 4, nt = blockIdx.x & 15;
    const int l = threadIdx.x & 63;
    const int wv = threadIdx.x >> 6;
    const int row0 = mt * 64 + wv * 16;
    const int row = row0 + (l & 15);
    const int kgrp = l >> 4;
    f32x4 acc[4];
#pragma unroll
    for (int js = 0; js < 4; ++js) acc[js] = (f32x4){0.f, 0.f, 0.f, 0.f};
#pragma unroll 2
    for (int ks = 0; ks < 16; ++ks) {
        const short8 av = *(const short8*)(kvnB + (size_t)row * NE + ks * 32 + kgrp * 8);
#pragma unroll
        for (int js = 0; js < 4; ++js) {
            const short8 bv8 = *(const short8*)(wkvpack +
                ((((size_t)(nt * 4 + js)) * 16 + ks) * 64 + l) * 8);
            acc[js] = __builtin_amdgcn_mfma_f32_16x16x32_bf16(av, bv8, acc[js], 0, 0, 0);
        }
    }
#pragma unroll
    for (int js = 0; js < 4; ++js) {
#pragma unroll
        for (int r = 0; r < 4; ++r) {
            const int tok = row0 + kgrp * 4 + r;
            const int j = nt * 64 + js * 16 + (l & 15);
            const float bias = (j < NE) ? bk[j] : bv[j - NE];
            kvp[(size_t)tok * 1024 + j] = f2bf(acc[js][r] + bias);
        }
    }
}

// w1 -> bw1t bf16 [n][m][hh]
__global__ __launch_bounds__(256) void k_w1t(const float* __restrict__ w1,
                                             bf16_t* __restrict__ bw1t) {
    __shared__ float tile[64][65];
    const int m = blockIdx.x >> 5, n0 = (blockIdx.x & 31) << 6;
    for (int i = threadIdx.x; i < 4096; i += 256) {
        const int hh = i >> 6, nn = i & 63;
        tile[hh][nn] = w1[(size_t)(m * 64 + hh) * ND + n0 + nn];
    }
    __syncthreads();
    for (int i = threadIdx.x; i < 4096; i += 256) {
        const int nn = i >> 6, hh = i & 63;
        bw1t[((size_t)(n0 + nn) * NM + m) * 64 + hh] = f2bf(tile[hh][nn]);
    }
}

__global__ __launch_bounds__(256) void k_w2t(const float* __restrict__ w2,
                                             float* __restrict__ w2t) {
    const int idx = blockIdx.x * 256 + threadIdx.x;
    const int i = idx & 31;
    const int c = (idx >> 5) & 1;
    const int n = idx >> 6;
    w2t[idx] = w2[(size_t)(i * 2 + c) * ND + n];
}

__global__ __launch_bounds__(256) void k_transpose(const float* __restrict__ predTemp,
                                                   float* __restrict__ out) {
    __shared__ float tile[NS * NITER];
    const int b = blockIdx.x >> 6;
    const int j0 = (blockIdx.x & 63) * 64;
    for (int i = threadIdx.x; i < 3200; i += 256) {
        const int tt = i >> 6, jj = i & 63;
        tile[jj * NITER + tt] = predTemp[((size_t)b * NITER + tt) * NOUT + j0 + jj];
    }
    __syncthreads();
    float* dst = out + ((size_t)b * NOUT + j0) * NITER;
    for (int i = threadIdx.x; i < 3200; i += 256) dst[i] = tile[i];
}

extern "C" void kernel_launch(void* const* d_in, const int* in_sizes, int n_in,
                              void* d_out, int out_size, void* d_ws, size_t ws_size,
                              hipStream_t stream) {
    const float* x        = (const float*)d_in[0];
    const float* kv_w     = (const float*)d_in[1];
    const float* kv_b     = (const float*)d_in[2];
    const float* kv_ln_g  = (const float*)d_in[3];
    const float* kv_ln_b  = (const float*)d_in[4];
    const float* q_w      = (const float*)d_in[5];
    const float* q_b      = (const float*)d_in[6];
    const float* wq       = (const float*)d_in[7];
    const float* wk       = (const float*)d_in[8];
    const float* wv       = (const float*)d_in[9];
    const float* wo       = (const float*)d_in[10];
    const float* bq       = (const float*)d_in[11];
    const float* bk       = (const float*)d_in[12];
    const float* bv       = (const float*)d_in[13];
    const float* bo       = (const float*)d_in[14];
    const float* syn_w    = (const float*)d_in[15];
    const float* syn_b    = (const float*)d_in[16];
    const float* syn_ln_g = (const float*)d_in[17];
    const float* syn_ln_b = (const float*)d_in[18];
    const float* nlm1_w   = (const float*)d_in[19];
    const float* nlm1_b   = (const float*)d_in[20];
    const float* nlm2_w   = (const float*)d_in[21];
    const float* nlm2_b   = (const float*)d_in[22];
    const float* start_a  = (const float*)d_in[23];
    const float* start_tr = (const float*)d_in[24];
    const float* dec_a    = (const float*)d_in[25];
    const float* dec_o    = (const float*)d_in[26];
    const float* out_w    = (const float*)d_in[27];
    const float* out_b    = (const float*)d_in[28];
    const int* ial        = (const int*)d_in[29];
    const int* iar        = (const int*)d_in[30];
    const int* iol        = (const int*)d_in[31];
    const int* ior        = (const int*)d_in[32];
    float* out = (float*)d_out;

    float* ws = (float*)d_ws;
    size_t off = 0;
    auto alloc = [&](size_t n) { float* p = ws + off; off += n; return p; };
    float* actT      = alloc((size_t)ND * NB);
    bf16_t* actB     = (bf16_t*)alloc((size_t)NB * NKSYN / 2);
    bf16_t* kvnB     = (bf16_t*)alloc((size_t)NB * NS * NE / 2);
    bf16_t* kvp      = (bf16_t*)alloc((size_t)NB * NS * 1024 / 2);
    bf16_t* wkvpack  = (bf16_t*)alloc((size_t)NE * 1024 / 2);
    bf16_t* W_qqb    = (bf16_t*)alloc((size_t)NE * NE / 2);
    bf16_t* boutw    = (bf16_t*)alloc((size_t)NE * NOUT / 2);
    float* woT       = alloc((size_t)NE * NE);
    float* woSyn     = alloc((size_t)NE * NOUT);
    bf16_t* bpack    = (bf16_t*)alloc((size_t)NKSYN * NOUT / 2);
    float* sbe       = alloc(NOUT);
    float* b_qq      = alloc(NE);
    float* r_a       = alloc(NE);
    float* r_o       = alloc(NE);
    float* statsPart = alloc(512);
    float* aA        = alloc((size_t)2 * NB * NE);      // zero span start
    float* bA        = alloc((size_t)2 * NB * NE);
    float* aO        = alloc((size_t)2 * NB * NE);
    float* bO        = alloc((size_t)2 * NB * NE);
    float* trace2    = alloc((size_t)NM * ND * NB);
    float* part_syn  = alloc((size_t)8 * NB * NOUT);
    float* part_out  = alloc((size_t)8 * NB * NOUT);
    bf16_t* bw1t     = (bf16_t*)alloc((size_t)ND * NM * 64 / 2);
    float* w2t       = alloc((size_t)ND * 64);
    int tmode = 0;
    float* predTemp = nullptr;
    if ((off + (size_t)PRED_TOTAL) * sizeof(float) <= ws_size) {
        predTemp = alloc((size_t)PRED_TOTAL);
        tmode = 1;
    }

    k_p0<<<1, 512, 0, stream>>>(dec_a, dec_o, q_b, wq, bq, r_a, r_o, b_qq);
    k_wqq<<<1024, 256, 0, stream>>>(q_w, wq, W_qqb);
    k_woT<<<64, 256, 0, stream>>>(wo, woT);
    k_woSyn<<<1024, 256, 0, stream>>>(woT, syn_w, woSyn);
    k_sbe<<<16, 256, 0, stream>>>(syn_b, bo, syn_w, sbe);
    k_bpack<<<5120, 256, 0, stream>>>(woSyn, syn_w, bpack);
    k_wkvpack<<<256, 256, 0, stream>>>(wk, wv, wkvpack);
    k_cvt<<<(NE * NOUT) / 256, 256, 0, stream>>>(out_w, boutw);
    k_init_trace2<<<(NM * ND * NB) / 256, 256, 0, stream>>>(start_tr, trace2);
    k_init_state<<<(INIT_TOTAL + 255) / 256, 256, 0, stream>>>(start_a, actT, actB, aA);
    k_p1a<<<256, 512, 0, stream>>>(x, kv_w, kv_b, kv_ln_g, kv_ln_b, kvnB);
    k_p1b<<<1024, 256, 0, stream>>>(kvnB, wkvpack, bk, bv, kvp);
    k_w1t<<<800, 256, 0, stream>>>(nlm1_w, bw1t);
    k_w2t<<<(ND * 64) / 256, 256, 0, stream>>>(nlm2_w, w2t);

    for (int t = 0; t < NITER; ++t) {
        k_fo<<<512, 512, 0, stream>>>(actT, actB, aA, bA, r_a, ial, iar, W_qqb, b_qq,
                                      kvp, aO, bO, r_o, iol, ior, boutw, part_out,
                                      1, (t > 0) ? 1 : 0, t);
        k_gf<<<576, 256, 0, stream>>>(actB, bpack, part_syn, part_out, out_b, out, predTemp,
                                      1, (t > 0) ? 1 : 0, t - 1, tmode);
        k_glu<<<256, 512, 0, stream>>>(part_syn, sbe, trace2, statsPart, t % NM);
        k_nlm<<<512, 256, 0, stream>>>(trace2, bw1t, nlm1_b, w2t, nlm2_b, statsPart,
                                       syn_ln_g, syn_ln_b, actT, actB, t % NM);
    }
    // tail: out(49) then final(49)
    k_fo<<<512, 512, 0, stream>>>(actT, actB, aA, bA, r_a, ial, iar, W_qqb, b_qq,
                                  kvp, aO, bO, r_o, iol, ior, boutw, part_out,
                                  0, 1, NITER);
    k_gf<<<576, 256, 0, stream>>>(actB, bpack, part_syn, part_out, out_b, out, predTemp,
                                  0, 1, NITER - 1, tmode);
    if (tmode) k_transpose<<<NB * 64, 256, 0, stream>>>(predTemp, out);
}